// Round 10
// baseline (191.356 us; speedup 1.0000x reference)
//
#include <hip/hip_runtime.h>
#include <cstddef>
#include <cstdint>

typedef short  s16x8 __attribute__((ext_vector_type(8)));
typedef float  f32x4 __attribute__((ext_vector_type(4)));
typedef unsigned short u16x4 __attribute__((ext_vector_type(4)));

typedef __attribute__((address_space(1))) const void gas_void;
typedef __attribute__((address_space(3))) void las_void;

// ---------------- bf16 helpers ----------------
__device__ __forceinline__ unsigned short f2bh(float x) {
    union { float f; unsigned int u; } c; c.f = x;
    unsigned int r = c.u + 0x7fffu + ((c.u >> 16) & 1u);
    return (unsigned short)(r >> 16);
}
__device__ __forceinline__ float bh2f(unsigned short h) {
    union { unsigned int u; float f; } c; c.u = ((unsigned int)h) << 16;
    return c.f;
}
__device__ __forceinline__ f32x4 MF(s16x8 a, s16x8 b, f32x4 c) {
    return __builtin_amdgcn_mfma_f32_16x16x32_bf16(a, b, c, 0, 0, 0);
}
__device__ __forceinline__ void gload16(const unsigned short* g, unsigned short* l) {
    __builtin_amdgcn_global_load_lds((gas_void*)g, (las_void*)l, 16, 0, 0);
}

// ---------------- vec region offsets (floats) ----------------
static constexpr size_t OFF_VIS  = 0;
static constexpr size_t OFF_SEM  = 512;
static constexpr size_t OFF_GCN  = 1024;
static constexpr size_t OFF_S512 = 1536;
static constexpr size_t OFF_VROW = 2048;
static constexpr size_t OFF_X    = 3072;
static constexpr size_t OFF_Y3   = 4096;
static constexpr size_t OFF_H3   = 8192;
// fallback big buffers (floats, absolute in ws)
static constexpr size_t OFF_BUF0 = 16384;
static constexpr size_t OFF_BUF1 = OFF_BUF0 + 4194304;
static constexpr size_t OFF_BUF2 = OFF_BUF1 + 4194304;

// ---------------- fast-path ws layout (bytes) ----------------
// adj_h fixed; SCRATCH time-shared: early {emb,sw,w1t,w2t,emT} + p1p, then h1
// (aliases p1p after combine), then whole SCR becomes #7's bf16 partials (p7h).
static constexpr size_t F_ADJH  = 0;                          // 33,554,432
static constexpr size_t F_SCR   = 33554432;                   // 33,554,432 scratch
static constexpr size_t F_EMB_H = F_SCR;                      // 2,621,440
static constexpr size_t F_EMB_L = F_SCR + 2621440;            // 2,621,440
static constexpr size_t F_SW_H  = F_SCR + 5242880;            // 327,680
static constexpr size_t F_SW_L  = F_SCR + 5570560;            // 327,680
static constexpr size_t F_W1T_H = F_SCR + 5898240;            // 1,048,576
static constexpr size_t F_W2T_H = F_SCR + 6946816;            // 2,097,152
static constexpr size_t F_EMT   = F_SCR + 9043968;            // 4,194,304
static constexpr size_t F_P1P   = F_SCR + 16777216;           // 16,777,216 (#4 bf16 partials x4)
static constexpr size_t F_H1    = F_SCR + 16777216;           // 8,388,608 (after p1p dead)
static constexpr size_t F_P7H   = F_SCR;                      // 33,554,432 (#7 bf16 partials x4)
static constexpr size_t F_P1H   = 67108864;                   // 4,194,304
static constexpr size_t F_Y2T   = 71303168;                   // 8,388,608
static constexpr size_t F_VEC   = 79691776;                   // 49,152
static constexpr size_t FAST_WS = 79740928;                   // ~76.0 MB

// ---------------- block reduction ----------------
__device__ inline float blockReduceSum256(float v) {
    #pragma unroll
    for (int o = 32; o > 0; o >>= 1) v += __shfl_down(v, o, 64);
    __shared__ float red[4];
    int w = threadIdx.x >> 6;
    if ((threadIdx.x & 63) == 0) red[w] = v;
    __syncthreads();
    if (threadIdx.x == 0) v = red[0] + red[1] + red[2] + red[3];
    return v;
}

// ---------------- vec3 body (visual branch float4-vectorized) ----------------
__device__ __forceinline__ void vec3_body(int b,
                            const float* __restrict__ frames,
                            const float* __restrict__ scores,
                            const float* __restrict__ word_embed,
                            const float* __restrict__ visual_W, const float* __restrict__ visual_b,
                            const float* __restrict__ semantic_W, const float* __restrict__ semantic_b,
                            const float* __restrict__ score_W, const float* __restrict__ score_b,
                            float* __restrict__ vec) {
    if (b < 512) {
        int row = b;
        const float4* w4 = (const float4*)(visual_W + (size_t)row * 8192);
        const float4* x4 = (const float4*)frames;
        float s = 0.f;
        #pragma unroll
        for (int c0 = 0; c0 < 2048; c0 += 256) {
            int c = c0 + threadIdx.x;
            float4 wv = w4[c], xv = x4[c];
            s += wv.x * xv.x + wv.y * xv.y + wv.z * xv.z + wv.w * xv.w;
        }
        s = blockReduceSum256(s);
        if (threadIdx.x == 0) (vec + OFF_VIS)[row] = fmaxf(s + visual_b[row], 0.f);
        return;
    }
    const float* x; const float* W; const float* bias; float* out; int K; int row;
    if (b < 1024) { row = b - 512;  x = word_embed; W = semantic_W; bias = semantic_b; out = vec + OFF_SEM;  K = 300;  }
    else          { row = b - 1024; x = scores;     W = score_W;    bias = score_b;    out = vec + OFF_S512; K = 1000; }
    const float* wr = W + (size_t)row * K;
    float s = 0.f;
    for (int k = threadIdx.x; k < K; k += 256) s += wr[k] * x[k];
    s = blockReduceSum256(s);
    if (threadIdx.x == 0) out[row] = fmaxf(s + bias[row], 0.f);
}

// ---------------- small kernels ----------------
__global__ void vec3_kernel(const float* __restrict__ frames,
                            const float* __restrict__ scores,
                            const float* __restrict__ word_embed,
                            const float* __restrict__ visual_W, const float* __restrict__ visual_b,
                            const float* __restrict__ semantic_W, const float* __restrict__ semantic_b,
                            const float* __restrict__ score_W, const float* __restrict__ score_b,
                            float* __restrict__ vec) {
    vec3_body(blockIdx.x, frames, scores, word_embed, visual_W, visual_b,
              semantic_W, semantic_b, score_W, score_b, vec);
}

__global__ void vrow_kernel(const float* __restrict__ gc1_W, float* __restrict__ vec) {
    __shared__ float part[128];
    const float* s512 = vec + OFF_S512;
    int jl = threadIdx.x & 127;
    int j = blockIdx.x * 128 + jl;
    int kh = threadIdx.x >> 7;
    float s = 0.f;
    #pragma unroll 4
    for (int k = kh * 256; k < kh * 256 + 256; k++)
        s += s512[k] * gc1_W[(size_t)k * 1024 + j];
    if (kh) part[jl] = s;
    __syncthreads();
    if (!kh) vec[OFF_VROW + j] = s + part[jl];
}

__global__ void y3_kernel(const float* __restrict__ H2, const float* __restrict__ gc3_W,
                          float* __restrict__ vec) {
    int i = blockIdx.x;
    const float* r = H2 + (size_t)i * 1024;
    float s = 0.f;
    for (int k = threadIdx.x; k < 1024; k += 256) s += r[k] * gc3_W[k];
    s = blockReduceSum256(s);
    if (threadIdx.x == 0) vec[OFF_Y3 + i] = s;
}

// fused: y3[i] = sum_j relu(sum_z p7h[z][i,j] + gc2_b[j]) * gc3_W[j]   (4 bf16 partials)
__global__ void h2y3_kernel(const unsigned short* __restrict__ p7h, const float* __restrict__ gc2_b,
                            const float* __restrict__ gc3_W, float* __restrict__ vec) {
    int i = blockIdx.x;
    int c = threadIdx.x;   // 256 threads x 4 cols = 1024
    float a0 = 0.f, a1 = 0.f, a2 = 0.f, a3 = 0.f;
    #pragma unroll
    for (int z = 0; z < 4; z++) {
        u16x4 v = *(const u16x4*)(p7h + (size_t)z * 4194304 + (size_t)i * 1024 + c * 4);
        a0 += bh2f(v[0]); a1 += bh2f(v[1]); a2 += bh2f(v[2]); a3 += bh2f(v[3]);
    }
    float4 bb = ((const float4*)gc2_b)[c];
    float4 ww = ((const float4*)gc3_W)[c];
    float s = fmaxf(a0 + bb.x, 0.f) * ww.x
            + fmaxf(a1 + bb.y, 0.f) * ww.y
            + fmaxf(a2 + bb.z, 0.f) * ww.z
            + fmaxf(a3 + bb.w, 0.f) * ww.w;
    s = blockReduceSum256(s);
    if (threadIdx.x == 0) vec[OFF_Y3 + i] = s;
}

// h3 from bf16 adj
__global__ void h3b_kernel(const unsigned short* __restrict__ adj_h,
                           const float* __restrict__ gc3_b, float* __restrict__ vec) {
    int i = blockIdx.x;
    const u16x4* rp = (const u16x4*)(adj_h + (size_t)i * 4096);
    const float* y3 = vec + OFF_Y3;
    float s = 0.f;
    for (int c = threadIdx.x; c < 1024; c += 256) {
        u16x4 v = rp[c];
        int k0 = c * 4;
        s += bh2f(v[0]) * y3[k0] + bh2f(v[1]) * y3[k0 + 1]
           + bh2f(v[2]) * y3[k0 + 2] + bh2f(v[3]) * y3[k0 + 3];
    }
    s = blockReduceSum256(s);
    if (threadIdx.x == 0) vec[OFF_H3 + i] = fmaxf(s + gc3_b[0], 0.f);
}

__global__ void h3_kernel(const float* __restrict__ adj, const float* __restrict__ gc3_b,
                          float* __restrict__ vec) {
    int i = blockIdx.x;
    const float* r = adj + (size_t)i * 4096;
    const float* y3 = vec + OFF_Y3;
    float s = 0.f;
    for (int k = threadIdx.x; k < 4096; k += 256) s += r[k] * y3[k];
    s = blockReduceSum256(s);
    if (threadIdx.x == 0) vec[OFF_H3 + i] = fmaxf(s + gc3_b[0], 0.f);
}

__global__ void gcn_kernel(const float* __restrict__ gcn512_W, const float* __restrict__ gcn512_b,
                           float* __restrict__ vec) {
    int j = blockIdx.x;
    const float* r = gcn512_W + (size_t)j * 4096;
    const float* h3 = vec + OFF_H3;
    float s = 0.f;
    for (int k = threadIdx.x; k < 4096; k += 256) s += r[k] * h3[k];
    s = blockReduceSum256(s);
    if (threadIdx.x == 0) vec[OFF_GCN + j] = fmaxf(s + gcn512_b[j], 0.f);
}

__global__ void x_kernel(const float* __restrict__ hidden_W, const float* __restrict__ hidden_b,
                         float* __restrict__ vec) {
    int j = blockIdx.x;
    const float* r = hidden_W + (size_t)j * 1536;
    const float* joint = vec;
    float s = 0.f;
    for (int k = threadIdx.x; k < 1536; k += 256) s += r[k] * joint[k];
    s = blockReduceSum256(s);
    if (threadIdx.x == 0) vec[OFF_X + j] = fmaxf(s + hidden_b[j], 0.f);
}

__global__ void out_kernel(const float* __restrict__ vec,
                           const float* __restrict__ critic_W, const float* __restrict__ critic_b,
                           const float* __restrict__ actor_W, const float* __restrict__ actor_b,
                           float* __restrict__ out) {
    const float* xv = vec + OFF_X;
    int w = threadIdx.x >> 6, l = threadIdx.x & 63;
    if (w >= 7) return;
    const float* row = (w == 0) ? critic_W : actor_W + (size_t)(w - 1) * 512;
    float s = 0.f;
    for (int q = l; q < 512; q += 64) s += xv[q] * row[q];
    #pragma unroll
    for (int o = 32; o > 0; o >>= 1) s += __shfl_down(s, o, 64);
    if (l == 0) out[w] = s + ((w == 0) ? critic_b[0] : actor_b[w - 1]);
}

// combine P1 split-K bf16 partials (x4) -> hi bf16
__global__ void combine_p1_kernel(const unsigned short* __restrict__ p1p,
                                  unsigned short* __restrict__ hi) {
    size_t i = (size_t)blockIdx.x * 256 + threadIdx.x;    // u16x4 index over 524288
    float s0 = 0.f, s1 = 0.f, s2 = 0.f, s3 = 0.f;
    #pragma unroll
    for (int z = 0; z < 4; z++) {
        u16x4 v = *(const u16x4*)(p1p + (size_t)z * 2097152 + i * 4);
        s0 += bh2f(v[0]); s1 += bh2f(v[1]); s2 += bh2f(v[2]); s3 += bh2f(v[3]);
    }
    u16x4 hv;
    hv[0] = f2bh(s0); hv[1] = f2bh(s1); hv[2] = f2bh(s2); hv[3] = f2bh(s3);
    *(u16x4*)(hi + i * 4) = hv;
}

// ---------------- fused prep kernel: all converts + vec3, ILP-4 streaming ----------------
__global__ void prep_kernel(const float* __restrict__ adj,
                            const float* __restrict__ all_embeds,
                            const float* __restrict__ semantic_W,
                            const float* __restrict__ gc1_W,
                            const float* __restrict__ gc2_W,
                            const float* __restrict__ frames,
                            const float* __restrict__ scores,
                            const float* __restrict__ word_embed,
                            const float* __restrict__ visual_W, const float* __restrict__ visual_b,
                            const float* __restrict__ semantic_b,
                            const float* __restrict__ score_W, const float* __restrict__ score_b,
                            unsigned short* __restrict__ adj_h,
                            unsigned short* __restrict__ emb_h, unsigned short* __restrict__ emb_l,
                            unsigned short* __restrict__ sw_h, unsigned short* __restrict__ sw_l,
                            unsigned short* __restrict__ w1t_h,
                            unsigned short* __restrict__ w2t_h,
                            float* __restrict__ vec) {
    __shared__ float tile[32][33];
    const int b = blockIdx.x, t = threadIdx.x;
    if (b < 4096) {
        size_t base = (size_t)b * 1024 + t;
        float4 v[4];
        #pragma unroll
        for (int j = 0; j < 4; j++) v[j] = ((const float4*)adj)[base + j * 256];
        #pragma unroll
        for (int j = 0; j < 4; j++) {
            u16x4 h;
            h[0] = f2bh(v[j].x); h[1] = f2bh(v[j].y);
            h[2] = f2bh(v[j].z); h[3] = f2bh(v[j].w);
            *(u16x4*)(adj_h + (base + j * 256) * 4) = h;
        }
    } else if (b < 4096 + 1280) {
        size_t base = (size_t)(b - 4096) * 256 + t;
        float v[4];
        #pragma unroll
        for (int j = 0; j < 4; j++) {
            size_t i = base + (size_t)j * 327680;
            int r = (int)(i / 320), c = (int)(i % 320);
            v[j] = (c < 300) ? all_embeds[(size_t)r * 300 + c] : 0.f;
        }
        #pragma unroll
        for (int j = 0; j < 4; j++) {
            size_t i = base + (size_t)j * 327680;
            unsigned short h = f2bh(v[j]);
            emb_h[i] = h; emb_l[i] = f2bh(v[j] - bh2f(h));
        }
    } else if (b < 4096 + 1280 + 160) {
        size_t base = (size_t)(b - 4096 - 1280) * 256 + t;
        float v[4];
        #pragma unroll
        for (int j = 0; j < 4; j++) {
            size_t i = base + (size_t)j * 40960;
            int r = (int)(i / 320), c = (int)(i % 320);
            v[j] = (c < 300) ? semantic_W[(size_t)r * 300 + c] : 0.f;
        }
        #pragma unroll
        for (int j = 0; j < 4; j++) {
            size_t i = base + (size_t)j * 40960;
            unsigned short h = f2bh(v[j]);
            sw_h[i] = h; sw_l[i] = f2bh(v[j] - bh2f(h));
        }
    } else if (b < 4096 + 1280 + 160 + 512) {
        int l2 = b - 4096 - 1280 - 160;
        const float* src = gc1_W + (size_t)512 * 1024;
        int kb = (l2 & 15) * 32, nb = (l2 >> 4) * 32;
        int tx = t & 31, ty = t >> 5;
        #pragma unroll
        for (int i = 0; i < 32; i += 8)
            tile[ty + i][tx] = src[(size_t)(kb + ty + i) * 1024 + nb + tx];
        __syncthreads();
        #pragma unroll
        for (int i = 0; i < 32; i += 8) {
            int n = nb + ty + i, k = kb + tx;
            w1t_h[(size_t)n * 512 + k] = f2bh(tile[tx][ty + i]);
        }
    } else if (b < 4096 + 1280 + 160 + 512 + 1024) {
        int l2 = b - 4096 - 1280 - 160 - 512;
        int kb = (l2 & 31) * 32, nb = (l2 >> 5) * 32;
        int tx = t & 31, ty = t >> 5;
        #pragma unroll
        for (int i = 0; i < 32; i += 8)
            tile[ty + i][tx] = gc2_W[(size_t)(kb + ty + i) * 1024 + nb + tx];
        __syncthreads();
        #pragma unroll
        for (int i = 0; i < 32; i += 8) {
            int n = nb + ty + i, k = kb + tx;
            w2t_h[(size_t)n * 1024 + k] = f2bh(tile[tx][ty + i]);
        }
    } else {
        vec3_body(b - (4096 + 1280 + 160 + 512 + 1024), frames, scores, word_embed,
                  visual_W, visual_b, semantic_W, semantic_b, score_W, score_b, vec);
    }
}

// ---------------- staging helpers ----------------
template<int NCHP, int NJ>
__device__ __forceinline__ void stg_mat(const unsigned short* __restrict__ src, int ld, int r0,
                                        int k0, unsigned short* dst, int t) {
    #pragma unroll
    for (int j = 0; j < NJ; j++) {
        int c = j * 256 + t;
        int p = c / NCHP;
        int idx = c % NCHP;
        int row = idx >> 2;
        int gg = (idx & 3) ^ ((row >> 1) & 3);
        gload16(src + (size_t)(r0 + row) * ld + (k0 + p * 32 + gg * 8),
                dst + (size_t)(j * 256 + (t & ~63)) * 8);
    }
}

template<int ROWS>
__device__ __forceinline__ s16x8 rfrag(const unsigned short* rb, int row, int p, int g4) {
    int byte = (p * ROWS + row) * 64 + ((g4 ^ ((row >> 1) & 3)) << 4);
    return *(const s16x8*)((const char*)rb + byte);
}

// ---------------- 4-wave MFMA GEMM (round-4 proven structure) ----------------
// C[M,N] = A[M,K] @ B^T ; tile BM x 64, wave (BM/2) x 32.
// PROD: 1 = Ah*Bh ; 3 = Ah*Bh + Ah*Bl + Al*Bh
// WMODE: 3 hi C[m][n]; 4 hi C^T[n][m] (ldc=M); 6 f32 C[m][n]
// SPLITK: blockIdx.z selects K-chunk; Ah/Bh advance z*K; C advances z*M*N.
template<int BM, int BK, int PROD, int WMODE, int RELU, int SPLITK>
__global__ __launch_bounds__(256) void mfma_g(
    const unsigned short* __restrict__ Ah, const unsigned short* __restrict__ Al,
    const unsigned short* __restrict__ Bh, const unsigned short* __restrict__ Bl,
    int K, int lda, int ldb,
    unsigned short* __restrict__ Ch, float* __restrict__ Cf, int ldc,
    const float* __restrict__ bias, const float* __restrict__ bias2)
{
    constexpr int A_USH = BM * BK;
    constexpr int B_USH = 64 * BK;
    constexpr int A_CH  = A_USH / 8;
    constexpr int B_CH  = B_USH / 8;
    constexpr int SLOT  = (PROD == 3) ? 2 * (A_USH + B_USH) : (A_USH + B_USH);
    constexpr int L     = ((A_CH + B_CH) / 256) * ((PROD == 3) ? 2 : 1);
    constexpr int FM    = BM / 32;
    __shared__ unsigned short lds[3 * SLOT];

    const int t = threadIdx.x;
    const int w = t >> 6, l = t & 63;
    const int r = l & 15, g4 = l >> 4;
    const int wr = (w >> 1) * (BM / 2);
    const int wc = (w & 1) * 32;

    const int gx = gridDim.x;
    const int nwg = gx * gridDim.y;
    int flat = blockIdx.y * gx + blockIdx.x;
    int swz = (flat & 7) * (nwg >> 3) + (flat >> 3);
    const int col0 = (swz % gx) * 64;
    const int row0 = (swz / gx) * BM;

    if constexpr (SPLITK) {
        int z = blockIdx.z;
        Ah += (size_t)z * K;
        Bh += (size_t)z * K;
        if (Cf) Cf += (size_t)z * (size_t)nwg * (BM * 64);
        if (Ch) Ch += (size_t)z * (size_t)nwg * (BM * 64);
    }

    f32x4 acc[FM][2];
    #pragma unroll
    for (int a = 0; a < FM; a++)
        #pragma unroll
        for (int b = 0; b < 2; b++) acc[a][b] = (f32x4){0.f, 0.f, 0.f, 0.f};

    auto stage = [&](int slot, int k0) {
        unsigned short* base = lds + slot * SLOT;
        stg_mat<BM * 4, A_CH / 256>(Ah, lda, row0, k0, base, t);
        stg_mat<256,    B_CH / 256>(Bh, ldb, col0, k0, base + A_USH, t);
        if constexpr (PROD == 3) {
            stg_mat<256,    B_CH / 256>(Bl, ldb, col0, k0, base + A_USH + B_USH, t);
            stg_mat<BM * 4, A_CH / 256>(Al, lda, row0, k0, base + A_USH + 2 * B_USH, t);
        }
    };

    const int T = K / BK;
    stage(0, 0);
    stage(1, BK);

    for (int tt = 0; tt < T; ++tt) {
        __builtin_amdgcn_s_barrier();
        if (tt + 2 < T) {
            stage((tt + 2) % 3, (tt + 2) * BK);
            if constexpr (L == 3)      asm volatile("s_waitcnt vmcnt(6)" ::: "memory");
            else if constexpr (L == 4) asm volatile("s_waitcnt vmcnt(8)" ::: "memory");
            else                       asm volatile("s_waitcnt vmcnt(12)" ::: "memory");
        } else if (tt + 1 < T) {
            if constexpr (L == 3)      asm volatile("s_waitcnt vmcnt(3)" ::: "memory");
            else if constexpr (L == 4) asm volatile("s_waitcnt vmcnt(4)" ::: "memory");
            else                       asm volatile("s_waitcnt vmcnt(6)" ::: "memory");
        } else {
            asm volatile("s_waitcnt vmcnt(0)" ::: "memory");
        }
        __builtin_amdgcn_s_barrier();

        const unsigned short* base = lds + (tt % 3) * SLOT;
        #pragma unroll
        for (int kk = 0; kk < BK / 32; kk++) {
            s16x8 a[FM], bb[2], alr[FM], blr[2];
            #pragma unroll
            for (int f = 0; f < FM; f++) a[f] = rfrag<BM>(base, wr + f * 16 + r, kk, g4);
            #pragma unroll
            for (int f = 0; f < 2; f++) bb[f] = rfrag<64>(base + A_USH, wc + f * 16 + r, kk, g4);
            if constexpr (PROD == 3) {
                #pragma unroll
                for (int f = 0; f < 2; f++) blr[f] = rfrag<64>(base + A_USH + B_USH, wc + f * 16 + r, kk, g4);
                #pragma unroll
                for (int f = 0; f < FM; f++) alr[f] = rfrag<BM>(base + A_USH + 2 * B_USH, wr + f * 16 + r, kk, g4);
            }
            __builtin_amdgcn_s_setprio(1);
            #pragma unroll
            for (int fm = 0; fm < FM; fm++)
                #pragma unroll
                for (int fn = 0; fn < 2; fn++) {
                    acc[fm][fn] = MF(a[fm], bb[fn], acc[fm][fn]);
                    if constexpr (PROD == 3) {
                        acc[fm][fn] = MF(a[fm], blr[fn], acc[fm][fn]);
                        acc[fm][fn] = MF(alr[fm], bb[fn], acc[fm][fn]);
                    }
                }
            __builtin_amdgcn_s_setprio(0);
        }
    }

    // epilogue (C/D: col = lane&15, row = 4*(lane>>4)+i — m89-verified)
    #pragma unroll
    for (int fn = 0; fn < 2; fn++) {
        int n = col0 + wc + fn * 16 + r;
        float bn = bias ? bias[n] : 0.f;
        if (bias2) bn += bias2[n];
        #pragma unroll
        for (int fm = 0; fm < FM; fm++) {
            int m0 = row0 + wr + fm * 16 + g4 * 4;
            f32x4 v = acc[fm][fn];
            if constexpr (WMODE == 4) {
                u16x4 hv;
                #pragma unroll
                for (int i = 0; i < 4; i++) {
                    float x = v[i] + bn;
                    if (RELU) x = fmaxf(x, 0.f);
                    hv[i] = f2bh(x);
                }
                *(u16x4*)(Ch + (size_t)n * ldc + m0) = hv;
            } else if constexpr (WMODE == 6) {
                #pragma unroll
                for (int i = 0; i < 4; i++) {
                    float x = v[i] + bn;
                    if (RELU) x = fmaxf(x, 0.f);
                    Cf[(size_t)(m0 + i) * ldc + n] = x;
                }
            } else {  // WMODE 3: hi bf16 C[m][n]
                #pragma unroll
                for (int i = 0; i < 4; i++) {
                    float x = v[i] + bn;
                    if (RELU) x = fmaxf(x, 0.f);
                    Ch[(size_t)(m0 + i) * ldc + n] = f2bh(x);
                }
            }
        }
    }
}

// ---------------- 4-wave SQUARE-tile GEMM: 128x128, wave 64x64, BK=32, ring-2, split-K4 ----
// bf16 partials: Ch[z*4096*1024 + m*ldc + n]. LDS 32 KB -> 4-5 blocks/CU; grid 1024 = 4/CU.
__global__ __launch_bounds__(256) void mfma_sq(
    const unsigned short* __restrict__ Ah,
    const unsigned short* __restrict__ Bh,
    int Kc, int lda, int ldb,
    unsigned short* __restrict__ Ch, int ldc)
{
    constexpr int A_USH = 128 * 32;           // 4096 ush
    constexpr int SLOT  = 2 * A_USH;          // 8192 ush = 16 KB
    __shared__ unsigned short lds[2 * SLOT];  // 32 KB ring-2

    const int t = threadIdx.x;
    const int w = t >> 6, l = t & 63;
    const int r = l & 15, g4 = l >> 4;
    const int wr = (w >> 1) * 64, wc = (w & 1) * 64;

    const int gx = gridDim.x;
    const int nwg = gx * gridDim.y;
    int flat = blockIdx.y * gx + blockIdx.x;
    int swz = (flat & 7) * (nwg >> 3) + (flat >> 3);
    const int col0 = (swz % gx) * 128;
    const int row0 = (swz / gx) * 128;

    const int z = blockIdx.z;
    Ah += (size_t)z * Kc;
    Bh += (size_t)z * Kc;
    Ch += (size_t)z * 4194304;

    f32x4 acc[4][4];
    #pragma unroll
    for (int a = 0; a < 4; a++)
        #pragma unroll
        for (int b = 0; b < 4; b++) acc[a][b] = (f32x4){0.f, 0.f, 0.f, 0.f};

    auto stage = [&](int slot, int k0) {
        unsigned short* base = lds + slot * SLOT;
        stg_mat<512, 2>(Ah, lda, row0, k0, base, t);
        stg_mat<512, 2>(Bh, ldb, col0, k0, base + A_USH, t);
    };

    const int T = Kc >> 5;
    stage(0, 0);

    for (int tt = 0; tt < T; ++tt) {
        __builtin_amdgcn_s_barrier();               // all waves done computing tt-1
        if (tt + 1 < T) {
            stage((tt + 1) & 1, (tt + 1) * 32);     // 4 loads/thread
            asm volatile("s_waitcnt vmcnt(4)" ::: "memory");   // tile tt landed
        } else {
            asm volatile("s_waitcnt vmcnt(0)" ::: "memory");
        }
        __builtin_amdgcn_s_barrier();               // tile tt staged for everyone

        const unsigned short* base = lds + (tt & 1) * SLOT;
        s16x8 a[4], bb[4];
        #pragma unroll
        for (int f = 0; f < 4; f++) a[f] = rfrag<128>(base, wr + f * 16 + r, 0, g4);
        #pragma unroll
        for (int f = 0; f < 4; f++) bb[f] = rfrag<128>(base + A_USH, wc + f * 16 + r, 0, g4);
        __builtin_amdgcn_s_setprio(1);
        #pragma unroll
        for (int fm = 0; fm < 4; fm++)
            #pragma unroll
            for (int fn = 0; fn < 4; fn++)
                acc[fm][fn] = MF(a[fm], bb[fn], acc[fm][fn]);
        __builtin_amdgcn_s_setprio(0);
    }

    // epilogue: bf16 partials (C/D: col = lane&15, row = 4*(lane>>4)+i)
    #pragma unroll
    for (int fn = 0; fn < 4; fn++) {
        int n = col0 + wc + fn * 16 + r;
        #pragma unroll
        for (int fm = 0; fm < 4; fm++) {
            int m0 = row0 + wr + fm * 16 + g4 * 4;
            f32x4 v = acc[fm][fn];
            #pragma unroll
            for (int i = 0; i < 4; i++)
                Ch[(size_t)(m0 + i) * ldc + n] = f2bh(v[i]);
        }
    }
}

// ---------------- fallback f32 tiled GEMM (round-1, proven) ----------------
template<int TRANSB>
__global__ __launch_bounds__(256) void gemm_f32_128(
    const float* __restrict__ A, const float* __restrict__ B, float* __restrict__ C,
    int M, int N, int K, int lda, int ldb,
    const float* __restrict__ bias, const float* __restrict__ vrow, int do_relu)
{
    constexpr int BM = 128, BN = 128, BK = 16;
    __shared__ float As[BK][BM + 4];
    __shared__ float Bs[BK][BN + 4];
    const int t = threadIdx.x;
    const int w = t >> 6, l = t & 63;
    const int cx = (w & 1) * 8 + (l & 7);
    const int cy = (w >> 1) * 8 + (l >> 3);
    const int row0 = blockIdx.y * BM;
    const int col0 = blockIdx.x * BN;

    float acc[8][8];
    #pragma unroll
    for (int i = 0; i < 8; i++)
        #pragma unroll
        for (int j = 0; j < 8; j++) acc[i][j] = 0.f;

    const int ka = t & 15;
    const int ma = t >> 4;

    for (int k0 = 0; k0 < K; k0 += BK) {
        #pragma unroll
        for (int i = 0; i < 8; i++) {
            int m = ma + i * 16;
            int gk = k0 + ka;
            float v = 0.f;
            if (gk < K) v = A[(size_t)(row0 + m) * lda + gk];
            As[ka][m] = v;
        }
        if (TRANSB) {
            #pragma unroll
            for (int i = 0; i < 8; i++) {
                int n = ma + i * 16;
                int gk = k0 + ka;
                float v = 0.f;
                if (gk < K) v = B[(size_t)(col0 + n) * ldb + gk];
                Bs[ka][n] = v;
            }
        } else {
            const int nb = t & 127;
            const int kb = t >> 7;
            #pragma unroll
            for (int i = 0; i < 8; i++) {
                int kk = kb + i * 2;
                int gk = k0 + kk;
                float v = 0.f;
                if (gk < K) v = B[(size_t)gk * ldb + col0 + nb];
                Bs[kk][nb] = v;
            }
        }
        __syncthreads();
        #pragma unroll
        for (int kk = 0; kk < BK; kk++) {
            float a[8], bb[8];
            *(float4*)&a[0]  = *(const float4*)&As[kk][cy * 8];
            *(float4*)&a[4]  = *(const float4*)&As[kk][cy * 8 + 4];
            *(float4*)&bb[0] = *(const float4*)&Bs[kk][cx * 8];
            *(float4*)&bb[4] = *(const float4*)&Bs[kk][cx * 8 + 4];
            #pragma unroll
            for (int i = 0; i < 8; i++)
                #pragma unroll
                for (int j = 0; j < 8; j++)
                    acc[i][j] = fmaf(a[i], bb[j], acc[i][j]);
        }
        __syncthreads();
    }

    #pragma unroll
    for (int i = 0; i < 8; i++) {
        int rr = row0 + cy * 8 + i;
        float vv[8];
        #pragma unroll
        for (int j = 0; j < 8; j++) {
            int c = col0 + cx * 8 + j;
            float v = acc[i][j];
            if (vrow) v += vrow[c];
            if (bias) v += bias[c];
            if (do_relu) v = fmaxf(v, 0.f);
            vv[j] = v;
        }
        float* cp = C + (size_t)rr * N + col0 + cx * 8;
        *(float4*)cp       = *(float4*)&vv[0];
        *(float4*)(cp + 4) = *(float4*)&vv[4];
    }
}

// ---------------- host launcher ----------------
extern "C" void kernel_launch(void* const* d_in, const int* in_sizes, int n_in,
                              void* d_out, int out_size, void* d_ws, size_t ws_size,
                              hipStream_t stream) {
    const float* frames     = (const float*)d_in[0];
    const float* scores     = (const float*)d_in[1];
    const float* word_embed = (const float*)d_in[2];
    const float* all_embeds = (const float*)d_in[3];
    const float* adj        = (const float*)d_in[4];
    const float* visual_W   = (const float*)d_in[5];
    const float* visual_b   = (const float*)d_in[6];
    const float* semantic_W = (const float*)d_in[7];
    const float* semantic_b = (const float*)d_in[8];
    const float* score_W    = (const float*)d_in[9];
    const float* score_b    = (const float*)d_in[10];
    const float* gc1_W      = (const float*)d_in[11];
    const float* gc1_b      = (const float*)d_in[12];
    const float* gc2_W      = (const float*)d_in[13];
    const float* gc2_b      = (const float*)d_in[14];
    const float* gc3_W      = (const float*)d_in[15];
    const float* gc3_b      = (const float*)d_in[16];
    const float* gcn512_W   = (const float*)d_in[17];
    const float* gcn512_b   = (const float*)d_in[18];
    const float* hidden_W   = (const float*)d_in[19];
    const float* hidden_b   = (const float*)d_in[20];
    const float* critic_W   = (const float*)d_in[21];
    const float* critic_b   = (const float*)d_in[22];
    const float* actor_W    = (const float*)d_in[23];
    const float* actor_b    = (const float*)d_in[24];

    float* out = (float*)d_out;

    if (ws_size >= FAST_WS) {
        char* wsb = (char*)d_ws;
        unsigned short* adj_h = (unsigned short*)(wsb + F_ADJH);
        unsigned short* emb_h = (unsigned short*)(wsb + F_EMB_H);
        unsigned short* emb_l = (unsigned short*)(wsb + F_EMB_L);
        unsigned short* sw_h  = (unsigned short*)(wsb + F_SW_H);
        unsigned short* sw_l  = (unsigned short*)(wsb + F_SW_L);
        unsigned short* w1t_h = (unsigned short*)(wsb + F_W1T_H);
        unsigned short* w2t_h = (unsigned short*)(wsb + F_W2T_H);
        unsigned short* emT   = (unsigned short*)(wsb + F_EMT);
        unsigned short* p1p   = (unsigned short*)(wsb + F_P1P);
        unsigned short* p1_h  = (unsigned short*)(wsb + F_P1H);
        unsigned short* h1    = (unsigned short*)(wsb + F_H1);
        unsigned short* y2t   = (unsigned short*)(wsb + F_Y2T);
        unsigned short* p7h   = (unsigned short*)(wsb + F_P7H);
        float*          vec   = (float*)(wsb + F_VEC);

        // 1. prep: all converts + vec3 (ILP-4 streaming)
        prep_kernel<<<4096 + 1280 + 160 + 512 + 1024 + 1536, 256, 0, stream>>>(
            adj, all_embeds, semantic_W, gc1_W, gc2_W,
            frames, scores, word_embed, visual_W, visual_b, semantic_b, score_W, score_b,
            adj_h, emb_h, emb_l, sw_h, sw_l, w1t_h, w2t_h, vec);
        // 2. vrow = s512 @ gc1_W[:512,:]
        vrow_kernel<<<8, 256, 0, stream>>>(gc1_W, vec);
        // 3. emT = relu(all_embeds @ semantic_W^T + b)^T  hi [512,4096], K=320, PROD=3
        mfma_g<64, 32, 3, 4, 1, 0><<<dim3(8, 64), 256, 0, stream>>>(
            emb_h, emb_l, sw_h, sw_l, 320, 320, 320,
            emT, nullptr, 4096, semantic_b, nullptr);
        // 4. P1 partials = adj @ em  bf16, split-K x4  [4096,512], BK=32 (4 blocks/CU)
        mfma_g<128, 32, 1, 3, 0, 1><<<dim3(8, 32, 4), 256, 0, stream>>>(
            adj_h, nullptr, emT, nullptr, 1024, 4096, 4096,
            p1p, nullptr, 512, nullptr, nullptr);
        // 4b. combine 4 bf16 partials -> p1 hi
        combine_p1_kernel<<<2048, 256, 0, stream>>>(p1p, p1_h);
        // 5. h1 = relu(P1_hi @ W1'_hi + vrow + b1)  hi [4096,1024], K=512, PROD=1
        mfma_g<128, 64, 1, 3, 1, 0><<<dim3(16, 32), 256, 0, stream>>>(
            p1_h, nullptr, w1t_h, nullptr, 512, 512, 512,
            h1, nullptr, 1024, gc1_b, vec + OFF_VROW);
        // 6. y2t = (h1 @ gc2_W)^T  hi [1024,4096], K=1024
        mfma_g<128, 64, 1, 4, 0, 0><<<dim3(16, 32), 256, 0, stream>>>(
            h1, nullptr, w2t_h, nullptr, 1024, 1024, 1024,
            y2t, nullptr, 4096, nullptr, nullptr);
        // 7. p7h partials = adj @ Y2  bf16, square tiles, split-K x4  [4096,1024]
        mfma_sq<<<dim3(8, 32, 4), 256, 0, stream>>>(
            adj_h, y2t, 1024, 4096, 4096, p7h, 1024);
        // 7b. y3[i] = sum_j relu(sum_z p7h + b2)[i,j] * gc3_W[j]
        h2y3_kernel<<<4096, 256, 0, stream>>>(p7h, gc2_b, gc3_W, vec);
        // 8-11. tail
        h3b_kernel<<<4096, 256, 0, stream>>>(adj_h, gc3_b, vec);
        gcn_kernel<<<512, 256, 0, stream>>>(gcn512_W, gcn512_b, vec);
        x_kernel<<<512, 256, 0, stream>>>(hidden_W, hidden_b, vec);
        out_kernel<<<1, 512, 0, stream>>>(vec, critic_W, critic_b, actor_W, actor_b, out);
    } else {
        // fallback f32 path (round-1, proven within 50.4 MB)
        float* ws = (float*)d_ws;
        float* em = ws + OFF_BUF0;
        float* Y1 = ws + OFF_BUF1;
        float* H1 = ws + OFF_BUF2;
        float* Y2 = ws + OFF_BUF1;
        float* H2 = ws + OFF_BUF0;

        vec3_kernel<<<1536, 256, 0, stream>>>(frames, scores, word_embed,
                                              visual_W, visual_b, semantic_W, semantic_b,
                                              score_W, score_b, ws);
        vrow_kernel<<<8, 256, 0, stream>>>(gc1_W, ws);
        gemm_f32_128<1><<<dim3(512 / 128, 4096 / 128), 256, 0, stream>>>(
            all_embeds, semantic_W, em, 4096, 512, 300, 300, 300, semantic_b, nullptr, 1);
        gemm_f32_128<0><<<dim3(1024 / 128, 4096 / 128), 256, 0, stream>>>(
            em, gc1_W + (size_t)512 * 1024, Y1, 4096, 1024, 512, 512, 1024,
            nullptr, ws + OFF_VROW, 0);
        gemm_f32_128<0><<<dim3(1024 / 128, 4096 / 128), 256, 0, stream>>>(
            adj, Y1, H1, 4096, 1024, 4096, 4096, 1024, gc1_b, nullptr, 1);
        gemm_f32_128<0><<<dim3(1024 / 128, 4096 / 128), 256, 0, stream>>>(
            H1, gc2_W, Y2, 4096, 1024, 1024, 1024, 1024, nullptr, nullptr, 0);
        gemm_f32_128<0><<<dim3(1024 / 128, 4096 / 128), 256, 0, stream>>>(
            adj, Y2, H2, 4096, 1024, 4096, 4096, 1024, gc2_b, nullptr, 1);
        y3_kernel<<<4096, 256, 0, stream>>>(H2, gc3_W, ws);
        h3_kernel<<<4096, 256, 0, stream>>>(adj, gc3_b, ws);
        gcn_kernel<<<512, 256, 0, stream>>>(gcn512_W, gcn512_b, ws);
        x_kernel<<<512, 256, 0, stream>>>(hidden_W, hidden_b, ws);
        out_kernel<<<1, 512, 0, stream>>>(ws, critic_W, critic_b, actor_W, actor_b, out);
    }

    (void)in_sizes; (void)n_in; (void)out_size;
}

// Round 11
// 190.473 us; speedup vs baseline: 1.0046x; 1.0046x over previous
//
#include <hip/hip_runtime.h>
#include <cstddef>
#include <cstdint>

typedef short  s16x8 __attribute__((ext_vector_type(8)));
typedef float  f32x4 __attribute__((ext_vector_type(4)));
typedef unsigned short u16x4 __attribute__((ext_vector_type(4)));

typedef __attribute__((address_space(1))) const void gas_void;
typedef __attribute__((address_space(3))) void las_void;

// ---------------- bf16 helpers ----------------
__device__ __forceinline__ unsigned short f2bh(float x) {
    union { float f; unsigned int u; } c; c.f = x;
    unsigned int r = c.u + 0x7fffu + ((c.u >> 16) & 1u);
    return (unsigned short)(r >> 16);
}
__device__ __forceinline__ float bh2f(unsigned short h) {
    union { unsigned int u; float f; } c; c.u = ((unsigned int)h) << 16;
    return c.f;
}
__device__ __forceinline__ f32x4 MF(s16x8 a, s16x8 b, f32x4 c) {
    return __builtin_amdgcn_mfma_f32_16x16x32_bf16(a, b, c, 0, 0, 0);
}
__device__ __forceinline__ void gload16(const unsigned short* g, unsigned short* l) {
    __builtin_amdgcn_global_load_lds((gas_void*)g, (las_void*)l, 16, 0, 0);
}

// ---------------- vec region offsets (floats) ----------------
static constexpr size_t OFF_VIS  = 0;
static constexpr size_t OFF_SEM  = 512;
static constexpr size_t OFF_GCN  = 1024;
static constexpr size_t OFF_S512 = 1536;
static constexpr size_t OFF_VROW = 2048;
static constexpr size_t OFF_X    = 3072;
static constexpr size_t OFF_Y3   = 4096;
static constexpr size_t OFF_H3   = 8192;
// fallback big buffers (floats, absolute in ws)
static constexpr size_t OFF_BUF0 = 16384;
static constexpr size_t OFF_BUF1 = OFF_BUF0 + 4194304;
static constexpr size_t OFF_BUF2 = OFF_BUF1 + 4194304;

// ---------------- fast-path ws layout (bytes) ----------------
static constexpr size_t F_ADJH  = 0;                          // 33,554,432
static constexpr size_t F_SCR   = 33554432;                   // 33,554,432 scratch
static constexpr size_t F_EMB_H = F_SCR;                      // 2,621,440
static constexpr size_t F_EMB_L = F_SCR + 2621440;            // 2,621,440
static constexpr size_t F_SW_H  = F_SCR + 5242880;            // 327,680
static constexpr size_t F_SW_L  = F_SCR + 5570560;            // 327,680
static constexpr size_t F_W1T_H = F_SCR + 5898240;            // 1,048,576
static constexpr size_t F_W2T_H = F_SCR + 6946816;            // 2,097,152
static constexpr size_t F_EMT   = F_SCR + 9043968;            // 4,194,304
static constexpr size_t F_P1F   = F_SCR + 16777216;           // 16,777,216 (#4 f32 partials x2)
static constexpr size_t F_H1    = F_SCR + 16777216;           // 8,388,608 (after p1f dead)
static constexpr size_t F_P7H   = F_SCR;                      // 33,554,432 (#7 bf16 partials x4)
static constexpr size_t F_P1H   = 67108864;                   // 4,194,304
static constexpr size_t F_Y2T   = 71303168;                   // 8,388,608
static constexpr size_t F_VEC   = 79691776;                   // 49,152
static constexpr size_t FAST_WS = 79740928;                   // ~76.0 MB

// ---------------- block reduction ----------------
__device__ inline float blockReduceSum256(float v) {
    #pragma unroll
    for (int o = 32; o > 0; o >>= 1) v += __shfl_down(v, o, 64);
    __shared__ float red[4];
    int w = threadIdx.x >> 6;
    if ((threadIdx.x & 63) == 0) red[w] = v;
    __syncthreads();
    if (threadIdx.x == 0) v = red[0] + red[1] + red[2] + red[3];
    return v;
}

// ---------------- vec3 body (visual branch float4-vectorized) ----------------
__device__ __forceinline__ void vec3_body(int b,
                            const float* __restrict__ frames,
                            const float* __restrict__ scores,
                            const float* __restrict__ word_embed,
                            const float* __restrict__ visual_W, const float* __restrict__ visual_b,
                            const float* __restrict__ semantic_W, const float* __restrict__ semantic_b,
                            const float* __restrict__ score_W, const float* __restrict__ score_b,
                            float* __restrict__ vec) {
    if (b < 512) {
        int row = b;
        const float4* w4 = (const float4*)(visual_W + (size_t)row * 8192);
        const float4* x4 = (const float4*)frames;
        float s = 0.f;
        #pragma unroll
        for (int c0 = 0; c0 < 2048; c0 += 256) {
            int c = c0 + threadIdx.x;
            float4 wv = w4[c], xv = x4[c];
            s += wv.x * xv.x + wv.y * xv.y + wv.z * xv.z + wv.w * xv.w;
        }
        s = blockReduceSum256(s);
        if (threadIdx.x == 0) (vec + OFF_VIS)[row] = fmaxf(s + visual_b[row], 0.f);
        return;
    }
    const float* x; const float* W; const float* bias; float* out; int K; int row;
    if (b < 1024) { row = b - 512;  x = word_embed; W = semantic_W; bias = semantic_b; out = vec + OFF_SEM;  K = 300;  }
    else          { row = b - 1024; x = scores;     W = score_W;    bias = score_b;    out = vec + OFF_S512; K = 1000; }
    const float* wr = W + (size_t)row * K;
    float s = 0.f;
    for (int k = threadIdx.x; k < K; k += 256) s += wr[k] * x[k];
    s = blockReduceSum256(s);
    if (threadIdx.x == 0) out[row] = fmaxf(s + bias[row], 0.f);
}

// ---------------- small kernels ----------------
__global__ void vec3_kernel(const float* __restrict__ frames,
                            const float* __restrict__ scores,
                            const float* __restrict__ word_embed,
                            const float* __restrict__ visual_W, const float* __restrict__ visual_b,
                            const float* __restrict__ semantic_W, const float* __restrict__ semantic_b,
                            const float* __restrict__ score_W, const float* __restrict__ score_b,
                            float* __restrict__ vec) {
    vec3_body(blockIdx.x, frames, scores, word_embed, visual_W, visual_b,
              semantic_W, semantic_b, score_W, score_b, vec);
}

__global__ void vrow_kernel(const float* __restrict__ gc1_W, float* __restrict__ vec) {
    __shared__ float part[128];
    const float* s512 = vec + OFF_S512;
    int jl = threadIdx.x & 127;
    int j = blockIdx.x * 128 + jl;
    int kh = threadIdx.x >> 7;
    float s = 0.f;
    #pragma unroll 4
    for (int k = kh * 256; k < kh * 256 + 256; k++)
        s += s512[k] * gc1_W[(size_t)k * 1024 + j];
    if (kh) part[jl] = s;
    __syncthreads();
    if (!kh) vec[OFF_VROW + j] = s + part[jl];
}

__global__ void y3_kernel(const float* __restrict__ H2, const float* __restrict__ gc3_W,
                          float* __restrict__ vec) {
    int i = blockIdx.x;
    const float* r = H2 + (size_t)i * 1024;
    float s = 0.f;
    for (int k = threadIdx.x; k < 1024; k += 256) s += r[k] * gc3_W[k];
    s = blockReduceSum256(s);
    if (threadIdx.x == 0) vec[OFF_Y3 + i] = s;
}

// fused: y3[i] = sum_j relu(sum_z p7h[z][i,j] + gc2_b[j]) * gc3_W[j]   (4 bf16 partials)
__global__ void h2y3_kernel(const unsigned short* __restrict__ p7h, const float* __restrict__ gc2_b,
                            const float* __restrict__ gc3_W, float* __restrict__ vec) {
    int i = blockIdx.x;
    int c = threadIdx.x;
    float a0 = 0.f, a1 = 0.f, a2 = 0.f, a3 = 0.f;
    #pragma unroll
    for (int z = 0; z < 4; z++) {
        u16x4 v = *(const u16x4*)(p7h + (size_t)z * 4194304 + (size_t)i * 1024 + c * 4);
        a0 += bh2f(v[0]); a1 += bh2f(v[1]); a2 += bh2f(v[2]); a3 += bh2f(v[3]);
    }
    float4 bb = ((const float4*)gc2_b)[c];
    float4 ww = ((const float4*)gc3_W)[c];
    float s = fmaxf(a0 + bb.x, 0.f) * ww.x
            + fmaxf(a1 + bb.y, 0.f) * ww.y
            + fmaxf(a2 + bb.z, 0.f) * ww.z
            + fmaxf(a3 + bb.w, 0.f) * ww.w;
    s = blockReduceSum256(s);
    if (threadIdx.x == 0) vec[OFF_Y3 + i] = s;
}

// h3 from bf16 adj
__global__ void h3b_kernel(const unsigned short* __restrict__ adj_h,
                           const float* __restrict__ gc3_b, float* __restrict__ vec) {
    int i = blockIdx.x;
    const u16x4* rp = (const u16x4*)(adj_h + (size_t)i * 4096);
    const float* y3 = vec + OFF_Y3;
    float s = 0.f;
    for (int c = threadIdx.x; c < 1024; c += 256) {
        u16x4 v = rp[c];
        int k0 = c * 4;
        s += bh2f(v[0]) * y3[k0] + bh2f(v[1]) * y3[k0 + 1]
           + bh2f(v[2]) * y3[k0 + 2] + bh2f(v[3]) * y3[k0 + 3];
    }
    s = blockReduceSum256(s);
    if (threadIdx.x == 0) vec[OFF_H3 + i] = fmaxf(s + gc3_b[0], 0.f);
}

__global__ void h3_kernel(const float* __restrict__ adj, const float* __restrict__ gc3_b,
                          float* __restrict__ vec) {
    int i = blockIdx.x;
    const float* r = adj + (size_t)i * 4096;
    const float* y3 = vec + OFF_Y3;
    float s = 0.f;
    for (int k = threadIdx.x; k < 4096; k += 256) s += r[k] * y3[k];
    s = blockReduceSum256(s);
    if (threadIdx.x == 0) vec[OFF_H3 + i] = fmaxf(s + gc3_b[0], 0.f);
}

__global__ void gcn_kernel(const float* __restrict__ gcn512_W, const float* __restrict__ gcn512_b,
                           float* __restrict__ vec) {
    int j = blockIdx.x;
    const float* r = gcn512_W + (size_t)j * 4096;
    const float* h3 = vec + OFF_H3;
    float s = 0.f;
    for (int k = threadIdx.x; k < 4096; k += 256) s += r[k] * h3[k];
    s = blockReduceSum256(s);
    if (threadIdx.x == 0) vec[OFF_GCN + j] = fmaxf(s + gcn512_b[j], 0.f);
}

__global__ void x_kernel(const float* __restrict__ hidden_W, const float* __restrict__ hidden_b,
                         float* __restrict__ vec) {
    int j = blockIdx.x;
    const float* r = hidden_W + (size_t)j * 1536;
    const float* joint = vec;
    float s = 0.f;
    for (int k = threadIdx.x; k < 1536; k += 256) s += r[k] * joint[k];
    s = blockReduceSum256(s);
    if (threadIdx.x == 0) vec[OFF_X + j] = fmaxf(s + hidden_b[j], 0.f);
}

__global__ void out_kernel(const float* __restrict__ vec,
                           const float* __restrict__ critic_W, const float* __restrict__ critic_b,
                           const float* __restrict__ actor_W, const float* __restrict__ actor_b,
                           float* __restrict__ out) {
    const float* xv = vec + OFF_X;
    int w = threadIdx.x >> 6, l = threadIdx.x & 63;
    if (w >= 7) return;
    const float* row = (w == 0) ? critic_W : actor_W + (size_t)(w - 1) * 512;
    float s = 0.f;
    for (int q = l; q < 512; q += 64) s += xv[q] * row[q];
    #pragma unroll
    for (int o = 32; o > 0; o >>= 1) s += __shfl_down(s, o, 64);
    if (l == 0) out[w] = s + ((w == 0) ? critic_b[0] : actor_b[w - 1]);
}

// combine P1 split-K f32 partials (x2) -> hi bf16
__global__ void combine_p1_kernel(const float* __restrict__ p1f,
                                  unsigned short* __restrict__ hi) {
    size_t i = (size_t)blockIdx.x * 256 + threadIdx.x;
    float4 a = ((const float4*)p1f)[i];
    float4 b = ((const float4*)(p1f + 2097152))[i];
    u16x4 hv;
    hv[0] = f2bh(a.x + b.x);
    hv[1] = f2bh(a.y + b.y);
    hv[2] = f2bh(a.z + b.z);
    hv[3] = f2bh(a.w + b.w);
    *(u16x4*)(hi + i * 4) = hv;
}

// ---------------- fused prep kernel: all converts + vec3, ILP-4 streaming ----------------
__global__ void prep_kernel(const float* __restrict__ adj,
                            const float* __restrict__ all_embeds,
                            const float* __restrict__ semantic_W,
                            const float* __restrict__ gc1_W,
                            const float* __restrict__ gc2_W,
                            const float* __restrict__ frames,
                            const float* __restrict__ scores,
                            const float* __restrict__ word_embed,
                            const float* __restrict__ visual_W, const float* __restrict__ visual_b,
                            const float* __restrict__ semantic_b,
                            const float* __restrict__ score_W, const float* __restrict__ score_b,
                            unsigned short* __restrict__ adj_h,
                            unsigned short* __restrict__ emb_h, unsigned short* __restrict__ emb_l,
                            unsigned short* __restrict__ sw_h, unsigned short* __restrict__ sw_l,
                            unsigned short* __restrict__ w1t_h,
                            unsigned short* __restrict__ w2t_h,
                            float* __restrict__ vec) {
    __shared__ float tile[32][33];
    const int b = blockIdx.x, t = threadIdx.x;
    if (b < 4096) {
        size_t base = (size_t)b * 1024 + t;
        float4 v[4];
        #pragma unroll
        for (int j = 0; j < 4; j++) v[j] = ((const float4*)adj)[base + j * 256];
        #pragma unroll
        for (int j = 0; j < 4; j++) {
            u16x4 h;
            h[0] = f2bh(v[j].x); h[1] = f2bh(v[j].y);
            h[2] = f2bh(v[j].z); h[3] = f2bh(v[j].w);
            *(u16x4*)(adj_h + (base + j * 256) * 4) = h;
        }
    } else if (b < 4096 + 1280) {
        size_t base = (size_t)(b - 4096) * 256 + t;
        float v[4];
        #pragma unroll
        for (int j = 0; j < 4; j++) {
            size_t i = base + (size_t)j * 327680;
            int r = (int)(i / 320), c = (int)(i % 320);
            v[j] = (c < 300) ? all_embeds[(size_t)r * 300 + c] : 0.f;
        }
        #pragma unroll
        for (int j = 0; j < 4; j++) {
            size_t i = base + (size_t)j * 327680;
            unsigned short h = f2bh(v[j]);
            emb_h[i] = h; emb_l[i] = f2bh(v[j] - bh2f(h));
        }
    } else if (b < 4096 + 1280 + 160) {
        size_t base = (size_t)(b - 4096 - 1280) * 256 + t;
        float v[4];
        #pragma unroll
        for (int j = 0; j < 4; j++) {
            size_t i = base + (size_t)j * 40960;
            int r = (int)(i / 320), c = (int)(i % 320);
            v[j] = (c < 300) ? semantic_W[(size_t)r * 300 + c] : 0.f;
        }
        #pragma unroll
        for (int j = 0; j < 4; j++) {
            size_t i = base + (size_t)j * 40960;
            unsigned short h = f2bh(v[j]);
            sw_h[i] = h; sw_l[i] = f2bh(v[j] - bh2f(h));
        }
    } else if (b < 4096 + 1280 + 160 + 512) {
        int l2 = b - 4096 - 1280 - 160;
        const float* src = gc1_W + (size_t)512 * 1024;
        int kb = (l2 & 15) * 32, nb = (l2 >> 4) * 32;
        int tx = t & 31, ty = t >> 5;
        #pragma unroll
        for (int i = 0; i < 32; i += 8)
            tile[ty + i][tx] = src[(size_t)(kb + ty + i) * 1024 + nb + tx];
        __syncthreads();
        #pragma unroll
        for (int i = 0; i < 32; i += 8) {
            int n = nb + ty + i, k = kb + tx;
            w1t_h[(size_t)n * 512 + k] = f2bh(tile[tx][ty + i]);
        }
    } else if (b < 4096 + 1280 + 160 + 512 + 1024) {
        int l2 = b - 4096 - 1280 - 160 - 512;
        int kb = (l2 & 31) * 32, nb = (l2 >> 5) * 32;
        int tx = t & 31, ty = t >> 5;
        #pragma unroll
        for (int i = 0; i < 32; i += 8)
            tile[ty + i][tx] = gc2_W[(size_t)(kb + ty + i) * 1024 + nb + tx];
        __syncthreads();
        #pragma unroll
        for (int i = 0; i < 32; i += 8) {
            int n = nb + ty + i, k = kb + tx;
            w2t_h[(size_t)n * 1024 + k] = f2bh(tile[tx][ty + i]);
        }
    } else {
        vec3_body(b - (4096 + 1280 + 160 + 512 + 1024), frames, scores, word_embed,
                  visual_W, visual_b, semantic_W, semantic_b, score_W, score_b, vec);
    }
}

// ---------------- staging helpers ----------------
template<int NCHP, int NJ>
__device__ __forceinline__ void stg_mat(const unsigned short* __restrict__ src, int ld, int r0,
                                        int k0, unsigned short* dst, int t) {
    #pragma unroll
    for (int j = 0; j < NJ; j++) {
        int c = j * 256 + t;
        int p = c / NCHP;
        int idx = c % NCHP;
        int row = idx >> 2;
        int gg = (idx & 3) ^ ((row >> 1) & 3);
        gload16(src + (size_t)(r0 + row) * ld + (k0 + p * 32 + gg * 8),
                dst + (size_t)(j * 256 + (t & ~63)) * 8);
    }
}

template<int ROWS>
__device__ __forceinline__ s16x8 rfrag(const unsigned short* rb, int row, int p, int g4) {
    int byte = (p * ROWS + row) * 64 + ((g4 ^ ((row >> 1) & 3)) << 4);
    return *(const s16x8*)((const char*)rb + byte);
}

// ---------------- 4-wave MFMA GEMM — SINGLE-BARRIER 2-phase recipe (T3 minimum) ----------
// Per step: {issue STAGE(next)} {ds_read cur + MFMA} {vmcnt(0)} {barrier}.
// C[M,N] = A[M,K] @ B^T ; tile BM x 64, wave (BM/2) x 32.
// PROD: 1 = Ah*Bh ; 3 = +Ah*Bl +Al*Bh
// WMODE: 3 hi C[m][n]; 4 hi C^T[n][m] (ldc=M); 6 f32 C[m][n]
template<int BM, int BK, int PROD, int WMODE, int RELU, int SPLITK>
__global__ __launch_bounds__(256) void mfma_g(
    const unsigned short* __restrict__ Ah, const unsigned short* __restrict__ Al,
    const unsigned short* __restrict__ Bh, const unsigned short* __restrict__ Bl,
    int K, int lda, int ldb,
    unsigned short* __restrict__ Ch, float* __restrict__ Cf, int ldc,
    const float* __restrict__ bias, const float* __restrict__ bias2)
{
    constexpr int A_USH = BM * BK;
    constexpr int B_USH = 64 * BK;
    constexpr int A_CH  = A_USH / 8;
    constexpr int B_CH  = B_USH / 8;
    constexpr int SLOT  = (PROD == 3) ? 2 * (A_USH + B_USH) : (A_USH + B_USH);
    constexpr int FM    = BM / 32;
    __shared__ unsigned short lds[2 * SLOT];

    const int t = threadIdx.x;
    const int w = t >> 6, l = t & 63;
    const int r = l & 15, g4 = l >> 4;
    const int wr = (w >> 1) * (BM / 2);
    const int wc = (w & 1) * 32;

    const int gx = gridDim.x;
    const int nwg = gx * gridDim.y;
    int flat = blockIdx.y * gx + blockIdx.x;
    int swz = (flat & 7) * (nwg >> 3) + (flat >> 3);
    const int col0 = (swz % gx) * 64;
    const int row0 = (swz / gx) * BM;

    if constexpr (SPLITK) {
        int z = blockIdx.z;
        Ah += (size_t)z * K;
        Bh += (size_t)z * K;
        if (Cf) Cf += (size_t)z * (size_t)nwg * (BM * 64);
        if (Ch) Ch += (size_t)z * (size_t)nwg * (BM * 64);
    }

    f32x4 acc[FM][2];
    #pragma unroll
    for (int a = 0; a < FM; a++)
        #pragma unroll
        for (int b = 0; b < 2; b++) acc[a][b] = (f32x4){0.f, 0.f, 0.f, 0.f};

    auto stage = [&](int slot, int k0) {
        unsigned short* base = lds + slot * SLOT;
        stg_mat<BM * 4, A_CH / 256>(Ah, lda, row0, k0, base, t);
        stg_mat<256,    B_CH / 256>(Bh, ldb, col0, k0, base + A_USH, t);
        if constexpr (PROD == 3) {
            stg_mat<256,    B_CH / 256>(Bl, ldb, col0, k0, base + A_USH + B_USH, t);
            stg_mat<BM * 4, A_CH / 256>(Al, lda, row0, k0, base + A_USH + 2 * B_USH, t);
        }
    };

    const int T = K / BK;
    stage(0, 0);
    asm volatile("s_waitcnt vmcnt(0)" ::: "memory");
    __builtin_amdgcn_s_barrier();

    for (int tt = 0; tt < T; ++tt) {
        if (tt + 1 < T) stage((tt + 1) & 1, (tt + 1) * BK);   // overlap with compute

        const unsigned short* base = lds + (tt & 1) * SLOT;
        #pragma unroll
        for (int kk = 0; kk < BK / 32; kk++) {
            s16x8 a[FM], bb[2], alr[FM], blr[2];
            #pragma unroll
            for (int f = 0; f < FM; f++) a[f] = rfrag<BM>(base, wr + f * 16 + r, kk, g4);
            #pragma unroll
            for (int f = 0; f < 2; f++) bb[f] = rfrag<64>(base + A_USH, wc + f * 16 + r, kk, g4);
            if constexpr (PROD == 3) {
                #pragma unroll
                for (int f = 0; f < 2; f++) blr[f] = rfrag<64>(base + A_USH + B_USH, wc + f * 16 + r, kk, g4);
                #pragma unroll
                for (int f = 0; f < FM; f++) alr[f] = rfrag<BM>(base + A_USH + 2 * B_USH, wr + f * 16 + r, kk, g4);
            }
            __builtin_amdgcn_s_setprio(1);
            #pragma unroll
            for (int fm = 0; fm < FM; fm++)
                #pragma unroll
                for (int fn = 0; fn < 2; fn++) {
                    acc[fm][fn] = MF(a[fm], bb[fn], acc[fm][fn]);
                    if constexpr (PROD == 3) {
                        acc[fm][fn] = MF(a[fm], blr[fn], acc[fm][fn]);
                        acc[fm][fn] = MF(alr[fm], bb[fn], acc[fm][fn]);
                    }
                }
            __builtin_amdgcn_s_setprio(0);
        }
        if (tt + 1 < T) {
            asm volatile("s_waitcnt vmcnt(0)" ::: "memory");  // next tile landed
            __builtin_amdgcn_s_barrier();
        }
    }

    // epilogue (C/D: col = lane&15, row = 4*(lane>>4)+i — m89-verified)
    #pragma unroll
    for (int fn = 0; fn < 2; fn++) {
        int n = col0 + wc + fn * 16 + r;
        float bn = bias ? bias[n] : 0.f;
        if (bias2) bn += bias2[n];
        #pragma unroll
        for (int fm = 0; fm < FM; fm++) {
            int m0 = row0 + wr + fm * 16 + g4 * 4;
            f32x4 v = acc[fm][fn];
            if constexpr (WMODE == 4) {
                u16x4 hv;
                #pragma unroll
                for (int i = 0; i < 4; i++) {
                    float x = v[i] + bn;
                    if (RELU) x = fmaxf(x, 0.f);
                    hv[i] = f2bh(x);
                }
                *(u16x4*)(Ch + (size_t)n * ldc + m0) = hv;
            } else if constexpr (WMODE == 6) {
                #pragma unroll
                for (int i = 0; i < 4; i++) {
                    float x = v[i] + bn;
                    if (RELU) x = fmaxf(x, 0.f);
                    Cf[(size_t)(m0 + i) * ldc + n] = x;
                }
            } else {  // WMODE 3: hi bf16 C[m][n]
                #pragma unroll
                for (int i = 0; i < 4; i++) {
                    float x = v[i] + bn;
                    if (RELU) x = fmaxf(x, 0.f);
                    Ch[(size_t)(m0 + i) * ldc + n] = f2bh(x);
                }
            }
        }
    }
}

// ---------------- SQUARE-tile GEMM 128x128, wave 64x64, BK=32 — single-barrier recipe ----
// bf16 partials: Ch[z*4096*1024 + m*ldc + n]. LDS 32 KB; grid 1024 = 4 blocks/CU.
__global__ __launch_bounds__(256) void mfma_sq(
    const unsigned short* __restrict__ Ah,
    const unsigned short* __restrict__ Bh,
    int Kc, int lda, int ldb,
    unsigned short* __restrict__ Ch, int ldc)
{
    constexpr int A_USH = 128 * 32;           // 4096 ush
    constexpr int SLOT  = 2 * A_USH;          // 8192 ush = 16 KB
    __shared__ unsigned short lds[2 * SLOT];  // 32 KB

    const int t = threadIdx.x;
    const int w = t >> 6, l = t & 63;
    const int r = l & 15, g4 = l >> 4;
    const int wr = (w >> 1) * 64, wc = (w & 1) * 64;

    const int gx = gridDim.x;
    const int nwg = gx * gridDim.y;
    int flat = blockIdx.y * gx + blockIdx.x;
    int swz = (flat & 7) * (nwg >> 3) + (flat >> 3);
    const int col0 = (swz % gx) * 128;
    const int row0 = (swz / gx) * 128;

    const int z = blockIdx.z;
    Ah += (size_t)z * Kc;
    Bh += (size_t)z * Kc;
    Ch += (size_t)z * 4194304;

    f32x4 acc[4][4];
    #pragma unroll
    for (int a = 0; a < 4; a++)
        #pragma unroll
        for (int b = 0; b < 4; b++) acc[a][b] = (f32x4){0.f, 0.f, 0.f, 0.f};

    auto stage = [&](int slot, int k0) {
        unsigned short* base = lds + slot * SLOT;
        stg_mat<512, 2>(Ah, lda, row0, k0, base, t);
        stg_mat<512, 2>(Bh, ldb, col0, k0, base + A_USH, t);
    };

    const int T = Kc >> 5;
    stage(0, 0);
    asm volatile("s_waitcnt vmcnt(0)" ::: "memory");
    __builtin_amdgcn_s_barrier();

    for (int tt = 0; tt < T; ++tt) {
        if (tt + 1 < T) stage((tt + 1) & 1, (tt + 1) * 32);   // overlap with compute

        const unsigned short* base = lds + (tt & 1) * SLOT;
        s16x8 a[4], bb[4];
        #pragma unroll
        for (int f = 0; f < 4; f++) a[f] = rfrag<128>(base, wr + f * 16 + r, 0, g4);
        #pragma unroll
        for (int f = 0; f < 4; f++) bb[f] = rfrag<128>(base + A_USH, wc + f * 16 + r, 0, g4);
        __builtin_amdgcn_s_setprio(1);
        #pragma unroll
        for (int fm = 0; fm < 4; fm++)
            #pragma unroll
            for (int fn = 0; fn < 4; fn++)
                acc[fm][fn] = MF(a[fm], bb[fn], acc[fm][fn]);
        __builtin_amdgcn_s_setprio(0);

        if (tt + 1 < T) {
            asm volatile("s_waitcnt vmcnt(0)" ::: "memory");
            __builtin_amdgcn_s_barrier();
        }
    }

    // epilogue: bf16 partials (C/D: col = lane&15, row = 4*(lane>>4)+i)
    #pragma unroll
    for (int fn = 0; fn < 4; fn++) {
        int n = col0 + wc + fn * 16 + r;
        #pragma unroll
        for (int fm = 0; fm < 4; fm++) {
            int m0 = row0 + wr + fm * 16 + g4 * 4;
            f32x4 v = acc[fm][fn];
            #pragma unroll
            for (int i = 0; i < 4; i++)
                Ch[(size_t)(m0 + i) * ldc + n] = f2bh(v[i]);
        }
    }
}

// ---------------- fallback f32 tiled GEMM (round-1, proven) ----------------
template<int TRANSB>
__global__ __launch_bounds__(256) void gemm_f32_128(
    const float* __restrict__ A, const float* __restrict__ B, float* __restrict__ C,
    int M, int N, int K, int lda, int ldb,
    const float* __restrict__ bias, const float* __restrict__ vrow, int do_relu)
{
    constexpr int BM = 128, BN = 128, BK = 16;
    __shared__ float As[BK][BM + 4];
    __shared__ float Bs[BK][BN + 4];
    const int t = threadIdx.x;
    const int w = t >> 6, l = t & 63;
    const int cx = (w & 1) * 8 + (l & 7);
    const int cy = (w >> 1) * 8 + (l >> 3);
    const int row0 = blockIdx.y * BM;
    const int col0 = blockIdx.x * BN;

    float acc[8][8];
    #pragma unroll
    for (int i = 0; i < 8; i++)
        #pragma unroll
        for (int j = 0; j < 8; j++) acc[i][j] = 0.f;

    const int ka = t & 15;
    const int ma = t >> 4;

    for (int k0 = 0; k0 < K; k0 += BK) {
        #pragma unroll
        for (int i = 0; i < 8; i++) {
            int m = ma + i * 16;
            int gk = k0 + ka;
            float v = 0.f;
            if (gk < K) v = A[(size_t)(row0 + m) * lda + gk];
            As[ka][m] = v;
        }
        if (TRANSB) {
            #pragma unroll
            for (int i = 0; i < 8; i++) {
                int n = ma + i * 16;
                int gk = k0 + ka;
                float v = 0.f;
                if (gk < K) v = B[(size_t)(col0 + n) * ldb + gk];
                Bs[ka][n] = v;
            }
        } else {
            const int nb = t & 127;
            const int kb = t >> 7;
            #pragma unroll
            for (int i = 0; i < 8; i++) {
                int kk = kb + i * 2;
                int gk = k0 + kk;
                float v = 0.f;
                if (gk < K) v = B[(size_t)gk * ldb + col0 + nb];
                Bs[kk][nb] = v;
            }
        }
        __syncthreads();
        #pragma unroll
        for (int kk = 0; kk < BK; kk++) {
            float a[8], bb[8];
            *(float4*)&a[0]  = *(const float4*)&As[kk][cy * 8];
            *(float4*)&a[4]  = *(const float4*)&As[kk][cy * 8 + 4];
            *(float4*)&bb[0] = *(const float4*)&Bs[kk][cx * 8];
            *(float4*)&bb[4] = *(const float4*)&Bs[kk][cx * 8 + 4];
            #pragma unroll
            for (int i = 0; i < 8; i++)
                #pragma unroll
                for (int j = 0; j < 8; j++)
                    acc[i][j] = fmaf(a[i], bb[j], acc[i][j]);
        }
        __syncthreads();
    }

    #pragma unroll
    for (int i = 0; i < 8; i++) {
        int rr = row0 + cy * 8 + i;
        float vv[8];
        #pragma unroll
        for (int j = 0; j < 8; j++) {
            int c = col0 + cx * 8 + j;
            float v = acc[i][j];
            if (vrow) v += vrow[c];
            if (bias) v += bias[c];
            if (do_relu) v = fmaxf(v, 0.f);
            vv[j] = v;
        }
        float* cp = C + (size_t)rr * N + col0 + cx * 8;
        *(float4*)cp       = *(float4*)&vv[0];
        *(float4*)(cp + 4) = *(float4*)&vv[4];
    }
}

// ---------------- host launcher ----------------
extern "C" void kernel_launch(void* const* d_in, const int* in_sizes, int n_in,
                              void* d_out, int out_size, void* d_ws, size_t ws_size,
                              hipStream_t stream) {
    const float* frames     = (const float*)d_in[0];
    const float* scores     = (const float*)d_in[1];
    const float* word_embed = (const float*)d_in[2];
    const float* all_embeds = (const float*)d_in[3];
    const float* adj        = (const float*)d_in[4];
    const float* visual_W   = (const float*)d_in[5];
    const float* visual_b   = (const float*)d_in[6];
    const float* semantic_W = (const float*)d_in[7];
    const float* semantic_b = (const float*)d_in[8];
    const float* score_W    = (const float*)d_in[9];
    const float* score_b    = (const float*)d_in[10];
    const float* gc1_W      = (const float*)d_in[11];
    const float* gc1_b      = (const float*)d_in[12];
    const float* gc2_W      = (const float*)d_in[13];
    const float* gc2_b      = (const float*)d_in[14];
    const float* gc3_W      = (const float*)d_in[15];
    const float* gc3_b      = (const float*)d_in[16];
    const float* gcn512_W   = (const float*)d_in[17];
    const float* gcn512_b   = (const float*)d_in[18];
    const float* hidden_W   = (const float*)d_in[19];
    const float* hidden_b   = (const float*)d_in[20];
    const float* critic_W   = (const float*)d_in[21];
    const float* critic_b   = (const float*)d_in[22];
    const float* actor_W    = (const float*)d_in[23];
    const float* actor_b    = (const float*)d_in[24];

    float* out = (float*)d_out;

    if (ws_size >= FAST_WS) {
        char* wsb = (char*)d_ws;
        unsigned short* adj_h = (unsigned short*)(wsb + F_ADJH);
        unsigned short* emb_h = (unsigned short*)(wsb + F_EMB_H);
        unsigned short* emb_l = (unsigned short*)(wsb + F_EMB_L);
        unsigned short* sw_h  = (unsigned short*)(wsb + F_SW_H);
        unsigned short* sw_l  = (unsigned short*)(wsb + F_SW_L);
        unsigned short* w1t_h = (unsigned short*)(wsb + F_W1T_H);
        unsigned short* w2t_h = (unsigned short*)(wsb + F_W2T_H);
        unsigned short* emT   = (unsigned short*)(wsb + F_EMT);
        float*          p1f   = (float*)(wsb + F_P1F);
        unsigned short* p1_h  = (unsigned short*)(wsb + F_P1H);
        unsigned short* h1    = (unsigned short*)(wsb + F_H1);
        unsigned short* y2t   = (unsigned short*)(wsb + F_Y2T);
        unsigned short* p7h   = (unsigned short*)(wsb + F_P7H);
        float*          vec   = (float*)(wsb + F_VEC);

        // 1. prep: all converts + vec3 (ILP-4 streaming)
        prep_kernel<<<4096 + 1280 + 160 + 512 + 1024 + 1536, 256, 0, stream>>>(
            adj, all_embeds, semantic_W, gc1_W, gc2_W,
            frames, scores, word_embed, visual_W, visual_b, semantic_b, score_W, score_b,
            adj_h, emb_h, emb_l, sw_h, sw_l, w1t_h, w2t_h, vec);
        // 2. vrow = s512 @ gc1_W[:512,:]
        vrow_kernel<<<8, 256, 0, stream>>>(gc1_W, vec);
        // 3. emT = relu(all_embeds @ semantic_W^T + b)^T  hi [512,4096], K=320, PROD=3
        mfma_g<64, 32, 3, 4, 1, 0><<<dim3(8, 64), 256, 0, stream>>>(
            emb_h, emb_l, sw_h, sw_l, 320, 320, 320,
            emT, nullptr, 4096, semantic_b, nullptr);
        // 4. P1 partials = adj @ em  f32, split-K x2  [4096,512]
        mfma_g<128, 64, 1, 6, 0, 1><<<dim3(8, 32, 2), 256, 0, stream>>>(
            adj_h, nullptr, emT, nullptr, 2048, 4096, 4096,
            nullptr, p1f, 512, nullptr, nullptr);
        // 4b. combine f32 partials -> p1 hi
        combine_p1_kernel<<<2048, 256, 0, stream>>>(p1f, p1_h);
        // 5. h1 = relu(P1_hi @ W1'_hi + vrow + b1)  hi [4096,1024], K=512, PROD=1
        mfma_g<128, 64, 1, 3, 1, 0><<<dim3(16, 32), 256, 0, stream>>>(
            p1_h, nullptr, w1t_h, nullptr, 512, 512, 512,
            h1, nullptr, 1024, gc1_b, vec + OFF_VROW);
        // 6. y2t = (h1 @ gc2_W)^T  hi [1024,4096], K=1024
        mfma_g<128, 64, 1, 4, 0, 0><<<dim3(16, 32), 256, 0, stream>>>(
            h1, nullptr, w2t_h, nullptr, 1024, 1024, 1024,
            y2t, nullptr, 4096, nullptr, nullptr);
        // 7. p7h partials = adj @ Y2  bf16, square tiles, split-K x4  [4096,1024]
        mfma_sq<<<dim3(8, 32, 4), 256, 0, stream>>>(
            adj_h, y2t, 1024, 4096, 4096, p7h, 1024);
        // 7b. y3[i] = sum_j relu(sum_z p7h + b2)[i,j] * gc3_W[j]
        h2y3_kernel<<<4096, 256, 0, stream>>>(p7h, gc2_b, gc3_W, vec);
        // 8-11. tail
        h3b_kernel<<<4096, 256, 0, stream>>>(adj_h, gc3_b, vec);
        gcn_kernel<<<512, 256, 0, stream>>>(gcn512_W, gcn512_b, vec);
        x_kernel<<<512, 256, 0, stream>>>(hidden_W, hidden_b, vec);
        out_kernel<<<1, 512, 0, stream>>>(vec, critic_W, critic_b, actor_W, actor_b, out);
    } else {
        // fallback f32 path (round-1, proven within 50.4 MB)
        float* ws = (float*)d_ws;
        float* em = ws + OFF_BUF0;
        float* Y1 = ws + OFF_BUF1;
        float* H1 = ws + OFF_BUF2;
        float* Y2 = ws + OFF_BUF1;
        float* H2 = ws + OFF_BUF0;

        vec3_kernel<<<1536, 256, 0, stream>>>(frames, scores, word_embed,
                                              visual_W, visual_b, semantic_W, semantic_b,
                                              score_W, score_b, ws);
        vrow_kernel<<<8, 256, 0, stream>>>(gc1_W, ws);
        gemm_f32_128<1><<<dim3(512 / 128, 4096 / 128), 256, 0, stream>>>(
            all_embeds, semantic_W, em, 4096, 512, 300, 300, 300, semantic_b, nullptr, 1);
        gemm_f32_128<0><<<dim3(1024 / 128, 4096 / 128), 256, 0, stream>>>(
            em, gc1_W + (size_t)512 * 1024, Y1, 4096, 1024, 512, 512, 1024,
            nullptr, ws + OFF_VROW, 0);
        gemm_f32_128<0><<<dim3(1024 / 128, 4096 / 128), 256, 0, stream>>>(
            adj, Y1, H1, 4096, 1024, 4096, 4096, 1024, gc1_b, nullptr, 1);
        gemm_f32_128<0><<<dim3(1024 / 128, 4096 / 128), 256, 0, stream>>>(
            H1, gc2_W, Y2, 4096, 1024, 1024, 1024, 1024, nullptr, nullptr, 0);
        gemm_f32_128<0><<<dim3(1024 / 128, 4096 / 128), 256, 0, stream>>>(
            adj, Y2, H2, 4096, 1024, 4096, 4096, 1024, gc2_b, nullptr, 1);
        y3_kernel<<<4096, 256, 0, stream>>>(H2, gc3_W, ws);
        h3_kernel<<<4096, 256, 0, stream>>>(adj, gc3_b, ws);
        gcn_kernel<<<512, 256, 0, stream>>>(gcn512_W, gcn512_b, ws);
        x_kernel<<<512, 256, 0, stream>>>(hidden_W, hidden_b, ws);
        out_kernel<<<1, 512, 0, stream>>>(ws, critic_W, critic_b, actor_W, actor_b, out);
    }

    (void)in_sizes; (void)n_in; (void)out_size;
}

// Round 12
// 180.597 us; speedup vs baseline: 1.0596x; 1.0547x over previous
//
#include <hip/hip_runtime.h>
#include <cstddef>
#include <cstdint>

typedef short  s16x8 __attribute__((ext_vector_type(8)));
typedef float  f32x4 __attribute__((ext_vector_type(4)));
typedef unsigned short u16x4 __attribute__((ext_vector_type(4)));

typedef __attribute__((address_space(1))) const void gas_void;
typedef __attribute__((address_space(3))) void las_void;

// ---------------- bf16 helpers ----------------
__device__ __forceinline__ unsigned short f2bh(float x) {
    union { float f; unsigned int u; } c; c.f = x;
    unsigned int r = c.u + 0x7fffu + ((c.u >> 16) & 1u);
    return (unsigned short)(r >> 16);
}
__device__ __forceinline__ float bh2f(unsigned short h) {
    union { unsigned int u; float f; } c; c.u = ((unsigned int)h) << 16;
    return c.f;
}
__device__ __forceinline__ f32x4 MF(s16x8 a, s16x8 b, f32x4 c) {
    return __builtin_amdgcn_mfma_f32_16x16x32_bf16(a, b, c, 0, 0, 0);
}
__device__ __forceinline__ void gload16(const unsigned short* g, unsigned short* l) {
    __builtin_amdgcn_global_load_lds((gas_void*)g, (las_void*)l, 16, 0, 0);
}

// ---------------- vec region offsets (floats) ----------------
static constexpr size_t OFF_VIS  = 0;
static constexpr size_t OFF_SEM  = 512;
static constexpr size_t OFF_GCN  = 1024;
static constexpr size_t OFF_S512 = 1536;
static constexpr size_t OFF_VROW = 2048;
static constexpr size_t OFF_X    = 3072;
static constexpr size_t OFF_Y3   = 4096;
static constexpr size_t OFF_H3   = 8192;
// fallback big buffers (floats, absolute in ws)
static constexpr size_t OFF_BUF0 = 16384;
static constexpr size_t OFF_BUF1 = OFF_BUF0 + 4194304;
static constexpr size_t OFF_BUF2 = OFF_BUF1 + 4194304;

// ---------------- fast-path ws layout (bytes) ----------------
static constexpr size_t F_ADJH  = 0;                          // 33,554,432
static constexpr size_t F_SCR   = 33554432;                   // 33,554,432 scratch
static constexpr size_t F_EMB_H = F_SCR;                      // 2,621,440
static constexpr size_t F_EMB_L = F_SCR + 2621440;            // 2,621,440
static constexpr size_t F_SW_H  = F_SCR + 5242880;            // 327,680
static constexpr size_t F_SW_L  = F_SCR + 5570560;            // 327,680
static constexpr size_t F_W1T_H = F_SCR + 5898240;            // 1,048,576
static constexpr size_t F_W2T_H = F_SCR + 6946816;            // 2,097,152
static constexpr size_t F_EMT   = F_SCR + 9043968;            // 4,194,304
static constexpr size_t F_P1F   = F_SCR + 16777216;           // 16,777,216 (#4 f32 partials x2)
static constexpr size_t F_H1    = F_SCR + 16777216;           // 8,388,608 (after p1f dead)
static constexpr size_t F_P7F   = F_SCR;                      // 33,554,432 (#7 f32 partials x2)
static constexpr size_t F_P1H   = 67108864;                   // 4,194,304
static constexpr size_t F_Y2T   = 71303168;                   // 8,388,608
static constexpr size_t F_VEC   = 79691776;                   // 49,152
static constexpr size_t FAST_WS = 79740928;                   // ~76.0 MB

// ---------------- block reduction ----------------
__device__ inline float blockReduceSum256(float v) {
    #pragma unroll
    for (int o = 32; o > 0; o >>= 1) v += __shfl_down(v, o, 64);
    __shared__ float red[4];
    int w = threadIdx.x >> 6;
    if ((threadIdx.x & 63) == 0) red[w] = v;
    __syncthreads();
    if (threadIdx.x == 0) v = red[0] + red[1] + red[2] + red[3];
    return v;
}

// ---------------- vec3 body (visual branch float4-vectorized) ----------------
__device__ __forceinline__ void vec3_body(int b,
                            const float* __restrict__ frames,
                            const float* __restrict__ scores,
                            const float* __restrict__ word_embed,
                            const float* __restrict__ visual_W, const float* __restrict__ visual_b,
                            const float* __restrict__ semantic_W, const float* __restrict__ semantic_b,
                            const float* __restrict__ score_W, const float* __restrict__ score_b,
                            float* __restrict__ vec) {
    if (b < 512) {
        int row = b;
        const float4* w4 = (const float4*)(visual_W + (size_t)row * 8192);
        const float4* x4 = (const float4*)frames;
        float s = 0.f;
        #pragma unroll
        for (int c0 = 0; c0 < 2048; c0 += 256) {
            int c = c0 + threadIdx.x;
            float4 wv = w4[c], xv = x4[c];
            s += wv.x * xv.x + wv.y * xv.y + wv.z * xv.z + wv.w * xv.w;
        }
        s = blockReduceSum256(s);
        if (threadIdx.x == 0) (vec + OFF_VIS)[row] = fmaxf(s + visual_b[row], 0.f);
        return;
    }
    const float* x; const float* W; const float* bias; float* out; int K; int row;
    if (b < 1024) { row = b - 512;  x = word_embed; W = semantic_W; bias = semantic_b; out = vec + OFF_SEM;  K = 300;  }
    else          { row = b - 1024; x = scores;     W = score_W;    bias = score_b;    out = vec + OFF_S512; K = 1000; }
    const float* wr = W + (size_t)row * K;
    float s = 0.f;
    for (int k = threadIdx.x; k < K; k += 256) s += wr[k] * x[k];
    s = blockReduceSum256(s);
    if (threadIdx.x == 0) out[row] = fmaxf(s + bias[row], 0.f);
}

// ---------------- small kernels ----------------
__global__ void vec3_kernel(const float* __restrict__ frames,
                            const float* __restrict__ scores,
                            const float* __restrict__ word_embed,
                            const float* __restrict__ visual_W, const float* __restrict__ visual_b,
                            const float* __restrict__ semantic_W, const float* __restrict__ semantic_b,
                            const float* __restrict__ score_W, const float* __restrict__ score_b,
                            float* __restrict__ vec) {
    vec3_body(blockIdx.x, frames, scores, word_embed, visual_W, visual_b,
              semantic_W, semantic_b, score_W, score_b, vec);
}

__global__ void vrow_kernel(const float* __restrict__ gc1_W, float* __restrict__ vec) {
    __shared__ float part[128];
    const float* s512 = vec + OFF_S512;
    int jl = threadIdx.x & 127;
    int j = blockIdx.x * 128 + jl;
    int kh = threadIdx.x >> 7;
    float s = 0.f;
    #pragma unroll 4
    for (int k = kh * 256; k < kh * 256 + 256; k++)
        s += s512[k] * gc1_W[(size_t)k * 1024 + j];
    if (kh) part[jl] = s;
    __syncthreads();
    if (!kh) vec[OFF_VROW + j] = s + part[jl];
}

__global__ void y3_kernel(const float* __restrict__ H2, const float* __restrict__ gc3_W,
                          float* __restrict__ vec) {
    int i = blockIdx.x;
    const float* r = H2 + (size_t)i * 1024;
    float s = 0.f;
    for (int k = threadIdx.x; k < 1024; k += 256) s += r[k] * gc3_W[k];
    s = blockReduceSum256(s);
    if (threadIdx.x == 0) vec[OFF_Y3 + i] = s;
}

// fused: y3[i] = sum_j relu(p7f0[i,j] + p7f1[i,j] + gc2_b[j]) * gc3_W[j]
__global__ void h2y3_kernel(const float* __restrict__ p7f, const float* __restrict__ gc2_b,
                            const float* __restrict__ gc3_W, float* __restrict__ vec) {
    int i = blockIdx.x;
    const float4* r0 = (const float4*)(p7f + (size_t)i * 1024);
    const float4* r1 = (const float4*)(p7f + 4194304 + (size_t)i * 1024);
    const float4* b4 = (const float4*)gc2_b;
    const float4* w4 = (const float4*)gc3_W;
    int c = threadIdx.x;   // 256 threads x float4 = 1024
    float4 a = r0[c], b = r1[c], bb = b4[c], ww = w4[c];
    float s = fmaxf(a.x + b.x + bb.x, 0.f) * ww.x
            + fmaxf(a.y + b.y + bb.y, 0.f) * ww.y
            + fmaxf(a.z + b.z + bb.z, 0.f) * ww.z
            + fmaxf(a.w + b.w + bb.w, 0.f) * ww.w;
    s = blockReduceSum256(s);
    if (threadIdx.x == 0) vec[OFF_Y3 + i] = s;
}

// h3 from bf16 adj
__global__ void h3b_kernel(const unsigned short* __restrict__ adj_h,
                           const float* __restrict__ gc3_b, float* __restrict__ vec) {
    int i = blockIdx.x;
    const u16x4* rp = (const u16x4*)(adj_h + (size_t)i * 4096);
    const float* y3 = vec + OFF_Y3;
    float s = 0.f;
    for (int c = threadIdx.x; c < 1024; c += 256) {
        u16x4 v = rp[c];
        int k0 = c * 4;
        s += bh2f(v[0]) * y3[k0] + bh2f(v[1]) * y3[k0 + 1]
           + bh2f(v[2]) * y3[k0 + 2] + bh2f(v[3]) * y3[k0 + 3];
    }
    s = blockReduceSum256(s);
    if (threadIdx.x == 0) vec[OFF_H3 + i] = fmaxf(s + gc3_b[0], 0.f);
}

__global__ void h3_kernel(const float* __restrict__ adj, const float* __restrict__ gc3_b,
                          float* __restrict__ vec) {
    int i = blockIdx.x;
    const float* r = adj + (size_t)i * 4096;
    const float* y3 = vec + OFF_Y3;
    float s = 0.f;
    for (int k = threadIdx.x; k < 4096; k += 256) s += r[k] * y3[k];
    s = blockReduceSum256(s);
    if (threadIdx.x == 0) vec[OFF_H3 + i] = fmaxf(s + gc3_b[0], 0.f);
}

__global__ void gcn_kernel(const float* __restrict__ gcn512_W, const float* __restrict__ gcn512_b,
                           float* __restrict__ vec) {
    int j = blockIdx.x;
    const float* r = gcn512_W + (size_t)j * 4096;
    const float* h3 = vec + OFF_H3;
    float s = 0.f;
    for (int k = threadIdx.x; k < 4096; k += 256) s += r[k] * h3[k];
    s = blockReduceSum256(s);
    if (threadIdx.x == 0) vec[OFF_GCN + j] = fmaxf(s + gcn512_b[j], 0.f);
}

__global__ void x_kernel(const float* __restrict__ hidden_W, const float* __restrict__ hidden_b,
                         float* __restrict__ vec) {
    int j = blockIdx.x;
    const float* r = hidden_W + (size_t)j * 1536;
    const float* joint = vec;
    float s = 0.f;
    for (int k = threadIdx.x; k < 1536; k += 256) s += r[k] * joint[k];
    s = blockReduceSum256(s);
    if (threadIdx.x == 0) vec[OFF_X + j] = fmaxf(s + hidden_b[j], 0.f);
}

__global__ void out_kernel(const float* __restrict__ vec,
                           const float* __restrict__ critic_W, const float* __restrict__ critic_b,
                           const float* __restrict__ actor_W, const float* __restrict__ actor_b,
                           float* __restrict__ out) {
    const float* xv = vec + OFF_X;
    int w = threadIdx.x >> 6, l = threadIdx.x & 63;
    if (w >= 7) return;
    const float* row = (w == 0) ? critic_W : actor_W + (size_t)(w - 1) * 512;
    float s = 0.f;
    for (int q = l; q < 512; q += 64) s += xv[q] * row[q];
    #pragma unroll
    for (int o = 32; o > 0; o >>= 1) s += __shfl_down(s, o, 64);
    if (l == 0) out[w] = s + ((w == 0) ? critic_b[0] : actor_b[w - 1]);
}

// combine P1 split-K f32 partials (x2) -> hi bf16
__global__ void combine_p1_kernel(const float* __restrict__ p1f,
                                  unsigned short* __restrict__ hi) {
    size_t i = (size_t)blockIdx.x * 256 + threadIdx.x;
    float4 a = ((const float4*)p1f)[i];
    float4 b = ((const float4*)(p1f + 2097152))[i];
    u16x4 hv;
    hv[0] = f2bh(a.x + b.x);
    hv[1] = f2bh(a.y + b.y);
    hv[2] = f2bh(a.z + b.z);
    hv[3] = f2bh(a.w + b.w);
    *(u16x4*)(hi + i * 4) = hv;
}

// ---------------- fused prep kernel: all converts + vec3, ILP-4 streaming ----------------
__global__ void prep_kernel(const float* __restrict__ adj,
                            const float* __restrict__ all_embeds,
                            const float* __restrict__ semantic_W,
                            const float* __restrict__ gc1_W,
                            const float* __restrict__ gc2_W,
                            const float* __restrict__ frames,
                            const float* __restrict__ scores,
                            const float* __restrict__ word_embed,
                            const float* __restrict__ visual_W, const float* __restrict__ visual_b,
                            const float* __restrict__ semantic_b,
                            const float* __restrict__ score_W, const float* __restrict__ score_b,
                            unsigned short* __restrict__ adj_h,
                            unsigned short* __restrict__ emb_h, unsigned short* __restrict__ emb_l,
                            unsigned short* __restrict__ sw_h, unsigned short* __restrict__ sw_l,
                            unsigned short* __restrict__ w1t_h,
                            unsigned short* __restrict__ w2t_h,
                            float* __restrict__ vec) {
    __shared__ float tile[32][33];
    const int b = blockIdx.x, t = threadIdx.x;
    if (b < 4096) {
        size_t base = (size_t)b * 1024 + t;
        float4 v[4];
        #pragma unroll
        for (int j = 0; j < 4; j++) v[j] = ((const float4*)adj)[base + j * 256];
        #pragma unroll
        for (int j = 0; j < 4; j++) {
            u16x4 h;
            h[0] = f2bh(v[j].x); h[1] = f2bh(v[j].y);
            h[2] = f2bh(v[j].z); h[3] = f2bh(v[j].w);
            *(u16x4*)(adj_h + (base + j * 256) * 4) = h;
        }
    } else if (b < 4096 + 1280) {
        size_t base = (size_t)(b - 4096) * 256 + t;
        float v[4];
        #pragma unroll
        for (int j = 0; j < 4; j++) {
            size_t i = base + (size_t)j * 327680;
            int r = (int)(i / 320), c = (int)(i % 320);
            v[j] = (c < 300) ? all_embeds[(size_t)r * 300 + c] : 0.f;
        }
        #pragma unroll
        for (int j = 0; j < 4; j++) {
            size_t i = base + (size_t)j * 327680;
            unsigned short h = f2bh(v[j]);
            emb_h[i] = h; emb_l[i] = f2bh(v[j] - bh2f(h));
        }
    } else if (b < 4096 + 1280 + 160) {
        size_t base = (size_t)(b - 4096 - 1280) * 256 + t;
        float v[4];
        #pragma unroll
        for (int j = 0; j < 4; j++) {
            size_t i = base + (size_t)j * 40960;
            int r = (int)(i / 320), c = (int)(i % 320);
            v[j] = (c < 300) ? semantic_W[(size_t)r * 300 + c] : 0.f;
        }
        #pragma unroll
        for (int j = 0; j < 4; j++) {
            size_t i = base + (size_t)j * 40960;
            unsigned short h = f2bh(v[j]);
            sw_h[i] = h; sw_l[i] = f2bh(v[j] - bh2f(h));
        }
    } else if (b < 4096 + 1280 + 160 + 512) {
        int l2 = b - 4096 - 1280 - 160;
        const float* src = gc1_W + (size_t)512 * 1024;
        int kb = (l2 & 15) * 32, nb = (l2 >> 4) * 32;
        int tx = t & 31, ty = t >> 5;
        #pragma unroll
        for (int i = 0; i < 32; i += 8)
            tile[ty + i][tx] = src[(size_t)(kb + ty + i) * 1024 + nb + tx];
        __syncthreads();
        #pragma unroll
        for (int i = 0; i < 32; i += 8) {
            int n = nb + ty + i, k = kb + tx;
            w1t_h[(size_t)n * 512 + k] = f2bh(tile[tx][ty + i]);
        }
    } else if (b < 4096 + 1280 + 160 + 512 + 1024) {
        int l2 = b - 4096 - 1280 - 160 - 512;
        int kb = (l2 & 31) * 32, nb = (l2 >> 5) * 32;
        int tx = t & 31, ty = t >> 5;
        #pragma unroll
        for (int i = 0; i < 32; i += 8)
            tile[ty + i][tx] = gc2_W[(size_t)(kb + ty + i) * 1024 + nb + tx];
        __syncthreads();
        #pragma unroll
        for (int i = 0; i < 32; i += 8) {
            int n = nb + ty + i, k = kb + tx;
            w2t_h[(size_t)n * 1024 + k] = f2bh(tile[tx][ty + i]);
        }
    } else {
        vec3_body(b - (4096 + 1280 + 160 + 512 + 1024), frames, scores, word_embed,
                  visual_W, visual_b, semantic_W, semantic_b, score_W, score_b, vec);
    }
}

// ---------------- staging helpers ----------------
template<int NCHP, int NJ>
__device__ __forceinline__ void stg_mat(const unsigned short* __restrict__ src, int ld, int r0,
                                        int k0, unsigned short* dst, int t) {
    #pragma unroll
    for (int j = 0; j < NJ; j++) {
        int c = j * 256 + t;
        int p = c / NCHP;
        int idx = c % NCHP;
        int row = idx >> 2;
        int gg = (idx & 3) ^ ((row >> 1) & 3);
        gload16(src + (size_t)(r0 + row) * ld + (k0 + p * 32 + gg * 8),
                dst + (size_t)(j * 256 + (t & ~63)) * 8);
    }
}

template<int ROWS>
__device__ __forceinline__ s16x8 rfrag(const unsigned short* rb, int row, int p, int g4) {
    int byte = (p * ROWS + row) * 64 + ((g4 ^ ((row >> 1) & 3)) << 4);
    return *(const s16x8*)((const char*)rb + byte);
}

// ---------------- 4-wave MFMA GEMM (round-4/9 proven structure, ring-3 counted) ----------
template<int BM, int BK, int PROD, int WMODE, int RELU, int SPLITK>
__global__ __launch_bounds__(256) void mfma_g(
    const unsigned short* __restrict__ Ah, const unsigned short* __restrict__ Al,
    const unsigned short* __restrict__ Bh, const unsigned short* __restrict__ Bl,
    int K, int lda, int ldb,
    unsigned short* __restrict__ Ch, float* __restrict__ Cf, int ldc,
    const float* __restrict__ bias, const float* __restrict__ bias2)
{
    constexpr int A_USH = BM * BK;
    constexpr int B_USH = 64 * BK;
    constexpr int A_CH  = A_USH / 8;
    constexpr int B_CH  = B_USH / 8;
    constexpr int SLOT  = (PROD == 3) ? 2 * (A_USH + B_USH) : (A_USH + B_USH);
    constexpr int L     = ((A_CH + B_CH) / 256) * ((PROD == 3) ? 2 : 1);
    constexpr int FM    = BM / 32;
    __shared__ unsigned short lds[3 * SLOT];

    const int t = threadIdx.x;
    const int w = t >> 6, l = t & 63;
    const int r = l & 15, g4 = l >> 4;
    const int wr = (w >> 1) * (BM / 2);
    const int wc = (w & 1) * 32;

    const int gx = gridDim.x;
    const int nwg = gx * gridDim.y;
    int flat = blockIdx.y * gx + blockIdx.x;
    int swz = (flat & 7) * (nwg >> 3) + (flat >> 3);
    const int col0 = (swz % gx) * 64;
    const int row0 = (swz / gx) * BM;

    if constexpr (SPLITK) {
        int z = blockIdx.z;
        Ah += (size_t)z * K;
        Bh += (size_t)z * K;
        if (Cf) Cf += (size_t)z * (size_t)nwg * (BM * 64);
        if (Ch) Ch += (size_t)z * (size_t)nwg * (BM * 64);
    }

    f32x4 acc[FM][2];
    #pragma unroll
    for (int a = 0; a < FM; a++)
        #pragma unroll
        for (int b = 0; b < 2; b++) acc[a][b] = (f32x4){0.f, 0.f, 0.f, 0.f};

    auto stage = [&](int slot, int k0) {
        unsigned short* base = lds + slot * SLOT;
        stg_mat<BM * 4, A_CH / 256>(Ah, lda, row0, k0, base, t);
        stg_mat<256,    B_CH / 256>(Bh, ldb, col0, k0, base + A_USH, t);
        if constexpr (PROD == 3) {
            stg_mat<256,    B_CH / 256>(Bl, ldb, col0, k0, base + A_USH + B_USH, t);
            stg_mat<BM * 4, A_CH / 256>(Al, lda, row0, k0, base + A_USH + 2 * B_USH, t);
        }
    };

    const int T = K / BK;
    stage(0, 0);
    stage(1, BK);

    for (int tt = 0; tt < T; ++tt) {
        __builtin_amdgcn_s_barrier();
        if (tt + 2 < T) {
            stage((tt + 2) % 3, (tt + 2) * BK);
            if constexpr (L == 4)      asm volatile("s_waitcnt vmcnt(8)" ::: "memory");
            else if constexpr (L == 6) asm volatile("s_waitcnt vmcnt(12)" ::: "memory");
            else                       asm volatile("s_waitcnt vmcnt(16)" ::: "memory");
        } else if (tt + 1 < T) {
            if constexpr (L == 4)      asm volatile("s_waitcnt vmcnt(4)" ::: "memory");
            else if constexpr (L == 6) asm volatile("s_waitcnt vmcnt(6)" ::: "memory");
            else                       asm volatile("s_waitcnt vmcnt(8)" ::: "memory");
        } else {
            asm volatile("s_waitcnt vmcnt(0)" ::: "memory");
        }
        __builtin_amdgcn_s_barrier();

        const unsigned short* base = lds + (tt % 3) * SLOT;
        #pragma unroll
        for (int kk = 0; kk < BK / 32; kk++) {
            s16x8 a[FM], bb[2], alr[FM], blr[2];
            #pragma unroll
            for (int f = 0; f < FM; f++) a[f] = rfrag<BM>(base, wr + f * 16 + r, kk, g4);
            #pragma unroll
            for (int f = 0; f < 2; f++) bb[f] = rfrag<64>(base + A_USH, wc + f * 16 + r, kk, g4);
            if constexpr (PROD == 3) {
                #pragma unroll
                for (int f = 0; f < 2; f++) blr[f] = rfrag<64>(base + A_USH + B_USH, wc + f * 16 + r, kk, g4);
                #pragma unroll
                for (int f = 0; f < FM; f++) alr[f] = rfrag<BM>(base + A_USH + 2 * B_USH, wr + f * 16 + r, kk, g4);
            }
            __builtin_amdgcn_s_setprio(1);
            #pragma unroll
            for (int fm = 0; fm < FM; fm++)
                #pragma unroll
                for (int fn = 0; fn < 2; fn++) {
                    acc[fm][fn] = MF(a[fm], bb[fn], acc[fm][fn]);
                    if constexpr (PROD == 3) {
                        acc[fm][fn] = MF(a[fm], blr[fn], acc[fm][fn]);
                        acc[fm][fn] = MF(alr[fm], bb[fn], acc[fm][fn]);
                    }
                }
            __builtin_amdgcn_s_setprio(0);
        }
    }

    // epilogue (C/D: col = lane&15, row = 4*(lane>>4)+i — m89-verified)
    #pragma unroll
    for (int fn = 0; fn < 2; fn++) {
        int n = col0 + wc + fn * 16 + r;
        float bn = bias ? bias[n] : 0.f;
        if (bias2) bn += bias2[n];
        #pragma unroll
        for (int fm = 0; fm < FM; fm++) {
            int m0 = row0 + wr + fm * 16 + g4 * 4;
            f32x4 v = acc[fm][fn];
            if constexpr (WMODE == 4) {
                u16x4 hv;
                #pragma unroll
                for (int i = 0; i < 4; i++) {
                    float x = v[i] + bn;
                    if (RELU) x = fmaxf(x, 0.f);
                    hv[i] = f2bh(x);
                }
                *(u16x4*)(Ch + (size_t)n * ldc + m0) = hv;
            } else if constexpr (WMODE == 6) {
                #pragma unroll
                for (int i = 0; i < 4; i++) {
                    float x = v[i] + bn;
                    if (RELU) x = fmaxf(x, 0.f);
                    Cf[(size_t)(m0 + i) * ldc + n] = x;
                }
            } else {  // WMODE 3: hi bf16 C[m][n]
                #pragma unroll
                for (int i = 0; i < 4; i++) {
                    float x = v[i] + bn;
                    if (RELU) x = fmaxf(x, 0.f);
                    Ch[(size_t)(m0 + i) * ldc + n] = f2bh(x);
                }
            }
        }
    }
}

// ---------------- SQUARE-tile GEMM 128x128, wave 64x64, BK=64, ring-2 counted, split-K2 --
// f32 partials: Cf[z*4096*1024 + m*ldc + n]. LDS 64 KB -> 2 blocks/CU; grid 512 = 2/CU.
__global__ __launch_bounds__(256) void mfma_sq(
    const unsigned short* __restrict__ Ah,
    const unsigned short* __restrict__ Bh,
    int Kc, int lda, int ldb,
    float* __restrict__ Cf, int ldc)
{
    constexpr int A_USH = 128 * 64;           // 8192 ush (2 K-panels x 128 rows)
    constexpr int SLOT  = 2 * A_USH;          // 16384 ush = 32 KB
    __shared__ unsigned short lds[2 * SLOT];  // 64 KB ring-2

    const int t = threadIdx.x;
    const int w = t >> 6, l = t & 63;
    const int r = l & 15, g4 = l >> 4;
    const int wr = (w >> 1) * 64, wc = (w & 1) * 64;

    const int gx = gridDim.x;
    const int nwg = gx * gridDim.y;
    int flat = blockIdx.y * gx + blockIdx.x;
    int swz = (flat & 7) * (nwg >> 3) + (flat >> 3);
    const int col0 = (swz % gx) * 128;
    const int row0 = (swz / gx) * 128;

    const int z = blockIdx.z;
    Ah += (size_t)z * Kc;
    Bh += (size_t)z * Kc;
    Cf += (size_t)z * 4194304;

    f32x4 acc[4][4];
    #pragma unroll
    for (int a = 0; a < 4; a++)
        #pragma unroll
        for (int b = 0; b < 4; b++) acc[a][b] = (f32x4){0.f, 0.f, 0.f, 0.f};

    auto stage = [&](int slot, int k0) {      // 8 loads/thread
        unsigned short* base = lds + slot * SLOT;
        stg_mat<512, 4>(Ah, lda, row0, k0, base, t);
        stg_mat<512, 4>(Bh, ldb, col0, k0, base + A_USH, t);
    };

    const int T = Kc >> 6;                    // 32 for Kc=2048
    stage(0, 0);

    for (int tt = 0; tt < T; ++tt) {
        __builtin_amdgcn_s_barrier();         // all waves done computing tt-1 (slot (tt+1)&1 free)
        if (tt + 1 < T) {
            stage((tt + 1) & 1, (tt + 1) * 64);
            asm volatile("s_waitcnt vmcnt(8)" ::: "memory");   // oldest 8 (tile tt) landed
        } else {
            asm volatile("s_waitcnt vmcnt(0)" ::: "memory");
        }
        __builtin_amdgcn_s_barrier();         // tile tt staged for everyone

        const unsigned short* base = lds + (tt & 1) * SLOT;
        #pragma unroll
        for (int kk = 0; kk < 2; kk++) {
            s16x8 a[4], bb[4];
            #pragma unroll
            for (int f = 0; f < 4; f++) a[f] = rfrag<128>(base, wr + f * 16 + r, kk, g4);
            #pragma unroll
            for (int f = 0; f < 4; f++) bb[f] = rfrag<128>(base + A_USH, wc + f * 16 + r, kk, g4);
            __builtin_amdgcn_s_setprio(1);
            #pragma unroll
            for (int fm = 0; fm < 4; fm++)
                #pragma unroll
                for (int fn = 0; fn < 4; fn++)
                    acc[fm][fn] = MF(a[fm], bb[fn], acc[fm][fn]);
            __builtin_amdgcn_s_setprio(0);
        }
    }

    // epilogue: f32 partials (C/D: col = lane&15, row = 4*(lane>>4)+i)
    #pragma unroll
    for (int fn = 0; fn < 4; fn++) {
        int n = col0 + wc + fn * 16 + r;
        #pragma unroll
        for (int fm = 0; fm < 4; fm++) {
            int m0 = row0 + wr + fm * 16 + g4 * 4;
            f32x4 v = acc[fm][fn];
            #pragma unroll
            for (int i = 0; i < 4; i++)
                Cf[(size_t)(m0 + i) * ldc + n] = v[i];
        }
    }
}

// ---------------- fallback f32 tiled GEMM (round-1, proven) ----------------
template<int TRANSB>
__global__ __launch_bounds__(256) void gemm_f32_128(
    const float* __restrict__ A, const float* __restrict__ B, float* __restrict__ C,
    int M, int N, int K, int lda, int ldb,
    const float* __restrict__ bias, const float* __restrict__ vrow, int do_relu)
{
    constexpr int BM = 128, BN = 128, BK = 16;
    __shared__ float As[BK][BM + 4];
    __shared__ float Bs[BK][BN + 4];
    const int t = threadIdx.x;
    const int w = t >> 6, l = t & 63;
    const int cx = (w & 1) * 8 + (l & 7);
    const int cy = (w >> 1) * 8 + (l >> 3);
    const int row0 = blockIdx.y * BM;
    const int col0 = blockIdx.x * BN;

    float acc[8][8];
    #pragma unroll
    for (int i = 0; i < 8; i++)
        #pragma unroll
        for (int j = 0; j < 8; j++) acc[i][j] = 0.f;

    const int ka = t & 15;
    const int ma = t >> 4;

    for (int k0 = 0; k0 < K; k0 += BK) {
        #pragma unroll
        for (int i = 0; i < 8; i++) {
            int m = ma + i * 16;
            int gk = k0 + ka;
            float v = 0.f;
            if (gk < K) v = A[(size_t)(row0 + m) * lda + gk];
            As[ka][m] = v;
        }
        if (TRANSB) {
            #pragma unroll
            for (int i = 0; i < 8; i++) {
                int n = ma + i * 16;
                int gk = k0 + ka;
                float v = 0.f;
                if (gk < K) v = B[(size_t)(col0 + n) * ldb + gk];
                Bs[ka][n] = v;
            }
        } else {
            const int nb = t & 127;
            const int kb = t >> 7;
            #pragma unroll
            for (int i = 0; i < 8; i++) {
                int kk = kb + i * 2;
                int gk = k0 + kk;
                float v = 0.f;
                if (gk < K) v = B[(size_t)gk * ldb + col0 + nb];
                Bs[kk][nb] = v;
            }
        }
        __syncthreads();
        #pragma unroll
        for (int kk = 0; kk < BK; kk++) {
            float a[8], bb[8];
            *(float4*)&a[0]  = *(const float4*)&As[kk][cy * 8];
            *(float4*)&a[4]  = *(const float4*)&As[kk][cy * 8 + 4];
            *(float4*)&bb[0] = *(const float4*)&Bs[kk][cx * 8];
            *(float4*)&bb[4] = *(const float4*)&Bs[kk][cx * 8 + 4];
            #pragma unroll
            for (int i = 0; i < 8; i++)
                #pragma unroll
                for (int j = 0; j < 8; j++)
                    acc[i][j] = fmaf(a[i], bb[j], acc[i][j]);
        }
        __syncthreads();
    }

    #pragma unroll
    for (int i = 0; i < 8; i++) {
        int rr = row0 + cy * 8 + i;
        float vv[8];
        #pragma unroll
        for (int j = 0; j < 8; j++) {
            int c = col0 + cx * 8 + j;
            float v = acc[i][j];
            if (vrow) v += vrow[c];
            if (bias) v += bias[c];
            if (do_relu) v = fmaxf(v, 0.f);
            vv[j] = v;
        }
        float* cp = C + (size_t)rr * N + col0 + cx * 8;
        *(float4*)cp       = *(float4*)&vv[0];
        *(float4*)(cp + 4) = *(float4*)&vv[4];
    }
}

// ---------------- host launcher ----------------
extern "C" void kernel_launch(void* const* d_in, const int* in_sizes, int n_in,
                              void* d_out, int out_size, void* d_ws, size_t ws_size,
                              hipStream_t stream) {
    const float* frames     = (const float*)d_in[0];
    const float* scores     = (const float*)d_in[1];
    const float* word_embed = (const float*)d_in[2];
    const float* all_embeds = (const float*)d_in[3];
    const float* adj        = (const float*)d_in[4];
    const float* visual_W   = (const float*)d_in[5];
    const float* visual_b   = (const float*)d_in[6];
    const float* semantic_W = (const float*)d_in[7];
    const float* semantic_b = (const float*)d_in[8];
    const float* score_W    = (const float*)d_in[9];
    const float* score_b    = (const float*)d_in[10];
    const float* gc1_W      = (const float*)d_in[11];
    const float* gc1_b      = (const float*)d_in[12];
    const float* gc2_W      = (const float*)d_in[13];
    const float* gc2_b      = (const float*)d_in[14];
    const float* gc3_W      = (const float*)d_in[15];
    const float* gc3_b      = (const float*)d_in[16];
    const float* gcn512_W   = (const float*)d_in[17];
    const float* gcn512_b   = (const float*)d_in[18];
    const float* hidden_W   = (const float*)d_in[19];
    const float* hidden_b   = (const float*)d_in[20];
    const float* critic_W   = (const float*)d_in[21];
    const float* critic_b   = (const float*)d_in[22];
    const float* actor_W    = (const float*)d_in[23];
    const float* actor_b    = (const float*)d_in[24];

    float* out = (float*)d_out;

    if (ws_size >= FAST_WS) {
        char* wsb = (char*)d_ws;
        unsigned short* adj_h = (unsigned short*)(wsb + F_ADJH);
        unsigned short* emb_h = (unsigned short*)(wsb + F_EMB_H);
        unsigned short* emb_l = (unsigned short*)(wsb + F_EMB_L);
        unsigned short* sw_h  = (unsigned short*)(wsb + F_SW_H);
        unsigned short* sw_l  = (unsigned short*)(wsb + F_SW_L);
        unsigned short* w1t_h = (unsigned short*)(wsb + F_W1T_H);
        unsigned short* w2t_h = (unsigned short*)(wsb + F_W2T_H);
        unsigned short* emT   = (unsigned short*)(wsb + F_EMT);
        float*          p1f   = (float*)(wsb + F_P1F);
        unsigned short* p1_h  = (unsigned short*)(wsb + F_P1H);
        unsigned short* h1    = (unsigned short*)(wsb + F_H1);
        unsigned short* y2t   = (unsigned short*)(wsb + F_Y2T);
        float*          p7f   = (float*)(wsb + F_P7F);
        float*          vec   = (float*)(wsb + F_VEC);

        // 1. prep: all converts + vec3 (ILP-4 streaming)
        prep_kernel<<<4096 + 1280 + 160 + 512 + 1024 + 1536, 256, 0, stream>>>(
            adj, all_embeds, semantic_W, gc1_W, gc2_W,
            frames, scores, word_embed, visual_W, visual_b, semantic_b, score_W, score_b,
            adj_h, emb_h, emb_l, sw_h, sw_l, w1t_h, w2t_h, vec);
        // 2. vrow = s512 @ gc1_W[:512,:]
        vrow_kernel<<<8, 256, 0, stream>>>(gc1_W, vec);
        // 3. emT = relu(all_embeds @ semantic_W^T + b)^T  hi [512,4096], K=320, PROD=3
        mfma_g<64, 32, 3, 4, 1, 0><<<dim3(8, 64), 256, 0, stream>>>(
            emb_h, emb_l, sw_h, sw_l, 320, 320, 320,
            emT, nullptr, 4096, semantic_b, nullptr);
        // 4. P1 partials = adj @ em  f32, split-K x2  [4096,512]
        mfma_g<128, 64, 1, 6, 0, 1><<<dim3(8, 32, 2), 256, 0, stream>>>(
            adj_h, nullptr, emT, nullptr, 2048, 4096, 4096,
            nullptr, p1f, 512, nullptr, nullptr);
        // 4b. combine f32 partials -> p1 hi
        combine_p1_kernel<<<2048, 256, 0, stream>>>(p1f, p1_h);
        // 5. h1 = relu(P1_hi @ W1'_hi + vrow + b1)  hi [4096,1024], K=512, PROD=1
        mfma_g<128, 64, 1, 3, 1, 0><<<dim3(16, 32), 256, 0, stream>>>(
            p1_h, nullptr, w1t_h, nullptr, 512, 512, 512,
            h1, nullptr, 1024, gc1_b, vec + OFF_VROW);
        // 6. y2t = (h1 @ gc2_W)^T  hi [1024,4096], K=1024
        mfma_g<128, 64, 1, 4, 0, 0><<<dim3(16, 32), 256, 0, stream>>>(
            h1, nullptr, w2t_h, nullptr, 1024, 1024, 1024,
            y2t, nullptr, 4096, nullptr, nullptr);
        // 7. p7f partials = adj @ Y2  f32, square tiles BK=64, split-K x2  [4096,1024]
        mfma_sq<<<dim3(8, 32, 2), 256, 0, stream>>>(
            adj_h, y2t, 2048, 4096, 4096, p7f, 1024);
        // 7b. y3[i] = sum_j relu(p7f0+p7f1+b2)[i,j] * gc3_W[j]
        h2y3_kernel<<<4096, 256, 0, stream>>>(p7f, gc2_b, gc3_W, vec);
        // 8-11. tail
        h3b_kernel<<<4096, 256, 0, stream>>>(adj_h, gc3_b, vec);
        gcn_kernel<<<512, 256, 0, stream>>>(gcn512_W, gcn512_b, vec);
        x_kernel<<<512, 256, 0, stream>>>(hidden_W, hidden_b, vec);
        out_kernel<<<1, 512, 0, stream>>>(vec, critic_W, critic_b, actor_W, actor_b, out);
    } else {
        // fallback f32 path (round-1, proven within 50.4 MB)
        float* ws = (float*)d_ws;
        float* em = ws + OFF_BUF0;
        float* Y1 = ws + OFF_BUF1;
        float* H1 = ws + OFF_BUF2;
        float* Y2 = ws + OFF_BUF1;
        float* H2 = ws + OFF_BUF0;

        vec3_kernel<<<1536, 256, 0, stream>>>(frames, scores, word_embed,
                                              visual_W, visual_b, semantic_W, semantic_b,
                                              score_W, score_b, ws);
        vrow_kernel<<<8, 256, 0, stream>>>(gc1_W, ws);
        gemm_f32_128<1><<<dim3(512 / 128, 4096 / 128), 256, 0, stream>>>(
            all_embeds, semantic_W, em, 4096, 512, 300, 300, 300, semantic_b, nullptr, 1);
        gemm_f32_128<0><<<dim3(1024 / 128, 4096 / 128), 256, 0, stream>>>(
            em, gc1_W + (size_t)512 * 1024, Y1, 4096, 1024, 512, 512, 1024,
            nullptr, ws + OFF_VROW, 0);
        gemm_f32_128<0><<<dim3(1024 / 128, 4096 / 128), 256, 0, stream>>>(
            adj, Y1, H1, 4096, 1024, 4096, 4096, 1024, gc1_b, nullptr, 1);
        gemm_f32_128<0><<<dim3(1024 / 128, 4096 / 128), 256, 0, stream>>>(
            H1, gc2_W, Y2, 4096, 1024, 1024, 1024, 1024, nullptr, nullptr, 0);
        gemm_f32_128<0><<<dim3(1024 / 128, 4096 / 128), 256, 0, stream>>>(
            adj, Y2, H2, 4096, 1024, 4096, 4096, 1024, gc2_b, nullptr, 1);
        y3_kernel<<<4096, 256, 0, stream>>>(H2, gc3_W, ws);
        h3_kernel<<<4096, 256, 0, stream>>>(adj, gc3_b, ws);
        gcn_kernel<<<512, 256, 0, stream>>>(gcn512_W, gcn512_b, ws);
        x_kernel<<<512, 256, 0, stream>>>(hidden_W, hidden_b, ws);
        out_kernel<<<1, 512, 0, stream>>>(ws, critic_W, critic_b, actor_W, actor_b, out);
    }

    (void)in_sizes; (void)n_in; (void)out_size;
}

// Round 13
// 175.669 us; speedup vs baseline: 1.0893x; 1.0280x over previous
//
#include <hip/hip_runtime.h>
#include <cstddef>
#include <cstdint>

typedef short  s16x8 __attribute__((ext_vector_type(8)));
typedef float  f32x4 __attribute__((ext_vector_type(4)));
typedef unsigned short u16x4 __attribute__((ext_vector_type(4)));

typedef __attribute__((address_space(1))) const void gas_void;
typedef __attribute__((address_space(3))) void las_void;

// ---------------- bf16 helpers ----------------
__device__ __forceinline__ unsigned short f2bh(float x) {
    union { float f; unsigned int u; } c; c.f = x;
    unsigned int r = c.u + 0x7fffu + ((c.u >> 16) & 1u);
    return (unsigned short)(r >> 16);
}
__device__ __forceinline__ float bh2f(unsigned short h) {
    union { unsigned int u; float f; } c; c.u = ((unsigned int)h) << 16;
    return c.f;
}
__device__ __forceinline__ f32x4 MF(s16x8 a, s16x8 b, f32x4 c) {
    return __builtin_amdgcn_mfma_f32_16x16x32_bf16(a, b, c, 0, 0, 0);
}
__device__ __forceinline__ void gload16(const unsigned short* g, unsigned short* l) {
    __builtin_amdgcn_global_load_lds((gas_void*)g, (las_void*)l, 16, 0, 0);
}

// ---------------- vec region offsets (floats) ----------------
static constexpr size_t OFF_VIS  = 0;
static constexpr size_t OFF_SEM  = 512;
static constexpr size_t OFF_GCN  = 1024;
static constexpr size_t OFF_S512 = 1536;
static constexpr size_t OFF_VROW = 2048;
static constexpr size_t OFF_X    = 3072;
static constexpr size_t OFF_Y3   = 4096;
static constexpr size_t OFF_H3   = 8192;
// fallback big buffers (floats, absolute in ws)
static constexpr size_t OFF_BUF0 = 16384;
static constexpr size_t OFF_BUF1 = OFF_BUF0 + 4194304;
static constexpr size_t OFF_BUF2 = OFF_BUF1 + 4194304;

// ---------------- fast-path ws layout (bytes) ----------------
static constexpr size_t F_ADJH  = 0;                          // 33,554,432
static constexpr size_t F_SCR   = 33554432;                   // 33,554,432 scratch
static constexpr size_t F_EMB_H = F_SCR;                      // 2,621,440
static constexpr size_t F_EMB_L = F_SCR + 2621440;            // 2,621,440
static constexpr size_t F_SW_H  = F_SCR + 5242880;            // 327,680
static constexpr size_t F_SW_L  = F_SCR + 5570560;            // 327,680
static constexpr size_t F_W1T_H = F_SCR + 5898240;            // 1,048,576
static constexpr size_t F_W2T_H = F_SCR + 6946816;            // 2,097,152
static constexpr size_t F_EMT   = F_SCR + 9043968;            // 4,194,304
static constexpr size_t F_P1P   = F_SCR + 16777216;           // 16,777,216 (#4 bf16 partials x4)
static constexpr size_t F_H1    = F_SCR + 16777216;           // 8,388,608 (after p1p dead)
static constexpr size_t F_P7F   = F_SCR;                      // 33,554,432 (#7 f32 partials x2)
static constexpr size_t F_P1H   = 67108864;                   // 4,194,304
static constexpr size_t F_Y2T   = 71303168;                   // 8,388,608
static constexpr size_t F_VEC   = 79691776;                   // 49,152
static constexpr size_t FAST_WS = 79740928;                   // ~76.0 MB

// ---------------- block reduction ----------------
__device__ inline float blockReduceSum256(float v) {
    #pragma unroll
    for (int o = 32; o > 0; o >>= 1) v += __shfl_down(v, o, 64);
    __shared__ float red[4];
    int w = threadIdx.x >> 6;
    if ((threadIdx.x & 63) == 0) red[w] = v;
    __syncthreads();
    if (threadIdx.x == 0) v = red[0] + red[1] + red[2] + red[3];
    return v;
}

// ---------------- vec3 body (visual branch float4-vectorized) ----------------
__device__ __forceinline__ void vec3_body(int b,
                            const float* __restrict__ frames,
                            const float* __restrict__ scores,
                            const float* __restrict__ word_embed,
                            const float* __restrict__ visual_W, const float* __restrict__ visual_b,
                            const float* __restrict__ semantic_W, const float* __restrict__ semantic_b,
                            const float* __restrict__ score_W, const float* __restrict__ score_b,
                            float* __restrict__ vec) {
    if (b < 512) {
        int row = b;
        const float4* w4 = (const float4*)(visual_W + (size_t)row * 8192);
        const float4* x4 = (const float4*)frames;
        float s = 0.f;
        #pragma unroll
        for (int c0 = 0; c0 < 2048; c0 += 256) {
            int c = c0 + threadIdx.x;
            float4 wv = w4[c], xv = x4[c];
            s += wv.x * xv.x + wv.y * xv.y + wv.z * xv.z + wv.w * xv.w;
        }
        s = blockReduceSum256(s);
        if (threadIdx.x == 0) (vec + OFF_VIS)[row] = fmaxf(s + visual_b[row], 0.f);
        return;
    }
    const float* x; const float* W; const float* bias; float* out; int K; int row;
    if (b < 1024) { row = b - 512;  x = word_embed; W = semantic_W; bias = semantic_b; out = vec + OFF_SEM;  K = 300;  }
    else          { row = b - 1024; x = scores;     W = score_W;    bias = score_b;    out = vec + OFF_S512; K = 1000; }
    const float* wr = W + (size_t)row * K;
    float s = 0.f;
    for (int k = threadIdx.x; k < K; k += 256) s += wr[k] * x[k];
    s = blockReduceSum256(s);
    if (threadIdx.x == 0) out[row] = fmaxf(s + bias[row], 0.f);
}

// ---------------- small kernels ----------------
__global__ void vec3_kernel(const float* __restrict__ frames,
                            const float* __restrict__ scores,
                            const float* __restrict__ word_embed,
                            const float* __restrict__ visual_W, const float* __restrict__ visual_b,
                            const float* __restrict__ semantic_W, const float* __restrict__ semantic_b,
                            const float* __restrict__ score_W, const float* __restrict__ score_b,
                            float* __restrict__ vec) {
    vec3_body(blockIdx.x, frames, scores, word_embed, visual_W, visual_b,
              semantic_W, semantic_b, score_W, score_b, vec);
}

__global__ void vrow_kernel(const float* __restrict__ gc1_W, float* __restrict__ vec) {
    __shared__ float part[128];
    const float* s512 = vec + OFF_S512;
    int jl = threadIdx.x & 127;
    int j = blockIdx.x * 128 + jl;
    int kh = threadIdx.x >> 7;
    float s = 0.f;
    #pragma unroll 4
    for (int k = kh * 256; k < kh * 256 + 256; k++)
        s += s512[k] * gc1_W[(size_t)k * 1024 + j];
    if (kh) part[jl] = s;
    __syncthreads();
    if (!kh) vec[OFF_VROW + j] = s + part[jl];
}

__global__ void y3_kernel(const float* __restrict__ H2, const float* __restrict__ gc3_W,
                          float* __restrict__ vec) {
    int i = blockIdx.x;
    const float* r = H2 + (size_t)i * 1024;
    float s = 0.f;
    for (int k = threadIdx.x; k < 1024; k += 256) s += r[k] * gc3_W[k];
    s = blockReduceSum256(s);
    if (threadIdx.x == 0) vec[OFF_Y3 + i] = s;
}

// fused: y3[i] = sum_j relu(p7f0[i,j] + p7f1[i,j] + gc2_b[j]) * gc3_W[j]
__global__ void h2y3_kernel(const float* __restrict__ p7f, const float* __restrict__ gc2_b,
                            const float* __restrict__ gc3_W, float* __restrict__ vec) {
    int i = blockIdx.x;
    const float4* r0 = (const float4*)(p7f + (size_t)i * 1024);
    const float4* r1 = (const float4*)(p7f + 4194304 + (size_t)i * 1024);
    const float4* b4 = (const float4*)gc2_b;
    const float4* w4 = (const float4*)gc3_W;
    int c = threadIdx.x;   // 256 threads x float4 = 1024
    float4 a = r0[c], b = r1[c], bb = b4[c], ww = w4[c];
    float s = fmaxf(a.x + b.x + bb.x, 0.f) * ww.x
            + fmaxf(a.y + b.y + bb.y, 0.f) * ww.y
            + fmaxf(a.z + b.z + bb.z, 0.f) * ww.z
            + fmaxf(a.w + b.w + bb.w, 0.f) * ww.w;
    s = blockReduceSum256(s);
    if (threadIdx.x == 0) vec[OFF_Y3 + i] = s;
}

// h3 from bf16 adj
__global__ void h3b_kernel(const unsigned short* __restrict__ adj_h,
                           const float* __restrict__ gc3_b, float* __restrict__ vec) {
    int i = blockIdx.x;
    const u16x4* rp = (const u16x4*)(adj_h + (size_t)i * 4096);
    const float* y3 = vec + OFF_Y3;
    float s = 0.f;
    for (int c = threadIdx.x; c < 1024; c += 256) {
        u16x4 v = rp[c];
        int k0 = c * 4;
        s += bh2f(v[0]) * y3[k0] + bh2f(v[1]) * y3[k0 + 1]
           + bh2f(v[2]) * y3[k0 + 2] + bh2f(v[3]) * y3[k0 + 3];
    }
    s = blockReduceSum256(s);
    if (threadIdx.x == 0) vec[OFF_H3 + i] = fmaxf(s + gc3_b[0], 0.f);
}

__global__ void h3_kernel(const float* __restrict__ adj, const float* __restrict__ gc3_b,
                          float* __restrict__ vec) {
    int i = blockIdx.x;
    const float* r = adj + (size_t)i * 4096;
    const float* y3 = vec + OFF_Y3;
    float s = 0.f;
    for (int k = threadIdx.x; k < 4096; k += 256) s += r[k] * y3[k];
    s = blockReduceSum256(s);
    if (threadIdx.x == 0) vec[OFF_H3 + i] = fmaxf(s + gc3_b[0], 0.f);
}

__global__ void gcn_kernel(const float* __restrict__ gcn512_W, const float* __restrict__ gcn512_b,
                           float* __restrict__ vec) {
    int j = blockIdx.x;
    const float* r = gcn512_W + (size_t)j * 4096;
    const float* h3 = vec + OFF_H3;
    float s = 0.f;
    for (int k = threadIdx.x; k < 4096; k += 256) s += r[k] * h3[k];
    s = blockReduceSum256(s);
    if (threadIdx.x == 0) vec[OFF_GCN + j] = fmaxf(s + gcn512_b[j], 0.f);
}

__global__ void x_kernel(const float* __restrict__ hidden_W, const float* __restrict__ hidden_b,
                         float* __restrict__ vec) {
    int j = blockIdx.x;
    const float* r = hidden_W + (size_t)j * 1536;
    const float* joint = vec;
    float s = 0.f;
    for (int k = threadIdx.x; k < 1536; k += 256) s += r[k] * joint[k];
    s = blockReduceSum256(s);
    if (threadIdx.x == 0) vec[OFF_X + j] = fmaxf(s + hidden_b[j], 0.f);
}

__global__ void out_kernel(const float* __restrict__ vec,
                           const float* __restrict__ critic_W, const float* __restrict__ critic_b,
                           const float* __restrict__ actor_W, const float* __restrict__ actor_b,
                           float* __restrict__ out) {
    const float* xv = vec + OFF_X;
    int w = threadIdx.x >> 6, l = threadIdx.x & 63;
    if (w >= 7) return;
    const float* row = (w == 0) ? critic_W : actor_W + (size_t)(w - 1) * 512;
    float s = 0.f;
    for (int q = l; q < 512; q += 64) s += xv[q] * row[q];
    #pragma unroll
    for (int o = 32; o > 0; o >>= 1) s += __shfl_down(s, o, 64);
    if (l == 0) out[w] = s + ((w == 0) ? critic_b[0] : actor_b[w - 1]);
}

// combine P1 split-K bf16 partials (x4) -> hi bf16
__global__ void combine_p1_kernel(const unsigned short* __restrict__ p1p,
                                  unsigned short* __restrict__ hi) {
    size_t i = (size_t)blockIdx.x * 256 + threadIdx.x;    // u16x4 index over 524288
    float s0 = 0.f, s1 = 0.f, s2 = 0.f, s3 = 0.f;
    #pragma unroll
    for (int z = 0; z < 4; z++) {
        u16x4 v = *(const u16x4*)(p1p + (size_t)z * 2097152 + i * 4);
        s0 += bh2f(v[0]); s1 += bh2f(v[1]); s2 += bh2f(v[2]); s3 += bh2f(v[3]);
    }
    u16x4 hv;
    hv[0] = f2bh(s0); hv[1] = f2bh(s1); hv[2] = f2bh(s2); hv[3] = f2bh(s3);
    *(u16x4*)(hi + i * 4) = hv;
}

// ---------------- fused prep kernel: all converts + vec3, ILP-4 streaming ----------------
__global__ void prep_kernel(const float* __restrict__ adj,
                            const float* __restrict__ all_embeds,
                            const float* __restrict__ semantic_W,
                            const float* __restrict__ gc1_W,
                            const float* __restrict__ gc2_W,
                            const float* __restrict__ frames,
                            const float* __restrict__ scores,
                            const float* __restrict__ word_embed,
                            const float* __restrict__ visual_W, const float* __restrict__ visual_b,
                            const float* __restrict__ semantic_b,
                            const float* __restrict__ score_W, const float* __restrict__ score_b,
                            unsigned short* __restrict__ adj_h,
                            unsigned short* __restrict__ emb_h, unsigned short* __restrict__ emb_l,
                            unsigned short* __restrict__ sw_h, unsigned short* __restrict__ sw_l,
                            unsigned short* __restrict__ w1t_h,
                            unsigned short* __restrict__ w2t_h,
                            float* __restrict__ vec) {
    __shared__ float tile[32][33];
    const int b = blockIdx.x, t = threadIdx.x;
    if (b < 4096) {
        size_t base = (size_t)b * 1024 + t;
        float4 v[4];
        #pragma unroll
        for (int j = 0; j < 4; j++) v[j] = ((const float4*)adj)[base + j * 256];
        #pragma unroll
        for (int j = 0; j < 4; j++) {
            u16x4 h;
            h[0] = f2bh(v[j].x); h[1] = f2bh(v[j].y);
            h[2] = f2bh(v[j].z); h[3] = f2bh(v[j].w);
            *(u16x4*)(adj_h + (base + j * 256) * 4) = h;
        }
    } else if (b < 4096 + 1280) {
        size_t base = (size_t)(b - 4096) * 256 + t;
        float v[4];
        #pragma unroll
        for (int j = 0; j < 4; j++) {
            size_t i = base + (size_t)j * 327680;
            int r = (int)(i / 320), c = (int)(i % 320);
            v[j] = (c < 300) ? all_embeds[(size_t)r * 300 + c] : 0.f;
        }
        #pragma unroll
        for (int j = 0; j < 4; j++) {
            size_t i = base + (size_t)j * 327680;
            unsigned short h = f2bh(v[j]);
            emb_h[i] = h; emb_l[i] = f2bh(v[j] - bh2f(h));
        }
    } else if (b < 4096 + 1280 + 160) {
        size_t base = (size_t)(b - 4096 - 1280) * 256 + t;
        float v[4];
        #pragma unroll
        for (int j = 0; j < 4; j++) {
            size_t i = base + (size_t)j * 40960;
            int r = (int)(i / 320), c = (int)(i % 320);
            v[j] = (c < 300) ? semantic_W[(size_t)r * 300 + c] : 0.f;
        }
        #pragma unroll
        for (int j = 0; j < 4; j++) {
            size_t i = base + (size_t)j * 40960;
            unsigned short h = f2bh(v[j]);
            sw_h[i] = h; sw_l[i] = f2bh(v[j] - bh2f(h));
        }
    } else if (b < 4096 + 1280 + 160 + 512) {
        int l2 = b - 4096 - 1280 - 160;
        const float* src = gc1_W + (size_t)512 * 1024;
        int kb = (l2 & 15) * 32, nb = (l2 >> 4) * 32;
        int tx = t & 31, ty = t >> 5;
        #pragma unroll
        for (int i = 0; i < 32; i += 8)
            tile[ty + i][tx] = src[(size_t)(kb + ty + i) * 1024 + nb + tx];
        __syncthreads();
        #pragma unroll
        for (int i = 0; i < 32; i += 8) {
            int n = nb + ty + i, k = kb + tx;
            w1t_h[(size_t)n * 512 + k] = f2bh(tile[tx][ty + i]);
        }
    } else if (b < 4096 + 1280 + 160 + 512 + 1024) {
        int l2 = b - 4096 - 1280 - 160 - 512;
        int kb = (l2 & 31) * 32, nb = (l2 >> 5) * 32;
        int tx = t & 31, ty = t >> 5;
        #pragma unroll
        for (int i = 0; i < 32; i += 8)
            tile[ty + i][tx] = gc2_W[(size_t)(kb + ty + i) * 1024 + nb + tx];
        __syncthreads();
        #pragma unroll
        for (int i = 0; i < 32; i += 8) {
            int n = nb + ty + i, k = kb + tx;
            w2t_h[(size_t)n * 1024 + k] = f2bh(tile[tx][ty + i]);
        }
    } else {
        vec3_body(b - (4096 + 1280 + 160 + 512 + 1024), frames, scores, word_embed,
                  visual_W, visual_b, semantic_W, semantic_b, score_W, score_b, vec);
    }
}

// ---------------- staging helpers ----------------
template<int NCHP, int NJ>
__device__ __forceinline__ void stg_mat(const unsigned short* __restrict__ src, int ld, int r0,
                                        int k0, unsigned short* dst, int t) {
    #pragma unroll
    for (int j = 0; j < NJ; j++) {
        int c = j * 256 + t;
        int p = c / NCHP;
        int idx = c % NCHP;
        int row = idx >> 2;
        int gg = (idx & 3) ^ ((row >> 1) & 3);
        gload16(src + (size_t)(r0 + row) * ld + (k0 + p * 32 + gg * 8),
                dst + (size_t)(j * 256 + (t & ~63)) * 8);
    }
}

template<int ROWS>
__device__ __forceinline__ s16x8 rfrag(const unsigned short* rb, int row, int p, int g4) {
    int byte = (p * ROWS + row) * 64 + ((g4 ^ ((row >> 1) & 3)) << 4);
    return *(const s16x8*)((const char*)rb + byte);
}

// ---------------- 4-wave MFMA GEMM (proven ring-3 counted structure) ----------------
template<int BM, int BK, int PROD, int WMODE, int RELU, int SPLITK>
__global__ __launch_bounds__(256) void mfma_g(
    const unsigned short* __restrict__ Ah, const unsigned short* __restrict__ Al,
    const unsigned short* __restrict__ Bh, const unsigned short* __restrict__ Bl,
    int K, int lda, int ldb,
    unsigned short* __restrict__ Ch, float* __restrict__ Cf, int ldc,
    const float* __restrict__ bias, const float* __restrict__ bias2)
{
    constexpr int A_USH = BM * BK;
    constexpr int B_USH = 64 * BK;
    constexpr int A_CH  = A_USH / 8;
    constexpr int B_CH  = B_USH / 8;
    constexpr int SLOT  = (PROD == 3) ? 2 * (A_USH + B_USH) : (A_USH + B_USH);
    constexpr int L     = ((A_CH + B_CH) / 256) * ((PROD == 3) ? 2 : 1);
    constexpr int FM    = BM / 32;
    __shared__ unsigned short lds[3 * SLOT];

    const int t = threadIdx.x;
    const int w = t >> 6, l = t & 63;
    const int r = l & 15, g4 = l >> 4;
    const int wr = (w >> 1) * (BM / 2);
    const int wc = (w & 1) * 32;

    const int gx = gridDim.x;
    const int nwg = gx * gridDim.y;
    int flat = blockIdx.y * gx + blockIdx.x;
    int swz = (flat & 7) * (nwg >> 3) + (flat >> 3);
    const int col0 = (swz % gx) * 64;
    const int row0 = (swz / gx) * BM;

    if constexpr (SPLITK) {
        int z = blockIdx.z;
        Ah += (size_t)z * K;
        Bh += (size_t)z * K;
        if (Cf) Cf += (size_t)z * (size_t)nwg * (BM * 64);
        if (Ch) Ch += (size_t)z * (size_t)nwg * (BM * 64);
    }

    f32x4 acc[FM][2];
    #pragma unroll
    for (int a = 0; a < FM; a++)
        #pragma unroll
        for (int b = 0; b < 2; b++) acc[a][b] = (f32x4){0.f, 0.f, 0.f, 0.f};

    auto stage = [&](int slot, int k0) {
        unsigned short* base = lds + slot * SLOT;
        stg_mat<BM * 4, A_CH / 256>(Ah, lda, row0, k0, base, t);
        stg_mat<256,    B_CH / 256>(Bh, ldb, col0, k0, base + A_USH, t);
        if constexpr (PROD == 3) {
            stg_mat<256,    B_CH / 256>(Bl, ldb, col0, k0, base + A_USH + B_USH, t);
            stg_mat<BM * 4, A_CH / 256>(Al, lda, row0, k0, base + A_USH + 2 * B_USH, t);
        }
    };

    const int T = K / BK;
    stage(0, 0);
    stage(1, BK);

    for (int tt = 0; tt < T; ++tt) {
        __builtin_amdgcn_s_barrier();
        if (tt + 2 < T) {
            stage((tt + 2) % 3, (tt + 2) * BK);
            if constexpr (L == 4)      asm volatile("s_waitcnt vmcnt(8)" ::: "memory");
            else if constexpr (L == 6) asm volatile("s_waitcnt vmcnt(12)" ::: "memory");
            else                       asm volatile("s_waitcnt vmcnt(16)" ::: "memory");
        } else if (tt + 1 < T) {
            if constexpr (L == 4)      asm volatile("s_waitcnt vmcnt(4)" ::: "memory");
            else if constexpr (L == 6) asm volatile("s_waitcnt vmcnt(6)" ::: "memory");
            else                       asm volatile("s_waitcnt vmcnt(8)" ::: "memory");
        } else {
            asm volatile("s_waitcnt vmcnt(0)" ::: "memory");
        }
        __builtin_amdgcn_s_barrier();

        const unsigned short* base = lds + (tt % 3) * SLOT;
        #pragma unroll
        for (int kk = 0; kk < BK / 32; kk++) {
            s16x8 a[FM], bb[2], alr[FM], blr[2];
            #pragma unroll
            for (int f = 0; f < FM; f++) a[f] = rfrag<BM>(base, wr + f * 16 + r, kk, g4);
            #pragma unroll
            for (int f = 0; f < 2; f++) bb[f] = rfrag<64>(base + A_USH, wc + f * 16 + r, kk, g4);
            if constexpr (PROD == 3) {
                #pragma unroll
                for (int f = 0; f < 2; f++) blr[f] = rfrag<64>(base + A_USH + B_USH, wc + f * 16 + r, kk, g4);
                #pragma unroll
                for (int f = 0; f < FM; f++) alr[f] = rfrag<BM>(base + A_USH + 2 * B_USH, wr + f * 16 + r, kk, g4);
            }
            __builtin_amdgcn_s_setprio(1);
            #pragma unroll
            for (int fm = 0; fm < FM; fm++)
                #pragma unroll
                for (int fn = 0; fn < 2; fn++) {
                    acc[fm][fn] = MF(a[fm], bb[fn], acc[fm][fn]);
                    if constexpr (PROD == 3) {
                        acc[fm][fn] = MF(a[fm], blr[fn], acc[fm][fn]);
                        acc[fm][fn] = MF(alr[fm], bb[fn], acc[fm][fn]);
                    }
                }
            __builtin_amdgcn_s_setprio(0);
        }
    }

    // epilogue (C/D: col = lane&15, row = 4*(lane>>4)+i — m89-verified)
    #pragma unroll
    for (int fn = 0; fn < 2; fn++) {
        int n = col0 + wc + fn * 16 + r;
        float bn = bias ? bias[n] : 0.f;
        if (bias2) bn += bias2[n];
        #pragma unroll
        for (int fm = 0; fm < FM; fm++) {
            int m0 = row0 + wr + fm * 16 + g4 * 4;
            f32x4 v = acc[fm][fn];
            if constexpr (WMODE == 4) {
                u16x4 hv;
                #pragma unroll
                for (int i = 0; i < 4; i++) {
                    float x = v[i] + bn;
                    if (RELU) x = fmaxf(x, 0.f);
                    hv[i] = f2bh(x);
                }
                *(u16x4*)(Ch + (size_t)n * ldc + m0) = hv;
            } else if constexpr (WMODE == 6) {
                #pragma unroll
                for (int i = 0; i < 4; i++) {
                    float x = v[i] + bn;
                    if (RELU) x = fmaxf(x, 0.f);
                    Cf[(size_t)(m0 + i) * ldc + n] = x;
                }
            } else {  // WMODE 3: hi bf16 C[m][n]
                #pragma unroll
                for (int i = 0; i < 4; i++) {
                    float x = v[i] + bn;
                    if (RELU) x = fmaxf(x, 0.f);
                    Ch[(size_t)(m0 + i) * ldc + n] = f2bh(x);
                }
            }
        }
    }
}

// ---------------- SQUARE-tile GEMM 128x128, wave 64x64, BK=64, ring-2 counted, split-K ----
// WM=6: f32 partials Cf; WM=3: bf16 partials Ch. zstride = elements per split slice.
template<int WM>
__global__ __launch_bounds__(256) void mfma_sq(
    const unsigned short* __restrict__ Ah,
    const unsigned short* __restrict__ Bh,
    int Kc, int lda, int ldb,
    unsigned short* __restrict__ Ch, float* __restrict__ Cf, int ldc, size_t zstride)
{
    constexpr int A_USH = 128 * 64;           // 8192 ush (2 K-panels x 128 rows)
    constexpr int SLOT  = 2 * A_USH;          // 16384 ush = 32 KB
    __shared__ unsigned short lds[2 * SLOT];  // 64 KB ring-2

    const int t = threadIdx.x;
    const int w = t >> 6, l = t & 63;
    const int r = l & 15, g4 = l >> 4;
    const int wr = (w >> 1) * 64, wc = (w & 1) * 64;

    const int gx = gridDim.x;
    const int nwg = gx * gridDim.y;
    int flat = blockIdx.y * gx + blockIdx.x;
    int swz = (flat & 7) * (nwg >> 3) + (flat >> 3);
    const int col0 = (swz % gx) * 128;
    const int row0 = (swz / gx) * 128;

    const int z = blockIdx.z;
    Ah += (size_t)z * Kc;
    Bh += (size_t)z * Kc;
    if constexpr (WM == 6) Cf += (size_t)z * zstride;
    else                   Ch += (size_t)z * zstride;

    f32x4 acc[4][4];
    #pragma unroll
    for (int a = 0; a < 4; a++)
        #pragma unroll
        for (int b = 0; b < 4; b++) acc[a][b] = (f32x4){0.f, 0.f, 0.f, 0.f};

    auto stage = [&](int slot, int k0) {      // 8 loads/thread
        unsigned short* base = lds + slot * SLOT;
        stg_mat<512, 4>(Ah, lda, row0, k0, base, t);
        stg_mat<512, 4>(Bh, ldb, col0, k0, base + A_USH, t);
    };

    const int T = Kc >> 6;
    stage(0, 0);

    for (int tt = 0; tt < T; ++tt) {
        __builtin_amdgcn_s_barrier();
        if (tt + 1 < T) {
            stage((tt + 1) & 1, (tt + 1) * 64);
            asm volatile("s_waitcnt vmcnt(8)" ::: "memory");   // oldest 8 (tile tt) landed
        } else {
            asm volatile("s_waitcnt vmcnt(0)" ::: "memory");
        }
        __builtin_amdgcn_s_barrier();

        const unsigned short* base = lds + (tt & 1) * SLOT;
        #pragma unroll
        for (int kk = 0; kk < 2; kk++) {
            s16x8 a[4], bb[4];
            #pragma unroll
            for (int f = 0; f < 4; f++) a[f] = rfrag<128>(base, wr + f * 16 + r, kk, g4);
            #pragma unroll
            for (int f = 0; f < 4; f++) bb[f] = rfrag<128>(base + A_USH, wc + f * 16 + r, kk, g4);
            __builtin_amdgcn_s_setprio(1);
            #pragma unroll
            for (int fm = 0; fm < 4; fm++)
                #pragma unroll
                for (int fn = 0; fn < 4; fn++)
                    acc[fm][fn] = MF(a[fm], bb[fn], acc[fm][fn]);
            __builtin_amdgcn_s_setprio(0);
        }
    }

    // epilogue (C/D: col = lane&15, row = 4*(lane>>4)+i)
    #pragma unroll
    for (int fn = 0; fn < 4; fn++) {
        int n = col0 + wc + fn * 16 + r;
        #pragma unroll
        for (int fm = 0; fm < 4; fm++) {
            int m0 = row0 + wr + fm * 16 + g4 * 4;
            f32x4 v = acc[fm][fn];
            #pragma unroll
            for (int i = 0; i < 4; i++) {
                if constexpr (WM == 6) Cf[(size_t)(m0 + i) * ldc + n] = v[i];
                else                   Ch[(size_t)(m0 + i) * ldc + n] = f2bh(v[i]);
            }
        }
    }
}

// ---------------- fallback f32 tiled GEMM (round-1, proven) ----------------
template<int TRANSB>
__global__ __launch_bounds__(256) void gemm_f32_128(
    const float* __restrict__ A, const float* __restrict__ B, float* __restrict__ C,
    int M, int N, int K, int lda, int ldb,
    const float* __restrict__ bias, const float* __restrict__ vrow, int do_relu)
{
    constexpr int BM = 128, BN = 128, BK = 16;
    __shared__ float As[BK][BM + 4];
    __shared__ float Bs[BK][BN + 4];
    const int t = threadIdx.x;
    const int w = t >> 6, l = t & 63;
    const int cx = (w & 1) * 8 + (l & 7);
    const int cy = (w >> 1) * 8 + (l >> 3);
    const int row0 = blockIdx.y * BM;
    const int col0 = blockIdx.x * BN;

    float acc[8][8];
    #pragma unroll
    for (int i = 0; i < 8; i++)
        #pragma unroll
        for (int j = 0; j < 8; j++) acc[i][j] = 0.f;

    const int ka = t & 15;
    const int ma = t >> 4;

    for (int k0 = 0; k0 < K; k0 += BK) {
        #pragma unroll
        for (int i = 0; i < 8; i++) {
            int m = ma + i * 16;
            int gk = k0 + ka;
            float v = 0.f;
            if (gk < K) v = A[(size_t)(row0 + m) * lda + gk];
            As[ka][m] = v;
        }
        if (TRANSB) {
            #pragma unroll
            for (int i = 0; i < 8; i++) {
                int n = ma + i * 16;
                int gk = k0 + ka;
                float v = 0.f;
                if (gk < K) v = B[(size_t)(col0 + n) * ldb + gk];
                Bs[ka][n] = v;
            }
        } else {
            const int nb = t & 127;
            const int kb = t >> 7;
            #pragma unroll
            for (int i = 0; i < 8; i++) {
                int kk = kb + i * 2;
                int gk = k0 + kk;
                float v = 0.f;
                if (gk < K) v = B[(size_t)gk * ldb + col0 + nb];
                Bs[kk][nb] = v;
            }
        }
        __syncthreads();
        #pragma unroll
        for (int kk = 0; kk < BK; kk++) {
            float a[8], bb[8];
            *(float4*)&a[0]  = *(const float4*)&As[kk][cy * 8];
            *(float4*)&a[4]  = *(const float4*)&As[kk][cy * 8 + 4];
            *(float4*)&bb[0] = *(const float4*)&Bs[kk][cx * 8];
            *(float4*)&bb[4] = *(const float4*)&Bs[kk][cx * 8 + 4];
            #pragma unroll
            for (int i = 0; i < 8; i++)
                #pragma unroll
                for (int j = 0; j < 8; j++)
                    acc[i][j] = fmaf(a[i], bb[j], acc[i][j]);
        }
        __syncthreads();
    }

    #pragma unroll
    for (int i = 0; i < 8; i++) {
        int rr = row0 + cy * 8 + i;
        float vv[8];
        #pragma unroll
        for (int j = 0; j < 8; j++) {
            int c = col0 + cx * 8 + j;
            float v = acc[i][j];
            if (vrow) v += vrow[c];
            if (bias) v += bias[c];
            if (do_relu) v = fmaxf(v, 0.f);
            vv[j] = v;
        }
        float* cp = C + (size_t)rr * N + col0 + cx * 8;
        *(float4*)cp       = *(float4*)&vv[0];
        *(float4*)(cp + 4) = *(float4*)&vv[4];
    }
}

// ---------------- host launcher ----------------
extern "C" void kernel_launch(void* const* d_in, const int* in_sizes, int n_in,
                              void* d_out, int out_size, void* d_ws, size_t ws_size,
                              hipStream_t stream) {
    const float* frames     = (const float*)d_in[0];
    const float* scores     = (const float*)d_in[1];
    const float* word_embed = (const float*)d_in[2];
    const float* all_embeds = (const float*)d_in[3];
    const float* adj        = (const float*)d_in[4];
    const float* visual_W   = (const float*)d_in[5];
    const float* visual_b   = (const float*)d_in[6];
    const float* semantic_W = (const float*)d_in[7];
    const float* semantic_b = (const float*)d_in[8];
    const float* score_W    = (const float*)d_in[9];
    const float* score_b    = (const float*)d_in[10];
    const float* gc1_W      = (const float*)d_in[11];
    const float* gc1_b      = (const float*)d_in[12];
    const float* gc2_W      = (const float*)d_in[13];
    const float* gc2_b      = (const float*)d_in[14];
    const float* gc3_W      = (const float*)d_in[15];
    const float* gc3_b      = (const float*)d_in[16];
    const float* gcn512_W   = (const float*)d_in[17];
    const float* gcn512_b   = (const float*)d_in[18];
    const float* hidden_W   = (const float*)d_in[19];
    const float* hidden_b   = (const float*)d_in[20];
    const float* critic_W   = (const float*)d_in[21];
    const float* critic_b   = (const float*)d_in[22];
    const float* actor_W    = (const float*)d_in[23];
    const float* actor_b    = (const float*)d_in[24];

    float* out = (float*)d_out;

    if (ws_size >= FAST_WS) {
        char* wsb = (char*)d_ws;
        unsigned short* adj_h = (unsigned short*)(wsb + F_ADJH);
        unsigned short* emb_h = (unsigned short*)(wsb + F_EMB_H);
        unsigned short* emb_l = (unsigned short*)(wsb + F_EMB_L);
        unsigned short* sw_h  = (unsigned short*)(wsb + F_SW_H);
        unsigned short* sw_l  = (unsigned short*)(wsb + F_SW_L);
        unsigned short* w1t_h = (unsigned short*)(wsb + F_W1T_H);
        unsigned short* w2t_h = (unsigned short*)(wsb + F_W2T_H);
        unsigned short* emT   = (unsigned short*)(wsb + F_EMT);
        unsigned short* p1p   = (unsigned short*)(wsb + F_P1P);
        unsigned short* p1_h  = (unsigned short*)(wsb + F_P1H);
        unsigned short* h1    = (unsigned short*)(wsb + F_H1);
        unsigned short* y2t   = (unsigned short*)(wsb + F_Y2T);
        float*          p7f   = (float*)(wsb + F_P7F);
        float*          vec   = (float*)(wsb + F_VEC);

        // 1. prep: all converts + vec3 (ILP-4 streaming)
        prep_kernel<<<4096 + 1280 + 160 + 512 + 1024 + 1536, 256, 0, stream>>>(
            adj, all_embeds, semantic_W, gc1_W, gc2_W,
            frames, scores, word_embed, visual_W, visual_b, semantic_b, score_W, score_b,
            adj_h, emb_h, emb_l, sw_h, sw_l, w1t_h, w2t_h, vec);
        // 2. vrow = s512 @ gc1_W[:512,:]
        vrow_kernel<<<8, 256, 0, stream>>>(gc1_W, vec);
        // 3. emT = relu(all_embeds @ semantic_W^T + b)^T  hi [512,4096], K=320, PROD=3
        mfma_g<64, 32, 3, 4, 1, 0><<<dim3(8, 64), 256, 0, stream>>>(
            emb_h, emb_l, sw_h, sw_l, 320, 320, 320,
            emT, nullptr, 4096, semantic_b, nullptr);
        // 4. p1p partials = adj @ em  bf16, square tiles BK=64, split-K x4  [4096,512]
        mfma_sq<3><<<dim3(4, 32, 4), 256, 0, stream>>>(
            adj_h, emT, 1024, 4096, 4096, p1p, nullptr, 512, 2097152);
        // 4b. combine 4 bf16 partials -> p1 hi
        combine_p1_kernel<<<2048, 256, 0, stream>>>(p1p, p1_h);
        // 5. h1 = relu(P1_hi @ W1'_hi + vrow + b1)  hi [4096,1024], K=512, PROD=1
        mfma_g<128, 64, 1, 3, 1, 0><<<dim3(16, 32), 256, 0, stream>>>(
            p1_h, nullptr, w1t_h, nullptr, 512, 512, 512,
            h1, nullptr, 1024, gc1_b, vec + OFF_VROW);
        // 6. y2t = (h1 @ gc2_W)^T  hi [1024,4096], K=1024
        mfma_g<128, 64, 1, 4, 0, 0><<<dim3(16, 32), 256, 0, stream>>>(
            h1, nullptr, w2t_h, nullptr, 1024, 1024, 1024,
            y2t, nullptr, 4096, nullptr, nullptr);
        // 7. p7f partials = adj @ Y2  f32, square tiles BK=64, split-K x2  [4096,1024]
        mfma_sq<6><<<dim3(8, 32, 2), 256, 0, stream>>>(
            adj_h, y2t, 2048, 4096, 4096, nullptr, p7f, 1024, 4194304);
        // 7b. y3[i] = sum_j relu(p7f0+p7f1+b2)[i,j] * gc3_W[j]
        h2y3_kernel<<<4096, 256, 0, stream>>>(p7f, gc2_b, gc3_W, vec);
        // 8-11. tail
        h3b_kernel<<<4096, 256, 0, stream>>>(adj_h, gc3_b, vec);
        gcn_kernel<<<512, 256, 0, stream>>>(gcn512_W, gcn512_b, vec);
        x_kernel<<<512, 256, 0, stream>>>(hidden_W, hidden_b, vec);
        out_kernel<<<1, 512, 0, stream>>>(vec, critic_W, critic_b, actor_W, actor_b, out);
    } else {
        // fallback f32 path (round-1, proven within 50.4 MB)
        float* ws = (float*)d_ws;
        float* em = ws + OFF_BUF0;
        float* Y1 = ws + OFF_BUF1;
        float* H1 = ws + OFF_BUF2;
        float* Y2 = ws + OFF_BUF1;
        float* H2 = ws + OFF_BUF0;

        vec3_kernel<<<1536, 256, 0, stream>>>(frames, scores, word_embed,
                                              visual_W, visual_b, semantic_W, semantic_b,
                                              score_W, score_b, ws);
        vrow_kernel<<<8, 256, 0, stream>>>(gc1_W, ws);
        gemm_f32_128<1><<<dim3(512 / 128, 4096 / 128), 256, 0, stream>>>(
            all_embeds, semantic_W, em, 4096, 512, 300, 300, 300, semantic_b, nullptr, 1);
        gemm_f32_128<0><<<dim3(1024 / 128, 4096 / 128), 256, 0, stream>>>(
            em, gc1_W + (size_t)512 * 1024, Y1, 4096, 1024, 512, 512, 1024,
            nullptr, ws + OFF_VROW, 0);
        gemm_f32_128<0><<<dim3(1024 / 128, 4096 / 128), 256, 0, stream>>>(
            adj, Y1, H1, 4096, 1024, 4096, 4096, 1024, gc1_b, nullptr, 1);
        gemm_f32_128<0><<<dim3(1024 / 128, 4096 / 128), 256, 0, stream>>>(
            H1, gc2_W, Y2, 4096, 1024, 1024, 1024, 1024, nullptr, nullptr, 0);
        gemm_f32_128<0><<<dim3(1024 / 128, 4096 / 128), 256, 0, stream>>>(
            adj, Y2, H2, 4096, 1024, 4096, 4096, 1024, gc2_b, nullptr, 1);
        y3_kernel<<<4096, 256, 0, stream>>>(H2, gc3_W, ws);
        h3_kernel<<<4096, 256, 0, stream>>>(adj, gc3_b, ws);
        gcn_kernel<<<512, 256, 0, stream>>>(gcn512_W, gcn512_b, ws);
        x_kernel<<<512, 256, 0, stream>>>(hidden_W, hidden_b, ws);
        out_kernel<<<1, 512, 0, stream>>>(ws, critic_W, critic_b, actor_W, actor_b, out);
    }

    (void)in_sizes; (void)n_in; (void)out_size;
}

// Round 14
// 173.538 us; speedup vs baseline: 1.1027x; 1.0123x over previous
//
#include <hip/hip_runtime.h>
#include <cstddef>
#include <cstdint>

typedef short  s16x8 __attribute__((ext_vector_type(8)));
typedef float  f32x4 __attribute__((ext_vector_type(4)));
typedef unsigned short u16x4 __attribute__((ext_vector_type(4)));
typedef unsigned short u16x8 __attribute__((ext_vector_type(8)));

typedef __attribute__((address_space(1))) const void gas_void;
typedef __attribute__((address_space(3))) void las_void;

// ---------------- bf16 helpers ----------------
__device__ __forceinline__ unsigned short f2bh(float x) {
    union { float f; unsigned int u; } c; c.f = x;
    unsigned int r = c.u + 0x7fffu + ((c.u >> 16) & 1u);
    return (unsigned short)(r >> 16);
}
__device__ __forceinline__ float bh2f(unsigned short h) {
    union { unsigned int u; float f; } c; c.u = ((unsigned int)h) << 16;
    return c.f;
}
__device__ __forceinline__ f32x4 MF(s16x8 a, s16x8 b, f32x4 c) {
    return __builtin_amdgcn_mfma_f32_16x16x32_bf16(a, b, c, 0, 0, 0);
}
__device__ __forceinline__ void gload16(const unsigned short* g, unsigned short* l) {
    __builtin_amdgcn_global_load_lds((gas_void*)g, (las_void*)l, 16, 0, 0);
}

// ---------------- vec region offsets (floats) ----------------
static constexpr size_t OFF_VIS  = 0;
static constexpr size_t OFF_SEM  = 512;
static constexpr size_t OFF_GCN  = 1024;
static constexpr size_t OFF_S512 = 1536;
static constexpr size_t OFF_VROW = 2048;
static constexpr size_t OFF_X    = 3072;
static constexpr size_t OFF_Y3   = 4096;
static constexpr size_t OFF_H3   = 8192;
// fallback big buffers (floats, absolute in ws)
static constexpr size_t OFF_BUF0 = 16384;
static constexpr size_t OFF_BUF1 = OFF_BUF0 + 4194304;
static constexpr size_t OFF_BUF2 = OFF_BUF1 + 4194304;

// ---------------- fast-path ws layout (bytes) ----------------
static constexpr size_t F_ADJH  = 0;                          // 33,554,432
static constexpr size_t F_SCR   = 33554432;                   // 33,554,432 scratch
static constexpr size_t F_EMB_H = F_SCR;                      // 2,621,440
static constexpr size_t F_EMB_L = F_SCR + 2621440;            // 2,621,440
static constexpr size_t F_SW_H  = F_SCR + 5242880;            // 327,680
static constexpr size_t F_SW_L  = F_SCR + 5570560;            // 327,680
static constexpr size_t F_W1T_H = F_SCR + 5898240;            // 1,048,576
static constexpr size_t F_W2T_H = F_SCR + 6946816;            // 2,097,152
static constexpr size_t F_EMT   = F_SCR + 9043968;            // 4,194,304
static constexpr size_t F_P1P   = F_SCR + 16777216;           // 16,777,216 (#4 bf16 partials x4)
static constexpr size_t F_H1    = F_SCR + 16777216;           // 8,388,608 (after p1p dead)
static constexpr size_t F_P7H   = F_SCR;                      // 16,777,216 (#7 bf16 partials x2)
static constexpr size_t F_P1H   = 67108864;                   // 4,194,304
static constexpr size_t F_Y2T   = 71303168;                   // 8,388,608
static constexpr size_t F_VEC   = 79691776;                   // 49,152
static constexpr size_t FAST_WS = 79740928;                   // ~76.0 MB

// ---------------- block reduction ----------------
__device__ inline float blockReduceSum256(float v) {
    #pragma unroll
    for (int o = 32; o > 0; o >>= 1) v += __shfl_down(v, o, 64);
    __shared__ float red[4];
    int w = threadIdx.x >> 6;
    if ((threadIdx.x & 63) == 0) red[w] = v;
    __syncthreads();
    if (threadIdx.x == 0) v = red[0] + red[1] + red[2] + red[3];
    return v;
}

// ---------------- vec3 body (visual branch float4-vectorized) ----------------
__device__ __forceinline__ void vec3_body(int b,
                            const float* __restrict__ frames,
                            const float* __restrict__ scores,
                            const float* __restrict__ word_embed,
                            const float* __restrict__ visual_W, const float* __restrict__ visual_b,
                            const float* __restrict__ semantic_W, const float* __restrict__ semantic_b,
                            const float* __restrict__ score_W, const float* __restrict__ score_b,
                            float* __restrict__ vec) {
    if (b < 512) {
        int row = b;
        const float4* w4 = (const float4*)(visual_W + (size_t)row * 8192);
        const float4* x4 = (const float4*)frames;
        float s = 0.f;
        #pragma unroll
        for (int c0 = 0; c0 < 2048; c0 += 256) {
            int c = c0 + threadIdx.x;
            float4 wv = w4[c], xv = x4[c];
            s += wv.x * xv.x + wv.y * xv.y + wv.z * xv.z + wv.w * xv.w;
        }
        s = blockReduceSum256(s);
        if (threadIdx.x == 0) (vec + OFF_VIS)[row] = fmaxf(s + visual_b[row], 0.f);
        return;
    }
    const float* x; const float* W; const float* bias; float* out; int K; int row;
    if (b < 1024) { row = b - 512;  x = word_embed; W = semantic_W; bias = semantic_b; out = vec + OFF_SEM;  K = 300;  }
    else          { row = b - 1024; x = scores;     W = score_W;    bias = score_b;    out = vec + OFF_S512; K = 1000; }
    const float* wr = W + (size_t)row * K;
    float s = 0.f;
    for (int k = threadIdx.x; k < K; k += 256) s += wr[k] * x[k];
    s = blockReduceSum256(s);
    if (threadIdx.x == 0) out[row] = fmaxf(s + bias[row], 0.f);
}

// ---------------- small kernels ----------------
__global__ void vec3_kernel(const float* __restrict__ frames,
                            const float* __restrict__ scores,
                            const float* __restrict__ word_embed,
                            const float* __restrict__ visual_W, const float* __restrict__ visual_b,
                            const float* __restrict__ semantic_W, const float* __restrict__ semantic_b,
                            const float* __restrict__ score_W, const float* __restrict__ score_b,
                            float* __restrict__ vec) {
    vec3_body(blockIdx.x, frames, scores, word_embed, visual_W, visual_b,
              semantic_W, semantic_b, score_W, score_b, vec);
}

__global__ void vrow_kernel(const float* __restrict__ gc1_W, float* __restrict__ vec) {
    __shared__ float part[128];
    const float* s512 = vec + OFF_S512;
    int jl = threadIdx.x & 127;
    int j = blockIdx.x * 128 + jl;
    int kh = threadIdx.x >> 7;
    float s = 0.f;
    #pragma unroll 4
    for (int k = kh * 256; k < kh * 256 + 256; k++)
        s += s512[k] * gc1_W[(size_t)k * 1024 + j];
    if (kh) part[jl] = s;
    __syncthreads();
    if (!kh) vec[OFF_VROW + j] = s + part[jl];
}

__global__ void y3_kernel(const float* __restrict__ H2, const float* __restrict__ gc3_W,
                          float* __restrict__ vec) {
    int i = blockIdx.x;
    const float* r = H2 + (size_t)i * 1024;
    float s = 0.f;
    for (int k = threadIdx.x; k < 1024; k += 256) s += r[k] * gc3_W[k];
    s = blockReduceSum256(s);
    if (threadIdx.x == 0) vec[OFF_Y3 + i] = s;
}

// fused: y3[i] = sum_j relu(sum_z p7h[z][i,j] + gc2_b[j]) * gc3_W[j]   (2 bf16 partials)
__global__ void h2y3_kernel(const unsigned short* __restrict__ p7h, const float* __restrict__ gc2_b,
                            const float* __restrict__ gc3_W, float* __restrict__ vec) {
    int i = blockIdx.x;
    int c = threadIdx.x;   // 256 threads x 4 cols = 1024
    float a0 = 0.f, a1 = 0.f, a2 = 0.f, a3 = 0.f;
    #pragma unroll
    for (int z = 0; z < 2; z++) {
        u16x4 v = *(const u16x4*)(p7h + (size_t)z * 4194304 + (size_t)i * 1024 + c * 4);
        a0 += bh2f(v[0]); a1 += bh2f(v[1]); a2 += bh2f(v[2]); a3 += bh2f(v[3]);
    }
    float4 bb = ((const float4*)gc2_b)[c];
    float4 ww = ((const float4*)gc3_W)[c];
    float s = fmaxf(a0 + bb.x, 0.f) * ww.x
            + fmaxf(a1 + bb.y, 0.f) * ww.y
            + fmaxf(a2 + bb.z, 0.f) * ww.z
            + fmaxf(a3 + bb.w, 0.f) * ww.w;
    s = blockReduceSum256(s);
    if (threadIdx.x == 0) vec[OFF_Y3 + i] = s;
}

// h3 from bf16 adj
__global__ void h3b_kernel(const unsigned short* __restrict__ adj_h,
                           const float* __restrict__ gc3_b, float* __restrict__ vec) {
    int i = blockIdx.x;
    const u16x4* rp = (const u16x4*)(adj_h + (size_t)i * 4096);
    const float* y3 = vec + OFF_Y3;
    float s = 0.f;
    for (int c = threadIdx.x; c < 1024; c += 256) {
        u16x4 v = rp[c];
        int k0 = c * 4;
        s += bh2f(v[0]) * y3[k0] + bh2f(v[1]) * y3[k0 + 1]
           + bh2f(v[2]) * y3[k0 + 2] + bh2f(v[3]) * y3[k0 + 3];
    }
    s = blockReduceSum256(s);
    if (threadIdx.x == 0) vec[OFF_H3 + i] = fmaxf(s + gc3_b[0], 0.f);
}

__global__ void h3_kernel(const float* __restrict__ adj, const float* __restrict__ gc3_b,
                          float* __restrict__ vec) {
    int i = blockIdx.x;
    const float* r = adj + (size_t)i * 4096;
    const float* y3 = vec + OFF_Y3;
    float s = 0.f;
    for (int k = threadIdx.x; k < 4096; k += 256) s += r[k] * y3[k];
    s = blockReduceSum256(s);
    if (threadIdx.x == 0) vec[OFF_H3 + i] = fmaxf(s + gc3_b[0], 0.f);
}

__global__ void gcn_kernel(const float* __restrict__ gcn512_W, const float* __restrict__ gcn512_b,
                           float* __restrict__ vec) {
    int j = blockIdx.x;
    const float* r = gcn512_W + (size_t)j * 4096;
    const float* h3 = vec + OFF_H3;
    float s = 0.f;
    for (int k = threadIdx.x; k < 4096; k += 256) s += r[k] * h3[k];
    s = blockReduceSum256(s);
    if (threadIdx.x == 0) vec[OFF_GCN + j] = fmaxf(s + gcn512_b[j], 0.f);
}

__global__ void x_kernel(const float* __restrict__ hidden_W, const float* __restrict__ hidden_b,
                         float* __restrict__ vec) {
    int j = blockIdx.x;
    const float* r = hidden_W + (size_t)j * 1536;
    const float* joint = vec;
    float s = 0.f;
    for (int k = threadIdx.x; k < 1536; k += 256) s += r[k] * joint[k];
    s = blockReduceSum256(s);
    if (threadIdx.x == 0) vec[OFF_X + j] = fmaxf(s + hidden_b[j], 0.f);
}

__global__ void out_kernel(const float* __restrict__ vec,
                           const float* __restrict__ critic_W, const float* __restrict__ critic_b,
                           const float* __restrict__ actor_W, const float* __restrict__ actor_b,
                           float* __restrict__ out) {
    const float* xv = vec + OFF_X;
    int w = threadIdx.x >> 6, l = threadIdx.x & 63;
    if (w >= 7) return;
    const float* row = (w == 0) ? critic_W : actor_W + (size_t)(w - 1) * 512;
    float s = 0.f;
    for (int q = l; q < 512; q += 64) s += xv[q] * row[q];
    #pragma unroll
    for (int o = 32; o > 0; o >>= 1) s += __shfl_down(s, o, 64);
    if (l == 0) out[w] = s + ((w == 0) ? critic_b[0] : actor_b[w - 1]);
}

// combine P1 split-K bf16 partials (x4) -> hi bf16
__global__ void combine_p1_kernel(const unsigned short* __restrict__ p1p,
                                  unsigned short* __restrict__ hi) {
    size_t i = (size_t)blockIdx.x * 256 + threadIdx.x;    // u16x4 index over 524288
    float s0 = 0.f, s1 = 0.f, s2 = 0.f, s3 = 0.f;
    #pragma unroll
    for (int z = 0; z < 4; z++) {
        u16x4 v = *(const u16x4*)(p1p + (size_t)z * 2097152 + i * 4);
        s0 += bh2f(v[0]); s1 += bh2f(v[1]); s2 += bh2f(v[2]); s3 += bh2f(v[3]);
    }
    u16x4 hv;
    hv[0] = f2bh(s0); hv[1] = f2bh(s1); hv[2] = f2bh(s2); hv[3] = f2bh(s3);
    *(u16x4*)(hi + i * 4) = hv;
}

// ---------------- fused prep kernel: all converts + vec3 ----------------
// grid: [0,2048) adj x8/16B-store | [,+1280) emb x4 | [,+160) sw x4 |
// [,+512) w1T | [,+1024) w2T | [,+1536) vec3
__global__ void prep_kernel(const float* __restrict__ adj,
                            const float* __restrict__ all_embeds,
                            const float* __restrict__ semantic_W,
                            const float* __restrict__ gc1_W,
                            const float* __restrict__ gc2_W,
                            const float* __restrict__ frames,
                            const float* __restrict__ scores,
                            const float* __restrict__ word_embed,
                            const float* __restrict__ visual_W, const float* __restrict__ visual_b,
                            const float* __restrict__ semantic_b,
                            const float* __restrict__ score_W, const float* __restrict__ score_b,
                            unsigned short* __restrict__ adj_h,
                            unsigned short* __restrict__ emb_h, unsigned short* __restrict__ emb_l,
                            unsigned short* __restrict__ sw_h, unsigned short* __restrict__ sw_l,
                            unsigned short* __restrict__ w1t_h,
                            unsigned short* __restrict__ w2t_h,
                            float* __restrict__ vec) {
    __shared__ float tile[32][33];
    const int b = blockIdx.x, t = threadIdx.x;
    if (b < 2048) {
        // adj f32 -> bf16: 8 float4 loads (4 consecutive pairs), 4 x 16B stores
        size_t base = (size_t)b * 2048 + t * 2;   // float4 index
        float4 v[8];
        #pragma unroll
        for (int j = 0; j < 4; j++) {
            v[2 * j]     = ((const float4*)adj)[base + j * 512];
            v[2 * j + 1] = ((const float4*)adj)[base + j * 512 + 1];
        }
        #pragma unroll
        for (int j = 0; j < 4; j++) {
            u16x8 h;
            h[0] = f2bh(v[2 * j].x);     h[1] = f2bh(v[2 * j].y);
            h[2] = f2bh(v[2 * j].z);     h[3] = f2bh(v[2 * j].w);
            h[4] = f2bh(v[2 * j + 1].x); h[5] = f2bh(v[2 * j + 1].y);
            h[6] = f2bh(v[2 * j + 1].z); h[7] = f2bh(v[2 * j + 1].w);
            *(u16x8*)(adj_h + (base + j * 512) * 4) = h;
        }
    } else if (b < 2048 + 1280) {
        size_t base = (size_t)(b - 2048) * 256 + t;
        float v[4];
        #pragma unroll
        for (int j = 0; j < 4; j++) {
            size_t i = base + (size_t)j * 327680;
            int r = (int)(i / 320), c = (int)(i % 320);
            v[j] = (c < 300) ? all_embeds[(size_t)r * 300 + c] : 0.f;
        }
        #pragma unroll
        for (int j = 0; j < 4; j++) {
            size_t i = base + (size_t)j * 327680;
            unsigned short h = f2bh(v[j]);
            emb_h[i] = h; emb_l[i] = f2bh(v[j] - bh2f(h));
        }
    } else if (b < 2048 + 1280 + 160) {
        size_t base = (size_t)(b - 2048 - 1280) * 256 + t;
        float v[4];
        #pragma unroll
        for (int j = 0; j < 4; j++) {
            size_t i = base + (size_t)j * 40960;
            int r = (int)(i / 320), c = (int)(i % 320);
            v[j] = (c < 300) ? semantic_W[(size_t)r * 300 + c] : 0.f;
        }
        #pragma unroll
        for (int j = 0; j < 4; j++) {
            size_t i = base + (size_t)j * 40960;
            unsigned short h = f2bh(v[j]);
            sw_h[i] = h; sw_l[i] = f2bh(v[j] - bh2f(h));
        }
    } else if (b < 2048 + 1280 + 160 + 512) {
        int l2 = b - 2048 - 1280 - 160;
        const float* src = gc1_W + (size_t)512 * 1024;
        int kb = (l2 & 15) * 32, nb = (l2 >> 4) * 32;
        int tx = t & 31, ty = t >> 5;
        #pragma unroll
        for (int i = 0; i < 32; i += 8)
            tile[ty + i][tx] = src[(size_t)(kb + ty + i) * 1024 + nb + tx];
        __syncthreads();
        #pragma unroll
        for (int i = 0; i < 32; i += 8) {
            int n = nb + ty + i, k = kb + tx;
            w1t_h[(size_t)n * 512 + k] = f2bh(tile[tx][ty + i]);
        }
    } else if (b < 2048 + 1280 + 160 + 512 + 1024) {
        int l2 = b - 2048 - 1280 - 160 - 512;
        int kb = (l2 & 31) * 32, nb = (l2 >> 5) * 32;
        int tx = t & 31, ty = t >> 5;
        #pragma unroll
        for (int i = 0; i < 32; i += 8)
            tile[ty + i][tx] = gc2_W[(size_t)(kb + ty + i) * 1024 + nb + tx];
        __syncthreads();
        #pragma unroll
        for (int i = 0; i < 32; i += 8) {
            int n = nb + ty + i, k = kb + tx;
            w2t_h[(size_t)n * 1024 + k] = f2bh(tile[tx][ty + i]);
        }
    } else {
        vec3_body(b - (2048 + 1280 + 160 + 512 + 1024), frames, scores, word_embed,
                  visual_W, visual_b, semantic_W, semantic_b, score_W, score_b, vec);
    }
}

// ---------------- staging helpers ----------------
template<int NCHP, int NJ>
__device__ __forceinline__ void stg_mat(const unsigned short* __restrict__ src, int ld, int r0,
                                        int k0, unsigned short* dst, int t) {
    #pragma unroll
    for (int j = 0; j < NJ; j++) {
        int c = j * 256 + t;
        int p = c / NCHP;
        int idx = c % NCHP;
        int row = idx >> 2;
        int gg = (idx & 3) ^ ((row >> 1) & 3);
        gload16(src + (size_t)(r0 + row) * ld + (k0 + p * 32 + gg * 8),
                dst + (size_t)(j * 256 + (t & ~63)) * 8);
    }
}

template<int ROWS>
__device__ __forceinline__ s16x8 rfrag(const unsigned short* rb, int row, int p, int g4) {
    int byte = (p * ROWS + row) * 64 + ((g4 ^ ((row >> 1) & 3)) << 4);
    return *(const s16x8*)((const char*)rb + byte);
}

// ---------------- 4-wave MFMA GEMM (proven ring-3 counted structure) ----------------
template<int BM, int BK, int PROD, int WMODE, int RELU, int SPLITK>
__global__ __launch_bounds__(256) void mfma_g(
    const unsigned short* __restrict__ Ah, const unsigned short* __restrict__ Al,
    const unsigned short* __restrict__ Bh, const unsigned short* __restrict__ Bl,
    int K, int lda, int ldb,
    unsigned short* __restrict__ Ch, float* __restrict__ Cf, int ldc,
    const float* __restrict__ bias, const float* __restrict__ bias2)
{
    constexpr int A_USH = BM * BK;
    constexpr int B_USH = 64 * BK;
    constexpr int A_CH  = A_USH / 8;
    constexpr int B_CH  = B_USH / 8;
    constexpr int SLOT  = (PROD == 3) ? 2 * (A_USH + B_USH) : (A_USH + B_USH);
    constexpr int L     = ((A_CH + B_CH) / 256) * ((PROD == 3) ? 2 : 1);
    constexpr int FM    = BM / 32;
    __shared__ unsigned short lds[3 * SLOT];

    const int t = threadIdx.x;
    const int w = t >> 6, l = t & 63;
    const int r = l & 15, g4 = l >> 4;
    const int wr = (w >> 1) * (BM / 2);
    const int wc = (w & 1) * 32;

    const int gx = gridDim.x;
    const int nwg = gx * gridDim.y;
    int flat = blockIdx.y * gx + blockIdx.x;
    int swz = (flat & 7) * (nwg >> 3) + (flat >> 3);
    const int col0 = (swz % gx) * 64;
    const int row0 = (swz / gx) * BM;

    if constexpr (SPLITK) {
        int z = blockIdx.z;
        Ah += (size_t)z * K;
        Bh += (size_t)z * K;
        if (Cf) Cf += (size_t)z * (size_t)nwg * (BM * 64);
        if (Ch) Ch += (size_t)z * (size_t)nwg * (BM * 64);
    }

    f32x4 acc[FM][2];
    #pragma unroll
    for (int a = 0; a < FM; a++)
        #pragma unroll
        for (int b = 0; b < 2; b++) acc[a][b] = (f32x4){0.f, 0.f, 0.f, 0.f};

    auto stage = [&](int slot, int k0) {
        unsigned short* base = lds + slot * SLOT;
        stg_mat<BM * 4, A_CH / 256>(Ah, lda, row0, k0, base, t);
        stg_mat<256,    B_CH / 256>(Bh, ldb, col0, k0, base + A_USH, t);
        if constexpr (PROD == 3) {
            stg_mat<256,    B_CH / 256>(Bl, ldb, col0, k0, base + A_USH + B_USH, t);
            stg_mat<BM * 4, A_CH / 256>(Al, lda, row0, k0, base + A_USH + 2 * B_USH, t);
        }
    };

    const int T = K / BK;
    stage(0, 0);
    stage(1, BK);

    for (int tt = 0; tt < T; ++tt) {
        __builtin_amdgcn_s_barrier();
        if (tt + 2 < T) {
            stage((tt + 2) % 3, (tt + 2) * BK);
            if constexpr (L == 4)      asm volatile("s_waitcnt vmcnt(8)" ::: "memory");
            else if constexpr (L == 6) asm volatile("s_waitcnt vmcnt(12)" ::: "memory");
            else                       asm volatile("s_waitcnt vmcnt(16)" ::: "memory");
        } else if (tt + 1 < T) {
            if constexpr (L == 4)      asm volatile("s_waitcnt vmcnt(4)" ::: "memory");
            else if constexpr (L == 6) asm volatile("s_waitcnt vmcnt(6)" ::: "memory");
            else                       asm volatile("s_waitcnt vmcnt(8)" ::: "memory");
        } else {
            asm volatile("s_waitcnt vmcnt(0)" ::: "memory");
        }
        __builtin_amdgcn_s_barrier();

        const unsigned short* base = lds + (tt % 3) * SLOT;
        #pragma unroll
        for (int kk = 0; kk < BK / 32; kk++) {
            s16x8 a[FM], bb[2], alr[FM], blr[2];
            #pragma unroll
            for (int f = 0; f < FM; f++) a[f] = rfrag<BM>(base, wr + f * 16 + r, kk, g4);
            #pragma unroll
            for (int f = 0; f < 2; f++) bb[f] = rfrag<64>(base + A_USH, wc + f * 16 + r, kk, g4);
            if constexpr (PROD == 3) {
                #pragma unroll
                for (int f = 0; f < 2; f++) blr[f] = rfrag<64>(base + A_USH + B_USH, wc + f * 16 + r, kk, g4);
                #pragma unroll
                for (int f = 0; f < FM; f++) alr[f] = rfrag<BM>(base + A_USH + 2 * B_USH, wr + f * 16 + r, kk, g4);
            }
            __builtin_amdgcn_s_setprio(1);
            #pragma unroll
            for (int fm = 0; fm < FM; fm++)
                #pragma unroll
                for (int fn = 0; fn < 2; fn++) {
                    acc[fm][fn] = MF(a[fm], bb[fn], acc[fm][fn]);
                    if constexpr (PROD == 3) {
                        acc[fm][fn] = MF(a[fm], blr[fn], acc[fm][fn]);
                        acc[fm][fn] = MF(alr[fm], bb[fn], acc[fm][fn]);
                    }
                }
            __builtin_amdgcn_s_setprio(0);
        }
    }

    // epilogue (C/D: col = lane&15, row = 4*(lane>>4)+i — m89-verified)
    #pragma unroll
    for (int fn = 0; fn < 2; fn++) {
        int n = col0 + wc + fn * 16 + r;
        float bn = bias ? bias[n] : 0.f;
        if (bias2) bn += bias2[n];
        #pragma unroll
        for (int fm = 0; fm < FM; fm++) {
            int m0 = row0 + wr + fm * 16 + g4 * 4;
            f32x4 v = acc[fm][fn];
            if constexpr (WMODE == 4) {
                u16x4 hv;
                #pragma unroll
                for (int i = 0; i < 4; i++) {
                    float x = v[i] + bn;
                    if (RELU) x = fmaxf(x, 0.f);
                    hv[i] = f2bh(x);
                }
                *(u16x4*)(Ch + (size_t)n * ldc + m0) = hv;
            } else if constexpr (WMODE == 6) {
                #pragma unroll
                for (int i = 0; i < 4; i++) {
                    float x = v[i] + bn;
                    if (RELU) x = fmaxf(x, 0.f);
                    Cf[(size_t)(m0 + i) * ldc + n] = x;
                }
            } else {  // WMODE 3: hi bf16 C[m][n]
                #pragma unroll
                for (int i = 0; i < 4; i++) {
                    float x = v[i] + bn;
                    if (RELU) x = fmaxf(x, 0.f);
                    Ch[(size_t)(m0 + i) * ldc + n] = f2bh(x);
                }
            }
        }
    }
}

// ---------------- SQUARE-tile GEMM 128x128, wave 64x64, BK=64, ring-2 counted, split-K ----
// WM=6: f32 partials Cf; WM=3: bf16 partials Ch. zstride = elements per split slice.
template<int WM>
__global__ __launch_bounds__(256) void mfma_sq(
    const unsigned short* __restrict__ Ah,
    const unsigned short* __restrict__ Bh,
    int Kc, int lda, int ldb,
    unsigned short* __restrict__ Ch, float* __restrict__ Cf, int ldc, size_t zstride)
{
    constexpr int A_USH = 128 * 64;           // 8192 ush (2 K-panels x 128 rows)
    constexpr int SLOT  = 2 * A_USH;          // 16384 ush = 32 KB
    __shared__ unsigned short lds[2 * SLOT];  // 64 KB ring-2

    const int t = threadIdx.x;
    const int w = t >> 6, l = t & 63;
    const int r = l & 15, g4 = l >> 4;
    const int wr = (w >> 1) * 64, wc = (w & 1) * 64;

    const int gx = gridDim.x;
    const int nwg = gx * gridDim.y;
    int flat = blockIdx.y * gx + blockIdx.x;
    int swz = (flat & 7) * (nwg >> 3) + (flat >> 3);
    const int col0 = (swz % gx) * 128;
    const int row0 = (swz / gx) * 128;

    const int z = blockIdx.z;
    Ah += (size_t)z * Kc;
    Bh += (size_t)z * Kc;
    if constexpr (WM == 6) Cf += (size_t)z * zstride;
    else                   Ch += (size_t)z * zstride;

    f32x4 acc[4][4];
    #pragma unroll
    for (int a = 0; a < 4; a++)
        #pragma unroll
        for (int b = 0; b < 4; b++) acc[a][b] = (f32x4){0.f, 0.f, 0.f, 0.f};

    auto stage = [&](int slot, int k0) {      // 8 loads/thread
        unsigned short* base = lds + slot * SLOT;
        stg_mat<512, 4>(Ah, lda, row0, k0, base, t);
        stg_mat<512, 4>(Bh, ldb, col0, k0, base + A_USH, t);
    };

    const int T = Kc >> 6;
    stage(0, 0);

    for (int tt = 0; tt < T; ++tt) {
        __builtin_amdgcn_s_barrier();
        if (tt + 1 < T) {
            stage((tt + 1) & 1, (tt + 1) * 64);
            asm volatile("s_waitcnt vmcnt(8)" ::: "memory");   // oldest 8 (tile tt) landed
        } else {
            asm volatile("s_waitcnt vmcnt(0)" ::: "memory");
        }
        __builtin_amdgcn_s_barrier();

        const unsigned short* base = lds + (tt & 1) * SLOT;
        #pragma unroll
        for (int kk = 0; kk < 2; kk++) {
            s16x8 a[4], bb[4];
            #pragma unroll
            for (int f = 0; f < 4; f++) a[f] = rfrag<128>(base, wr + f * 16 + r, kk, g4);
            #pragma unroll
            for (int f = 0; f < 4; f++) bb[f] = rfrag<128>(base + A_USH, wc + f * 16 + r, kk, g4);
            __builtin_amdgcn_s_setprio(1);
            #pragma unroll
            for (int fm = 0; fm < 4; fm++)
                #pragma unroll
                for (int fn = 0; fn < 4; fn++)
                    acc[fm][fn] = MF(a[fm], bb[fn], acc[fm][fn]);
            __builtin_amdgcn_s_setprio(0);
        }
    }

    // epilogue (C/D: col = lane&15, row = 4*(lane>>4)+i)
    #pragma unroll
    for (int fn = 0; fn < 4; fn++) {
        int n = col0 + wc + fn * 16 + r;
        #pragma unroll
        for (int fm = 0; fm < 4; fm++) {
            int m0 = row0 + wr + fm * 16 + g4 * 4;
            f32x4 v = acc[fm][fn];
            #pragma unroll
            for (int i = 0; i < 4; i++) {
                if constexpr (WM == 6) Cf[(size_t)(m0 + i) * ldc + n] = v[i];
                else                   Ch[(size_t)(m0 + i) * ldc + n] = f2bh(v[i]);
            }
        }
    }
}

// ---------------- fallback f32 tiled GEMM (round-1, proven) ----------------
template<int TRANSB>
__global__ __launch_bounds__(256) void gemm_f32_128(
    const float* __restrict__ A, const float* __restrict__ B, float* __restrict__ C,
    int M, int N, int K, int lda, int ldb,
    const float* __restrict__ bias, const float* __restrict__ vrow, int do_relu)
{
    constexpr int BM = 128, BN = 128, BK = 16;
    __shared__ float As[BK][BM + 4];
    __shared__ float Bs[BK][BN + 4];
    const int t = threadIdx.x;
    const int w = t >> 6, l = t & 63;
    const int cx = (w & 1) * 8 + (l & 7);
    const int cy = (w >> 1) * 8 + (l >> 3);
    const int row0 = blockIdx.y * BM;
    const int col0 = blockIdx.x * BN;

    float acc[8][8];
    #pragma unroll
    for (int i = 0; i < 8; i++)
        #pragma unroll
        for (int j = 0; j < 8; j++) acc[i][j] = 0.f;

    const int ka = t & 15;
    const int ma = t >> 4;

    for (int k0 = 0; k0 < K; k0 += BK) {
        #pragma unroll
        for (int i = 0; i < 8; i++) {
            int m = ma + i * 16;
            int gk = k0 + ka;
            float v = 0.f;
            if (gk < K) v = A[(size_t)(row0 + m) * lda + gk];
            As[ka][m] = v;
        }
        if (TRANSB) {
            #pragma unroll
            for (int i = 0; i < 8; i++) {
                int n = ma + i * 16;
                int gk = k0 + ka;
                float v = 0.f;
                if (gk < K) v = B[(size_t)(col0 + n) * ldb + gk];
                Bs[ka][n] = v;
            }
        } else {
            const int nb = t & 127;
            const int kb = t >> 7;
            #pragma unroll
            for (int i = 0; i < 8; i++) {
                int kk = kb + i * 2;
                int gk = k0 + kk;
                float v = 0.f;
                if (gk < K) v = B[(size_t)gk * ldb + col0 + nb];
                Bs[kk][nb] = v;
            }
        }
        __syncthreads();
        #pragma unroll
        for (int kk = 0; kk < BK; kk++) {
            float a[8], bb[8];
            *(float4*)&a[0]  = *(const float4*)&As[kk][cy * 8];
            *(float4*)&a[4]  = *(const float4*)&As[kk][cy * 8 + 4];
            *(float4*)&bb[0] = *(const float4*)&Bs[kk][cx * 8];
            *(float4*)&bb[4] = *(const float4*)&Bs[kk][cx * 8 + 4];
            #pragma unroll
            for (int i = 0; i < 8; i++)
                #pragma unroll
                for (int j = 0; j < 8; j++)
                    acc[i][j] = fmaf(a[i], bb[j], acc[i][j]);
        }
        __syncthreads();
    }

    #pragma unroll
    for (int i = 0; i < 8; i++) {
        int rr = row0 + cy * 8 + i;
        float vv[8];
        #pragma unroll
        for (int j = 0; j < 8; j++) {
            int c = col0 + cx * 8 + j;
            float v = acc[i][j];
            if (vrow) v += vrow[c];
            if (bias) v += bias[c];
            if (do_relu) v = fmaxf(v, 0.f);
            vv[j] = v;
        }
        float* cp = C + (size_t)rr * N + col0 + cx * 8;
        *(float4*)cp       = *(float4*)&vv[0];
        *(float4*)(cp + 4) = *(float4*)&vv[4];
    }
}

// ---------------- host launcher ----------------
extern "C" void kernel_launch(void* const* d_in, const int* in_sizes, int n_in,
                              void* d_out, int out_size, void* d_ws, size_t ws_size,
                              hipStream_t stream) {
    const float* frames     = (const float*)d_in[0];
    const float* scores     = (const float*)d_in[1];
    const float* word_embed = (const float*)d_in[2];
    const float* all_embeds = (const float*)d_in[3];
    const float* adj        = (const float*)d_in[4];
    const float* visual_W   = (const float*)d_in[5];
    const float* visual_b   = (const float*)d_in[6];
    const float* semantic_W = (const float*)d_in[7];
    const float* semantic_b = (const float*)d_in[8];
    const float* score_W    = (const float*)d_in[9];
    const float* score_b    = (const float*)d_in[10];
    const float* gc1_W      = (const float*)d_in[11];
    const float* gc1_b      = (const float*)d_in[12];
    const float* gc2_W      = (const float*)d_in[13];
    const float* gc2_b      = (const float*)d_in[14];
    const float* gc3_W      = (const float*)d_in[15];
    const float* gc3_b      = (const float*)d_in[16];
    const float* gcn512_W   = (const float*)d_in[17];
    const float* gcn512_b   = (const float*)d_in[18];
    const float* hidden_W   = (const float*)d_in[19];
    const float* hidden_b   = (const float*)d_in[20];
    const float* critic_W   = (const float*)d_in[21];
    const float* critic_b   = (const float*)d_in[22];
    const float* actor_W    = (const float*)d_in[23];
    const float* actor_b    = (const float*)d_in[24];

    float* out = (float*)d_out;

    if (ws_size >= FAST_WS) {
        char* wsb = (char*)d_ws;
        unsigned short* adj_h = (unsigned short*)(wsb + F_ADJH);
        unsigned short* emb_h = (unsigned short*)(wsb + F_EMB_H);
        unsigned short* emb_l = (unsigned short*)(wsb + F_EMB_L);
        unsigned short* sw_h  = (unsigned short*)(wsb + F_SW_H);
        unsigned short* sw_l  = (unsigned short*)(wsb + F_SW_L);
        unsigned short* w1t_h = (unsigned short*)(wsb + F_W1T_H);
        unsigned short* w2t_h = (unsigned short*)(wsb + F_W2T_H);
        unsigned short* emT   = (unsigned short*)(wsb + F_EMT);
        unsigned short* p1p   = (unsigned short*)(wsb + F_P1P);
        unsigned short* p1_h  = (unsigned short*)(wsb + F_P1H);
        unsigned short* h1    = (unsigned short*)(wsb + F_H1);
        unsigned short* y2t   = (unsigned short*)(wsb + F_Y2T);
        unsigned short* p7h   = (unsigned short*)(wsb + F_P7H);
        float*          vec   = (float*)(wsb + F_VEC);

        // 1. prep: all converts + vec3 (wide stores + ILP-8 for adj)
        prep_kernel<<<2048 + 1280 + 160 + 512 + 1024 + 1536, 256, 0, stream>>>(
            adj, all_embeds, semantic_W, gc1_W, gc2_W,
            frames, scores, word_embed, visual_W, visual_b, semantic_b, score_W, score_b,
            adj_h, emb_h, emb_l, sw_h, sw_l, w1t_h, w2t_h, vec);
        // 2. vrow = s512 @ gc1_W[:512,:]
        vrow_kernel<<<8, 256, 0, stream>>>(gc1_W, vec);
        // 3. emT = relu(all_embeds @ semantic_W^T + b)^T  hi [512,4096], K=320, PROD=3
        mfma_g<64, 32, 3, 4, 1, 0><<<dim3(8, 64), 256, 0, stream>>>(
            emb_h, emb_l, sw_h, sw_l, 320, 320, 320,
            emT, nullptr, 4096, semantic_b, nullptr);
        // 4. p1p partials = adj @ em  bf16, square tiles BK=64, split-K x4  [4096,512]
        mfma_sq<3><<<dim3(4, 32, 4), 256, 0, stream>>>(
            adj_h, emT, 1024, 4096, 4096, p1p, nullptr, 512, 2097152);
        // 4b. combine 4 bf16 partials -> p1 hi
        combine_p1_kernel<<<2048, 256, 0, stream>>>(p1p, p1_h);
        // 5. h1 = relu(P1_hi @ W1'_hi + vrow + b1)  hi [4096,1024], K=512, PROD=1
        mfma_g<128, 64, 1, 3, 1, 0><<<dim3(16, 32), 256, 0, stream>>>(
            p1_h, nullptr, w1t_h, nullptr, 512, 512, 512,
            h1, nullptr, 1024, gc1_b, vec + OFF_VROW);
        // 6. y2t = (h1 @ gc2_W)^T  hi [1024,4096], K=1024
        mfma_g<128, 64, 1, 4, 0, 0><<<dim3(16, 32), 256, 0, stream>>>(
            h1, nullptr, w2t_h, nullptr, 1024, 1024, 1024,
            y2t, nullptr, 4096, nullptr, nullptr);
        // 7. p7h partials = adj @ Y2  bf16, square tiles BK=64, split-K x2  [4096,1024]
        mfma_sq<3><<<dim3(8, 32, 2), 256, 0, stream>>>(
            adj_h, y2t, 2048, 4096, 4096, p7h, nullptr, 1024, 4194304);
        // 7b. y3[i] = sum_j relu(p7h0+p7h1+b2)[i,j] * gc3_W[j]
        h2y3_kernel<<<4096, 256, 0, stream>>>(p7h, gc2_b, gc3_W, vec);
        // 8-11. tail
        h3b_kernel<<<4096, 256, 0, stream>>>(adj_h, gc3_b, vec);
        gcn_kernel<<<512, 256, 0, stream>>>(gcn512_W, gcn512_b, vec);
        x_kernel<<<512, 256, 0, stream>>>(hidden_W, hidden_b, vec);
        out_kernel<<<1, 512, 0, stream>>>(vec, critic_W, critic_b, actor_W, actor_b, out);
    } else {
        // fallback f32 path (round-1, proven within 50.4 MB)
        float* ws = (float*)d_ws;
        float* em = ws + OFF_BUF0;
        float* Y1 = ws + OFF_BUF1;
        float* H1 = ws + OFF_BUF2;
        float* Y2 = ws + OFF_BUF1;
        float* H2 = ws + OFF_BUF0;

        vec3_kernel<<<1536, 256, 0, stream>>>(frames, scores, word_embed,
                                              visual_W, visual_b, semantic_W, semantic_b,
                                              score_W, score_b, ws);
        vrow_kernel<<<8, 256, 0, stream>>>(gc1_W, ws);
        gemm_f32_128<1><<<dim3(512 / 128, 4096 / 128), 256, 0, stream>>>(
            all_embeds, semantic_W, em, 4096, 512, 300, 300, 300, semantic_b, nullptr, 1);
        gemm_f32_128<0><<<dim3(1024 / 128, 4096 / 128), 256, 0, stream>>>(
            em, gc1_W + (size_t)512 * 1024, Y1, 4096, 1024, 512, 512, 1024,
            nullptr, ws + OFF_VROW, 0);
        gemm_f32_128<0><<<dim3(1024 / 128, 4096 / 128), 256, 0, stream>>>(
            adj, Y1, H1, 4096, 1024, 4096, 4096, 1024, gc1_b, nullptr, 1);
        gemm_f32_128<0><<<dim3(1024 / 128, 4096 / 128), 256, 0, stream>>>(
            H1, gc2_W, Y2, 4096, 1024, 1024, 1024, 1024, nullptr, nullptr, 0);
        gemm_f32_128<0><<<dim3(1024 / 128, 4096 / 128), 256, 0, stream>>>(
            adj, Y2, H2, 4096, 1024, 4096, 4096, 1024, gc2_b, nullptr, 1);
        y3_kernel<<<4096, 256, 0, stream>>>(H2, gc3_W, ws);
        h3_kernel<<<4096, 256, 0, stream>>>(adj, gc3_b, ws);
        gcn_kernel<<<512, 256, 0, stream>>>(gcn512_W, gcn512_b, ws);
        x_kernel<<<512, 256, 0, stream>>>(hidden_W, hidden_b, ws);
        out_kernel<<<1, 512, 0, stream>>>(ws, critic_W, critic_b, actor_W, actor_b, out);
    }

    (void)in_sizes; (void)n_in; (void)out_size;
}

// Round 15
// 168.804 us; speedup vs baseline: 1.1336x; 1.0280x over previous
//
#include <hip/hip_runtime.h>
#include <cstddef>
#include <cstdint>

typedef short  s16x8 __attribute__((ext_vector_type(8)));
typedef float  f32x4 __attribute__((ext_vector_type(4)));
typedef unsigned short u16x4 __attribute__((ext_vector_type(4)));
typedef unsigned short u16x8 __attribute__((ext_vector_type(8)));

typedef __attribute__((address_space(1))) const void gas_void;
typedef __attribute__((address_space(3))) void las_void;

// ---------------- bf16 helpers ----------------
__device__ __forceinline__ unsigned short f2bh(float x) {
    union { float f; unsigned int u; } c; c.f = x;
    unsigned int r = c.u + 0x7fffu + ((c.u >> 16) & 1u);
    return (unsigned short)(r >> 16);
}
__device__ __forceinline__ float bh2f(unsigned short h) {
    union { unsigned int u; float f; } c; c.u = ((unsigned int)h) << 16;
    return c.f;
}
__device__ __forceinline__ f32x4 MF(s16x8 a, s16x8 b, f32x4 c) {
    return __builtin_amdgcn_mfma_f32_16x16x32_bf16(a, b, c, 0, 0, 0);
}
__device__ __forceinline__ void gload16(const unsigned short* g, unsigned short* l) {
    __builtin_amdgcn_global_load_lds((gas_void*)g, (las_void*)l, 16, 0, 0);
}

// ---------------- vec region offsets (floats) ----------------
static constexpr size_t OFF_VIS  = 0;
static constexpr size_t OFF_SEM  = 512;
static constexpr size_t OFF_GCN  = 1024;
static constexpr size_t OFF_S512 = 1536;
static constexpr size_t OFF_VROW = 2048;
static constexpr size_t OFF_X    = 3072;
static constexpr size_t OFF_Y3   = 4096;
static constexpr size_t OFF_H3   = 8192;
// fallback big buffers (floats, absolute in ws)
static constexpr size_t OFF_BUF0 = 16384;
static constexpr size_t OFF_BUF1 = OFF_BUF0 + 4194304;
static constexpr size_t OFF_BUF2 = OFF_BUF1 + 4194304;

// ---------------- fast-path ws layout (bytes) ----------------
static constexpr size_t F_ADJH  = 0;                          // 33,554,432
static constexpr size_t F_SCR   = 33554432;                   // 33,554,432 scratch
static constexpr size_t F_EMB_H = F_SCR;                      // 2,621,440
static constexpr size_t F_SW_H  = F_SCR + 2621440;            // 327,680
static constexpr size_t F_W1T_H = F_SCR + 2949120;            // 1,048,576
static constexpr size_t F_W2T_H = F_SCR + 3997696;            // 2,097,152
static constexpr size_t F_EMT   = F_SCR + 6094848;            // 4,194,304
static constexpr size_t F_P1P   = F_SCR + 16777216;           // 16,777,216 (#4 bf16 partials x4)
static constexpr size_t F_H1    = F_SCR + 16777216;           // 8,388,608 (after p1p dead)
static constexpr size_t F_P7H   = F_SCR;                      // 16,777,216 (#7 bf16 partials x2)
static constexpr size_t F_P1H   = 67108864;                   // 4,194,304
static constexpr size_t F_Y2T   = 71303168;                   // 8,388,608
static constexpr size_t F_VEC   = 79691776;                   // 49,152
static constexpr size_t FAST_WS = 79740928;                   // ~76.0 MB

// ---------------- block reduction ----------------
__device__ inline float blockReduceSum256(float v) {
    #pragma unroll
    for (int o = 32; o > 0; o >>= 1) v += __shfl_down(v, o, 64);
    __shared__ float red[4];
    int w = threadIdx.x >> 6;
    if ((threadIdx.x & 63) == 0) red[w] = v;
    __syncthreads();
    if (threadIdx.x == 0) v = red[0] + red[1] + red[2] + red[3];
    return v;
}

// ---------------- vec3 body (visual branch float4-vectorized) ----------------
__device__ __forceinline__ void vec3_body(int b,
                            const float* __restrict__ frames,
                            const float* __restrict__ scores,
                            const float* __restrict__ word_embed,
                            const float* __restrict__ visual_W, const float* __restrict__ visual_b,
                            const float* __restrict__ semantic_W, const float* __restrict__ semantic_b,
                            const float* __restrict__ score_W, const float* __restrict__ score_b,
                            float* __restrict__ vec) {
    if (b < 512) {
        int row = b;
        const float4* w4 = (const float4*)(visual_W + (size_t)row * 8192);
        const float4* x4 = (const float4*)frames;
        float s = 0.f;
        #pragma unroll
        for (int c0 = 0; c0 < 2048; c0 += 256) {
            int c = c0 + threadIdx.x;
            float4 wv = w4[c], xv = x4[c];
            s += wv.x * xv.x + wv.y * xv.y + wv.z * xv.z + wv.w * xv.w;
        }
        s = blockReduceSum256(s);
        if (threadIdx.x == 0) (vec + OFF_VIS)[row] = fmaxf(s + visual_b[row], 0.f);
        return;
    }
    const float* x; const float* W; const float* bias; float* out; int K; int row;
    if (b < 1024) { row = b - 512;  x = word_embed; W = semantic_W; bias = semantic_b; out = vec + OFF_SEM;  K = 300;  }
    else          { row = b - 1024; x = scores;     W = score_W;    bias = score_b;    out = vec + OFF_S512; K = 1000; }
    const float* wr = W + (size_t)row * K;
    float s = 0.f;
    for (int k = threadIdx.x; k < K; k += 256) s += wr[k] * x[k];
    s = blockReduceSum256(s);
    if (threadIdx.x == 0) out[row] = fmaxf(s + bias[row], 0.f);
}

// ---------------- small kernels ----------------
__global__ void vec3_kernel(const float* __restrict__ frames,
                            const float* __restrict__ scores,
                            const float* __restrict__ word_embed,
                            const float* __restrict__ visual_W, const float* __restrict__ visual_b,
                            const float* __restrict__ semantic_W, const float* __restrict__ semantic_b,
                            const float* __restrict__ score_W, const float* __restrict__ score_b,
                            float* __restrict__ vec) {
    vec3_body(blockIdx.x, frames, scores, word_embed, visual_W, visual_b,
              semantic_W, semantic_b, score_W, score_b, vec);
}

__global__ void vrow_kernel(const float* __restrict__ gc1_W, float* __restrict__ vec) {
    __shared__ float part[128];
    const float* s512 = vec + OFF_S512;
    int jl = threadIdx.x & 127;
    int j = blockIdx.x * 128 + jl;
    int kh = threadIdx.x >> 7;
    float s = 0.f;
    #pragma unroll 4
    for (int k = kh * 256; k < kh * 256 + 256; k++)
        s += s512[k] * gc1_W[(size_t)k * 1024 + j];
    if (kh) part[jl] = s;
    __syncthreads();
    if (!kh) vec[OFF_VROW + j] = s + part[jl];
}

__global__ void y3_kernel(const float* __restrict__ H2, const float* __restrict__ gc3_W,
                          float* __restrict__ vec) {
    int i = blockIdx.x;
    const float* r = H2 + (size_t)i * 1024;
    float s = 0.f;
    for (int k = threadIdx.x; k < 1024; k += 256) s += r[k] * gc3_W[k];
    s = blockReduceSum256(s);
    if (threadIdx.x == 0) vec[OFF_Y3 + i] = s;
}

// fused: y3[i] = sum_j relu(sum_z p7h[z][i,j] + gc2_b[j]) * gc3_W[j]   (2 bf16 partials)
__global__ void h2y3_kernel(const unsigned short* __restrict__ p7h, const float* __restrict__ gc2_b,
                            const float* __restrict__ gc3_W, float* __restrict__ vec) {
    int i = blockIdx.x;
    int c = threadIdx.x;   // 256 threads x 4 cols = 1024
    float a0 = 0.f, a1 = 0.f, a2 = 0.f, a3 = 0.f;
    #pragma unroll
    for (int z = 0; z < 2; z++) {
        u16x4 v = *(const u16x4*)(p7h + (size_t)z * 4194304 + (size_t)i * 1024 + c * 4);
        a0 += bh2f(v[0]); a1 += bh2f(v[1]); a2 += bh2f(v[2]); a3 += bh2f(v[3]);
    }
    float4 bb = ((const float4*)gc2_b)[c];
    float4 ww = ((const float4*)gc3_W)[c];
    float s = fmaxf(a0 + bb.x, 0.f) * ww.x
            + fmaxf(a1 + bb.y, 0.f) * ww.y
            + fmaxf(a2 + bb.z, 0.f) * ww.z
            + fmaxf(a3 + bb.w, 0.f) * ww.w;
    s = blockReduceSum256(s);
    if (threadIdx.x == 0) vec[OFF_Y3 + i] = s;
}

// h3 from bf16 adj
__global__ void h3b_kernel(const unsigned short* __restrict__ adj_h,
                           const float* __restrict__ gc3_b, float* __restrict__ vec) {
    int i = blockIdx.x;
    const u16x4* rp = (const u16x4*)(adj_h + (size_t)i * 4096);
    const float* y3 = vec + OFF_Y3;
    float s = 0.f;
    for (int c = threadIdx.x; c < 1024; c += 256) {
        u16x4 v = rp[c];
        int k0 = c * 4;
        s += bh2f(v[0]) * y3[k0] + bh2f(v[1]) * y3[k0 + 1]
           + bh2f(v[2]) * y3[k0 + 2] + bh2f(v[3]) * y3[k0 + 3];
    }
    s = blockReduceSum256(s);
    if (threadIdx.x == 0) vec[OFF_H3 + i] = fmaxf(s + gc3_b[0], 0.f);
}

__global__ void h3_kernel(const float* __restrict__ adj, const float* __restrict__ gc3_b,
                          float* __restrict__ vec) {
    int i = blockIdx.x;
    const float* r = adj + (size_t)i * 4096;
    const float* y3 = vec + OFF_Y3;
    float s = 0.f;
    for (int k = threadIdx.x; k < 4096; k += 256) s += r[k] * y3[k];
    s = blockReduceSum256(s);
    if (threadIdx.x == 0) vec[OFF_H3 + i] = fmaxf(s + gc3_b[0], 0.f);
}

__global__ void gcn_kernel(const float* __restrict__ gcn512_W, const float* __restrict__ gcn512_b,
                           float* __restrict__ vec) {
    int j = blockIdx.x;
    const float* r = gcn512_W + (size_t)j * 4096;
    const float* h3 = vec + OFF_H3;
    float s = 0.f;
    for (int k = threadIdx.x; k < 4096; k += 256) s += r[k] * h3[k];
    s = blockReduceSum256(s);
    if (threadIdx.x == 0) vec[OFF_GCN + j] = fmaxf(s + gcn512_b[j], 0.f);
}

__global__ void x_kernel(const float* __restrict__ hidden_W, const float* __restrict__ hidden_b,
                         float* __restrict__ vec) {
    int j = blockIdx.x;
    const float* r = hidden_W + (size_t)j * 1536;
    const float* joint = vec;
    float s = 0.f;
    for (int k = threadIdx.x; k < 1536; k += 256) s += r[k] * joint[k];
    s = blockReduceSum256(s);
    if (threadIdx.x == 0) vec[OFF_X + j] = fmaxf(s + hidden_b[j], 0.f);
}

__global__ void out_kernel(const float* __restrict__ vec,
                           const float* __restrict__ critic_W, const float* __restrict__ critic_b,
                           const float* __restrict__ actor_W, const float* __restrict__ actor_b,
                           float* __restrict__ out) {
    const float* xv = vec + OFF_X;
    int w = threadIdx.x >> 6, l = threadIdx.x & 63;
    if (w >= 7) return;
    const float* row = (w == 0) ? critic_W : actor_W + (size_t)(w - 1) * 512;
    float s = 0.f;
    for (int q = l; q < 512; q += 64) s += xv[q] * row[q];
    #pragma unroll
    for (int o = 32; o > 0; o >>= 1) s += __shfl_down(s, o, 64);
    if (l == 0) out[w] = s + ((w == 0) ? critic_b[0] : actor_b[w - 1]);
}

// combine P1 split-K bf16 partials (x4) -> hi bf16
__global__ void combine_p1_kernel(const unsigned short* __restrict__ p1p,
                                  unsigned short* __restrict__ hi) {
    size_t i = (size_t)blockIdx.x * 256 + threadIdx.x;    // u16x4 index over 524288
    float s0 = 0.f, s1 = 0.f, s2 = 0.f, s3 = 0.f;
    #pragma unroll
    for (int z = 0; z < 4; z++) {
        u16x4 v = *(const u16x4*)(p1p + (size_t)z * 2097152 + i * 4);
        s0 += bh2f(v[0]); s1 += bh2f(v[1]); s2 += bh2f(v[2]); s3 += bh2f(v[3]);
    }
    u16x4 hv;
    hv[0] = f2bh(s0); hv[1] = f2bh(s1); hv[2] = f2bh(s2); hv[3] = f2bh(s3);
    *(u16x4*)(hi + i * 4) = hv;
}

// ---------------- prep kernel: ONLY emb_h + sw_h (hi, PROD=1 consumers) ----------------
// grid: [0,1280) emb | [1280,1440) sw
__global__ void prep_kernel(const float* __restrict__ all_embeds,
                            const float* __restrict__ semantic_W,
                            unsigned short* __restrict__ emb_h,
                            unsigned short* __restrict__ sw_h) {
    const int b = blockIdx.x, t = threadIdx.x;
    if (b < 1280) {
        size_t base = (size_t)b * 256 + t;
        float v[4];
        #pragma unroll
        for (int j = 0; j < 4; j++) {
            size_t i = base + (size_t)j * 327680;
            int r = (int)(i / 320), c = (int)(i % 320);
            v[j] = (c < 300) ? all_embeds[(size_t)r * 300 + c] : 0.f;
        }
        #pragma unroll
        for (int j = 0; j < 4; j++) emb_h[base + (size_t)j * 327680] = f2bh(v[j]);
    } else {
        size_t base = (size_t)(b - 1280) * 256 + t;
        float v[4];
        #pragma unroll
        for (int j = 0; j < 4; j++) {
            size_t i = base + (size_t)j * 40960;
            int r = (int)(i / 320), c = (int)(i % 320);
            v[j] = (c < 300) ? semantic_W[(size_t)r * 300 + c] : 0.f;
        }
        #pragma unroll
        for (int j = 0; j < 4; j++) sw_h[base + (size_t)j * 40960] = f2bh(v[j]);
    }
}

// ---------------- staging helpers ----------------
template<int NCHP, int NJ>
__device__ __forceinline__ void stg_mat(const unsigned short* __restrict__ src, int ld, int r0,
                                        int k0, unsigned short* dst, int t) {
    #pragma unroll
    for (int j = 0; j < NJ; j++) {
        int c = j * 256 + t;
        int p = c / NCHP;
        int idx = c % NCHP;
        int row = idx >> 2;
        int gg = (idx & 3) ^ ((row >> 1) & 3);
        gload16(src + (size_t)(r0 + row) * ld + (k0 + p * 32 + gg * 8),
                dst + (size_t)(j * 256 + (t & ~63)) * 8);
    }
}

template<int ROWS>
__device__ __forceinline__ s16x8 rfrag(const unsigned short* rb, int row, int p, int g4) {
    int byte = (p * ROWS + row) * 64 + ((g4 ^ ((row >> 1) & 3)) << 4);
    return *(const s16x8*)((const char*)rb + byte);
}

// ---------------- fused3: emT GEMM (PROD=1) + adj cvt + w1T + w2T + vec3 ----------------
// grid 1D: [0,512) emT GEMM | [512,2560) adj cvt | [2560,3072) w1T | [3072,4096) w2T |
// [4096,5632) vec3.  emb_h/sw_h are produced by the PREVIOUS prep launch.
__global__ __launch_bounds__(256) void fused3_kernel(
    const unsigned short* __restrict__ emb_h, const unsigned short* __restrict__ sw_h,
    unsigned short* __restrict__ emT, const float* __restrict__ semantic_b,
    const float* __restrict__ adj, unsigned short* __restrict__ adj_h,
    const float* __restrict__ gc1_W, const float* __restrict__ gc2_W,
    unsigned short* __restrict__ w1t_h, unsigned short* __restrict__ w2t_h,
    const float* __restrict__ frames, const float* __restrict__ scores,
    const float* __restrict__ word_embed,
    const float* __restrict__ visual_W, const float* __restrict__ visual_b,
    const float* __restrict__ semantic_W,
    const float* __restrict__ score_W, const float* __restrict__ score_b,
    float* __restrict__ vec)
{
    __shared__ unsigned short lds[3 * 4096];   // 24 KB (GEMM ring-3); aliased by transposes
    const int b = blockIdx.x, t = threadIdx.x;

    if (b < 512) {
        // ---- emT = relu(emb @ sw^T + b)^T  hi [512,4096], K=320, BM=64, BK=32, PROD=1
        const int w = t >> 6, l = t & 63;
        const int r = l & 15, g4 = l >> 4;
        const int wr = (w >> 1) * 32;
        const int wc = (w & 1) * 32;
        int swz = (b & 7) * 64 + (b >> 3);     // XCD swizzle, gx=8, nwg=512
        const int col0 = (swz % 8) * 64;
        const int row0 = (swz / 8) * 64;

        f32x4 acc[2][2];
        #pragma unroll
        for (int a = 0; a < 2; a++)
            #pragma unroll
            for (int bb2 = 0; bb2 < 2; bb2++) acc[a][bb2] = (f32x4){0.f, 0.f, 0.f, 0.f};

        auto stage = [&](int slot, int k0) {
            unsigned short* base = lds + slot * 4096;
            stg_mat<256, 1>(emb_h, 320, row0, k0, base, t);
            stg_mat<256, 1>(sw_h, 320, col0, k0, base + 2048, t);
        };

        const int T = 10;   // 320/32
        stage(0, 0);
        stage(1, 32);
        for (int tt = 0; tt < T; ++tt) {
            __builtin_amdgcn_s_barrier();
            if (tt + 2 < T) {
                stage((tt + 2) % 3, (tt + 2) * 32);
                asm volatile("s_waitcnt vmcnt(4)" ::: "memory");
            } else if (tt + 1 < T) {
                asm volatile("s_waitcnt vmcnt(2)" ::: "memory");
            } else {
                asm volatile("s_waitcnt vmcnt(0)" ::: "memory");
            }
            __builtin_amdgcn_s_barrier();

            const unsigned short* base = lds + (tt % 3) * 4096;
            s16x8 a[2], bb[2];
            #pragma unroll
            for (int f = 0; f < 2; f++) a[f] = rfrag<64>(base, wr + f * 16 + r, 0, g4);
            #pragma unroll
            for (int f = 0; f < 2; f++) bb[f] = rfrag<64>(base + 2048, wc + f * 16 + r, 0, g4);
            __builtin_amdgcn_s_setprio(1);
            #pragma unroll
            for (int fm = 0; fm < 2; fm++)
                #pragma unroll
                for (int fn = 0; fn < 2; fn++)
                    acc[fm][fn] = MF(a[fm], bb[fn], acc[fm][fn]);
            __builtin_amdgcn_s_setprio(0);
        }

        // epilogue: hi C^T [n][m], ldc = 4096
        #pragma unroll
        for (int fn = 0; fn < 2; fn++) {
            int n = col0 + wc + fn * 16 + r;
            float bn = semantic_b[n];
            #pragma unroll
            for (int fm = 0; fm < 2; fm++) {
                int m0 = row0 + wr + fm * 16 + g4 * 4;
                u16x4 hv;
                #pragma unroll
                for (int i = 0; i < 4; i++)
                    hv[i] = f2bh(fmaxf(acc[fm][fn][i] + bn, 0.f));
                *(u16x4*)(emT + (size_t)n * 4096 + m0) = hv;
            }
        }
        return;
    }

    if (b < 2560) {
        // ---- adj f32 -> bf16 (round-14 proven): 8 float4 loads, 4 x 16B stores
        size_t base = (size_t)(b - 512) * 2048 + t * 2;
        float4 v[8];
        #pragma unroll
        for (int j = 0; j < 4; j++) {
            v[2 * j]     = ((const float4*)adj)[base + j * 512];
            v[2 * j + 1] = ((const float4*)adj)[base + j * 512 + 1];
        }
        #pragma unroll
        for (int j = 0; j < 4; j++) {
            u16x8 h;
            h[0] = f2bh(v[2 * j].x);     h[1] = f2bh(v[2 * j].y);
            h[2] = f2bh(v[2 * j].z);     h[3] = f2bh(v[2 * j].w);
            h[4] = f2bh(v[2 * j + 1].x); h[5] = f2bh(v[2 * j + 1].y);
            h[6] = f2bh(v[2 * j + 1].z); h[7] = f2bh(v[2 * j + 1].w);
            *(u16x8*)(adj_h + (base + j * 512) * 4) = h;
        }
        return;
    }

    float* tile = (float*)lds;   // [32][33] = 4224 B, fits in the 24 KB buffer
    if (b < 3072) {
        // ---- w1T: gc1_W[512:,:] f32 [512,1024] -> [N,K] hi
        int l2 = b - 2560;
        const float* src = gc1_W + (size_t)512 * 1024;
        int kb = (l2 & 15) * 32, nb = (l2 >> 4) * 32;
        int tx = t & 31, ty = t >> 5;
        #pragma unroll
        for (int i = 0; i < 32; i += 8)
            tile[(ty + i) * 33 + tx] = src[(size_t)(kb + ty + i) * 1024 + nb + tx];
        __syncthreads();
        #pragma unroll
        for (int i = 0; i < 32; i += 8) {
            int n = nb + ty + i, k = kb + tx;
            w1t_h[(size_t)n * 512 + k] = f2bh(tile[tx * 33 + ty + i]);
        }
        return;
    }
    if (b < 4096) {
        // ---- w2T: gc2_W f32 [1024,1024] -> [N,K] hi
        int l2 = b - 3072;
        int kb = (l2 & 31) * 32, nb = (l2 >> 5) * 32;
        int tx = t & 31, ty = t >> 5;
        #pragma unroll
        for (int i = 0; i < 32; i += 8)
            tile[(ty + i) * 33 + tx] = gc2_W[(size_t)(kb + ty + i) * 1024 + nb + tx];
        __syncthreads();
        #pragma unroll
        for (int i = 0; i < 32; i += 8) {
            int n = nb + ty + i, k = kb + tx;
            w2t_h[(size_t)n * 1024 + k] = f2bh(tile[tx * 33 + ty + i]);
        }
        return;
    }
    // ---- vec3
    vec3_body(b - 4096, frames, scores, word_embed, visual_W, visual_b,
              semantic_W, semantic_b, score_W, score_b, vec);
}

// ---------------- 4-wave MFMA GEMM (proven ring-3 counted structure) ----------------
template<int BM, int BK, int PROD, int WMODE, int RELU, int SPLITK>
__global__ __launch_bounds__(256) void mfma_g(
    const unsigned short* __restrict__ Ah, const unsigned short* __restrict__ Al,
    const unsigned short* __restrict__ Bh, const unsigned short* __restrict__ Bl,
    int K, int lda, int ldb,
    unsigned short* __restrict__ Ch, float* __restrict__ Cf, int ldc,
    const float* __restrict__ bias, const float* __restrict__ bias2)
{
    constexpr int A_USH = BM * BK;
    constexpr int B_USH = 64 * BK;
    constexpr int A_CH  = A_USH / 8;
    constexpr int B_CH  = B_USH / 8;
    constexpr int SLOT  = (PROD == 3) ? 2 * (A_USH + B_USH) : (A_USH + B_USH);
    constexpr int L     = ((A_CH + B_CH) / 256) * ((PROD == 3) ? 2 : 1);
    constexpr int FM    = BM / 32;
    __shared__ unsigned short lds[3 * SLOT];

    const int t = threadIdx.x;
    const int w = t >> 6, l = t & 63;
    const int r = l & 15, g4 = l >> 4;
    const int wr = (w >> 1) * (BM / 2);
    const int wc = (w & 1) * 32;

    const int gx = gridDim.x;
    const int nwg = gx * gridDim.y;
    int flat = blockIdx.y * gx + blockIdx.x;
    int swz = (flat & 7) * (nwg >> 3) + (flat >> 3);
    const int col0 = (swz % gx) * 64;
    const int row0 = (swz / gx) * BM;

    if constexpr (SPLITK) {
        int z = blockIdx.z;
        Ah += (size_t)z * K;
        Bh += (size_t)z * K;
        if (Cf) Cf += (size_t)z * (size_t)nwg * (BM * 64);
        if (Ch) Ch += (size_t)z * (size_t)nwg * (BM * 64);
    }

    f32x4 acc[FM][2];
    #pragma unroll
    for (int a = 0; a < FM; a++)
        #pragma unroll
        for (int b = 0; b < 2; b++) acc[a][b] = (f32x4){0.f, 0.f, 0.f, 0.f};

    auto stage = [&](int slot, int k0) {
        unsigned short* base = lds + slot * SLOT;
        stg_mat<BM * 4, A_CH / 256>(Ah, lda, row0, k0, base, t);
        stg_mat<256,    B_CH / 256>(Bh, ldb, col0, k0, base + A_USH, t);
        if constexpr (PROD == 3) {
            stg_mat<256,    B_CH / 256>(Bl, ldb, col0, k0, base + A_USH + B_USH, t);
            stg_mat<BM * 4, A_CH / 256>(Al, lda, row0, k0, base + A_USH + 2 * B_USH, t);
        }
    };

    const int T = K / BK;
    stage(0, 0);
    stage(1, BK);

    for (int tt = 0; tt < T; ++tt) {
        __builtin_amdgcn_s_barrier();
        if (tt + 2 < T) {
            stage((tt + 2) % 3, (tt + 2) * BK);
            if constexpr (L == 2)      asm volatile("s_waitcnt vmcnt(4)" ::: "memory");
            else if constexpr (L == 4) asm volatile("s_waitcnt vmcnt(8)" ::: "memory");
            else if constexpr (L == 6) asm volatile("s_waitcnt vmcnt(12)" ::: "memory");
            else                       asm volatile("s_waitcnt vmcnt(16)" ::: "memory");
        } else if (tt + 1 < T) {
            if constexpr (L == 2)      asm volatile("s_waitcnt vmcnt(2)" ::: "memory");
            else if constexpr (L == 4) asm volatile("s_waitcnt vmcnt(4)" ::: "memory");
            else if constexpr (L == 6) asm volatile("s_waitcnt vmcnt(6)" ::: "memory");
            else                       asm volatile("s_waitcnt vmcnt(8)" ::: "memory");
        } else {
            asm volatile("s_waitcnt vmcnt(0)" ::: "memory");
        }
        __builtin_amdgcn_s_barrier();

        const unsigned short* base = lds + (tt % 3) * SLOT;
        #pragma unroll
        for (int kk = 0; kk < BK / 32; kk++) {
            s16x8 a[FM], bb[2], alr[FM], blr[2];
            #pragma unroll
            for (int f = 0; f < FM; f++) a[f] = rfrag<BM>(base, wr + f * 16 + r, kk, g4);
            #pragma unroll
            for (int f = 0; f < 2; f++) bb[f] = rfrag<64>(base + A_USH, wc + f * 16 + r, kk, g4);
            if constexpr (PROD == 3) {
                #pragma unroll
                for (int f = 0; f < 2; f++) blr[f] = rfrag<64>(base + A_USH + B_USH, wc + f * 16 + r, kk, g4);
                #pragma unroll
                for (int f = 0; f < FM; f++) alr[f] = rfrag<BM>(base + A_USH + 2 * B_USH, wr + f * 16 + r, kk, g4);
            }
            __builtin_amdgcn_s_setprio(1);
            #pragma unroll
            for (int fm = 0; fm < FM; fm++)
                #pragma unroll
                for (int fn = 0; fn < 2; fn++) {
                    acc[fm][fn] = MF(a[fm], bb[fn], acc[fm][fn]);
                    if constexpr (PROD == 3) {
                        acc[fm][fn] = MF(a[fm], blr[fn], acc[fm][fn]);
                        acc[fm][fn] = MF(alr[fm], bb[fn], acc[fm][fn]);
                    }
                }
            __builtin_amdgcn_s_setprio(0);
        }
    }

    // epilogue (C/D: col = lane&15, row = 4*(lane>>4)+i — m89-verified)
    #pragma unroll
    for (int fn = 0; fn < 2; fn++) {
        int n = col0 + wc + fn * 16 + r;
        float bn = bias ? bias[n] : 0.f;
        if (bias2) bn += bias2[n];
        #pragma unroll
        for (int fm = 0; fm < FM; fm++) {
            int m0 = row0 + wr + fm * 16 + g4 * 4;
            f32x4 v = acc[fm][fn];
            if constexpr (WMODE == 4) {
                u16x4 hv;
                #pragma unroll
                for (int i = 0; i < 4; i++) {
                    float x = v[i] + bn;
                    if (RELU) x = fmaxf(x, 0.f);
                    hv[i] = f2bh(x);
                }
                *(u16x4*)(Ch + (size_t)n * ldc + m0) = hv;
            } else if constexpr (WMODE == 6) {
                #pragma unroll
                for (int i = 0; i < 4; i++) {
                    float x = v[i] + bn;
                    if (RELU) x = fmaxf(x, 0.f);
                    Cf[(size_t)(m0 + i) * ldc + n] = x;
                }
            } else {  // WMODE 3: hi bf16 C[m][n]
                #pragma unroll
                for (int i = 0; i < 4; i++) {
                    float x = v[i] + bn;
                    if (RELU) x = fmaxf(x, 0.f);
                    Ch[(size_t)(m0 + i) * ldc + n] = f2bh(x);
                }
            }
        }
    }
}

// ---------------- SQUARE-tile GEMM 128x128, wave 64x64, BK=64, ring-2 counted, split-K ----
// WM=6: f32 partials Cf; WM=3: bf16 partials Ch. zstride = elements per split slice.
template<int WM>
__global__ __launch_bounds__(256) void mfma_sq(
    const unsigned short* __restrict__ Ah,
    const unsigned short* __restrict__ Bh,
    int Kc, int lda, int ldb,
    unsigned short* __restrict__ Ch, float* __restrict__ Cf, int ldc, size_t zstride)
{
    constexpr int A_USH = 128 * 64;           // 8192 ush (2 K-panels x 128 rows)
    constexpr int SLOT  = 2 * A_USH;          // 16384 ush = 32 KB
    __shared__ unsigned short lds[2 * SLOT];  // 64 KB ring-2

    const int t = threadIdx.x;
    const int w = t >> 6, l = t & 63;
    const int r = l & 15, g4 = l >> 4;
    const int wr = (w >> 1) * 64, wc = (w & 1) * 64;

    const int gx = gridDim.x;
    const int nwg = gx * gridDim.y;
    int flat = blockIdx.y * gx + blockIdx.x;
    int swz = (flat & 7) * (nwg >> 3) + (flat >> 3);
    const int col0 = (swz % gx) * 128;
    const int row0 = (swz / gx) * 128;

    const int z = blockIdx.z;
    Ah += (size_t)z * Kc;
    Bh += (size_t)z * Kc;
    if constexpr (WM == 6) Cf += (size_t)z * zstride;
    else                   Ch += (size_t)z * zstride;

    f32x4 acc[4][4];
    #pragma unroll
    for (int a = 0; a < 4; a++)
        #pragma unroll
        for (int b = 0; b < 4; b++) acc[a][b] = (f32x4){0.f, 0.f, 0.f, 0.f};

    auto stage = [&](int slot, int k0) {      // 8 loads/thread
        unsigned short* base = lds + slot * SLOT;
        stg_mat<512, 4>(Ah, lda, row0, k0, base, t);
        stg_mat<512, 4>(Bh, ldb, col0, k0, base + A_USH, t);
    };

    const int T = Kc >> 6;
    stage(0, 0);

    for (int tt = 0; tt < T; ++tt) {
        __builtin_amdgcn_s_barrier();
        if (tt + 1 < T) {
            stage((tt + 1) & 1, (tt + 1) * 64);
            asm volatile("s_waitcnt vmcnt(8)" ::: "memory");   // oldest 8 (tile tt) landed
        } else {
            asm volatile("s_waitcnt vmcnt(0)" ::: "memory");
        }
        __builtin_amdgcn_s_barrier();

        const unsigned short* base = lds + (tt & 1) * SLOT;
        #pragma unroll
        for (int kk = 0; kk < 2; kk++) {
            s16x8 a[4], bb[4];
            #pragma unroll
            for (int f = 0; f < 4; f++) a[f] = rfrag<128>(base, wr + f * 16 + r, kk, g4);
            #pragma unroll
            for (int f = 0; f < 4; f++) bb[f] = rfrag<128>(base + A_USH, wc + f * 16 + r, kk, g4);
            __builtin_amdgcn_s_setprio(1);
            #pragma unroll
            for (int fm = 0; fm < 4; fm++)
                #pragma unroll
                for (int fn = 0; fn < 4; fn++)
                    acc[fm][fn] = MF(a[fm], bb[fn], acc[fm][fn]);
            __builtin_amdgcn_s_setprio(0);
        }
    }

    // epilogue (C/D: col = lane&15, row = 4*(lane>>4)+i)
    #pragma unroll
    for (int fn = 0; fn < 4; fn++) {
        int n = col0 + wc + fn * 16 + r;
        #pragma unroll
        for (int fm = 0; fm < 4; fm++) {
            int m0 = row0 + wr + fm * 16 + g4 * 4;
            f32x4 v = acc[fm][fn];
            #pragma unroll
            for (int i = 0; i < 4; i++) {
                if constexpr (WM == 6) Cf[(size_t)(m0 + i) * ldc + n] = v[i];
                else                   Ch[(size_t)(m0 + i) * ldc + n] = f2bh(v[i]);
            }
        }
    }
}

// ---------------- fallback f32 tiled GEMM (round-1, proven) ----------------
template<int TRANSB>
__global__ __launch_bounds__(256) void gemm_f32_128(
    const float* __restrict__ A, const float* __restrict__ B, float* __restrict__ C,
    int M, int N, int K, int lda, int ldb,
    const float* __restrict__ bias, const float* __restrict__ vrow, int do_relu)
{
    constexpr int BM = 128, BN = 128, BK = 16;
    __shared__ float As[BK][BM + 4];
    __shared__ float Bs[BK][BN + 4];
    const int t = threadIdx.x;
    const int w = t >> 6, l = t & 63;
    const int cx = (w & 1) * 8 + (l & 7);
    const int cy = (w >> 1) * 8 + (l >> 3);
    const int row0 = blockIdx.y * BM;
    const int col0 = blockIdx.x * BN;

    float acc[8][8];
    #pragma unroll
    for (int i = 0; i < 8; i++)
        #pragma unroll
        for (int j = 0; j < 8; j++) acc[i][j] = 0.f;

    const int ka = t & 15;
    const int ma = t >> 4;

    for (int k0 = 0; k0 < K; k0 += BK) {
        #pragma unroll
        for (int i = 0; i < 8; i++) {
            int m = ma + i * 16;
            int gk = k0 + ka;
            float v = 0.f;
            if (gk < K) v = A[(size_t)(row0 + m) * lda + gk];
            As[ka][m] = v;
        }
        if (TRANSB) {
            #pragma unroll
            for (int i = 0; i < 8; i++) {
                int n = ma + i * 16;
                int gk = k0 + ka;
                float v = 0.f;
                if (gk < K) v = B[(size_t)(col0 + n) * ldb + gk];
                Bs[ka][n] = v;
            }
        } else {
            const int nb = t & 127;
            const int kb = t >> 7;
            #pragma unroll
            for (int i = 0; i < 8; i++) {
                int kk = kb + i * 2;
                int gk = k0 + kk;
                float v = 0.f;
                if (gk < K) v = B[(size_t)gk * ldb + col0 + nb];
                Bs[kk][nb] = v;
            }
        }
        __syncthreads();
        #pragma unroll
        for (int kk = 0; kk < BK; kk++) {
            float a[8], bb[8];
            *(float4*)&a[0]  = *(const float4*)&As[kk][cy * 8];
            *(float4*)&a[4]  = *(const float4*)&As[kk][cy * 8 + 4];
            *(float4*)&bb[0] = *(const float4*)&Bs[kk][cx * 8];
            *(float4*)&bb[4] = *(const float4*)&Bs[kk][cx * 8 + 4];
            #pragma unroll
            for (int i = 0; i < 8; i++)
                #pragma unroll
                for (int j = 0; j < 8; j++)
                    acc[i][j] = fmaf(a[i], bb[j], acc[i][j]);
        }
        __syncthreads();
    }

    #pragma unroll
    for (int i = 0; i < 8; i++) {
        int rr = row0 + cy * 8 + i;
        float vv[8];
        #pragma unroll
        for (int j = 0; j < 8; j++) {
            int c = col0 + cx * 8 + j;
            float v = acc[i][j];
            if (vrow) v += vrow[c];
            if (bias) v += bias[c];
            if (do_relu) v = fmaxf(v, 0.f);
            vv[j] = v;
        }
        float* cp = C + (size_t)rr * N + col0 + cx * 8;
        *(float4*)cp       = *(float4*)&vv[0];
        *(float4*)(cp + 4) = *(float4*)&vv[4];
    }
}

// ---------------- host launcher ----------------
extern "C" void kernel_launch(void* const* d_in, const int* in_sizes, int n_in,
                              void* d_out, int out_size, void* d_ws, size_t ws_size,
                              hipStream_t stream) {
    const float* frames     = (const float*)d_in[0];
    const float* scores     = (const float*)d_in[1];
    const float* word_embed = (const float*)d_in[2];
    const float* all_embeds = (const float*)d_in[3];
    const float* adj        = (const float*)d_in[4];
    const float* visual_W   = (const float*)d_in[5];
    const float* visual_b   = (const float*)d_in[6];
    const float* semantic_W = (const float*)d_in[7];
    const float* semantic_b = (const float*)d_in[8];
    const float* score_W    = (const float*)d_in[9];
    const float* score_b    = (const float*)d_in[10];
    const float* gc1_W      = (const float*)d_in[11];
    const float* gc1_b      = (const float*)d_in[12];
    const float* gc2_W      = (const float*)d_in[13];
    const float* gc2_b      = (const float*)d_in[14];
    const float* gc3_W      = (const float*)d_in[15];
    const float* gc3_b      = (const float*)d_in[16];
    const float* gcn512_W   = (const float*)d_in[17];
    const float* gcn512_b   = (const float*)d_in[18];
    const float* hidden_W   = (const float*)d_in[19];
    const float* hidden_b   = (const float*)d_in[20];
    const float* critic_W   = (const float*)d_in[21];
    const float* critic_b   = (const float*)d_in[22];
    const float* actor_W    = (const float*)d_in[23];
    const float* actor_b    = (const float*)d_in[24];

    float* out = (float*)d_out;

    if (ws_size >= FAST_WS) {
        char* wsb = (char*)d_ws;
        unsigned short* adj_h = (unsigned short*)(wsb + F_ADJH);
        unsigned short* emb_h = (unsigned short*)(wsb + F_EMB_H);
        unsigned short* sw_h  = (unsigned short*)(wsb + F_SW_H);
        unsigned short* w1t_h = (unsigned short*)(wsb + F_W1T_H);
        unsigned short* w2t_h = (unsigned short*)(wsb + F_W2T_H);
        unsigned short* emT   = (unsigned short*)(wsb + F_EMT);
        unsigned short* p1p   = (unsigned short*)(wsb + F_P1P);
        unsigned short* p1_h  = (unsigned short*)(wsb + F_P1H);
        unsigned short* h1    = (unsigned short*)(wsb + F_H1);
        unsigned short* y2t   = (unsigned short*)(wsb + F_Y2T);
        unsigned short* p7h   = (unsigned short*)(wsb + F_P7H);
        float*          vec   = (float*)(wsb + F_VEC);

        // 1. prep: emb_h + sw_h only (needed by fused3's GEMM blocks)
        prep_kernel<<<1440, 256, 0, stream>>>(all_embeds, semantic_W, emb_h, sw_h);
        // 2. fused3: emT GEMM (PROD=1) ∥ adj convert ∥ w1T ∥ w2T ∥ vec3
        fused3_kernel<<<5632, 256, 0, stream>>>(
            emb_h, sw_h, emT, semantic_b,
            adj, adj_h, gc1_W, gc2_W, w1t_h, w2t_h,
            frames, scores, word_embed, visual_W, visual_b, semantic_W,
            score_W, score_b, vec);
        // 3. vrow = s512 @ gc1_W[:512,:]
        vrow_kernel<<<8, 256, 0, stream>>>(gc1_W, vec);
        // 4. p1p partials = adj @ em  bf16, square tiles BK=64, split-K x4  [4096,512]
        mfma_sq<3><<<dim3(4, 32, 4), 256, 0, stream>>>(
            adj_h, emT, 1024, 4096, 4096, p1p, nullptr, 512, 2097152);
        // 4b. combine 4 bf16 partials -> p1 hi
        combine_p1_kernel<<<2048, 256, 0, stream>>>(p1p, p1_h);
        // 5. h1 = relu(P1_hi @ W1'_hi + vrow + b1)  hi [4096,1024], K=512, PROD=1
        mfma_g<128, 64, 1, 3, 1, 0><<<dim3(16, 32), 256, 0, stream>>>(
            p1_h, nullptr, w1t_h, nullptr, 512, 512, 512,
            h1, nullptr, 1024, gc1_b, vec + OFF_VROW);
        // 6. y2t = (h1 @ gc2_W)^T  hi [1024,4096], K=1024
        mfma_g<128, 64, 1, 4, 0, 0><<<dim3(16, 32), 256, 0, stream>>>(
            h1, nullptr, w2t_h, nullptr, 1024, 1024, 1024,
            y2t, nullptr, 4096, nullptr, nullptr);
        // 7. p7h partials = adj @ Y2  bf16, square tiles BK=64, split-K x2  [4096,1024]
        mfma_sq<3><<<dim3(8, 32, 2), 256, 0, stream>>>(
            adj_h, y2t, 2048, 4096, 4096, p7h, nullptr, 1024, 4194304);
        // 7b. y3[i] = sum_j relu(p7h0+p7h1+b2)[i,j] * gc3_W[j]
        h2y3_kernel<<<4096, 256, 0, stream>>>(p7h, gc2_b, gc3_W, vec);
        // 8-11. tail
        h3b_kernel<<<4096, 256, 0, stream>>>(adj_h, gc3_b, vec);
        gcn_kernel<<<512, 256, 0, stream>>>(gcn512_W, gcn512_b, vec);
        x_kernel<<<512, 256, 0, stream>>>(hidden_W, hidden_b, vec);
        out_kernel<<<1, 512, 0, stream>>>(vec, critic_W, critic_b, actor_W, actor_b, out);
    } else {
        // fallback f32 path (round-1, proven within 50.4 MB)
        float* ws = (float*)d_ws;
        float* em = ws + OFF_BUF0;
        float* Y1 = ws + OFF_BUF1;
        float* H1 = ws + OFF_BUF2;
        float* Y2 = ws + OFF_BUF1;
        float* H2 = ws + OFF_BUF0;

        vec3_kernel<<<1536, 256, 0, stream>>>(frames, scores, word_embed,
                                              visual_W, visual_b, semantic_W, semantic_b,
                                              score_W, score_b, ws);
        vrow_kernel<<<8, 256, 0, stream>>>(gc1_W, ws);
        gemm_f32_128<1><<<dim3(512 / 128, 4096 / 128), 256, 0, stream>>>(
            all_embeds, semantic_W, em, 4096, 512, 300, 300, 300, semantic_b, nullptr, 1);
        gemm_f32_128<0><<<dim3(1024 / 128, 4096 / 128), 256, 0, stream>>>(
            em, gc1_W + (size_t)512 * 1024, Y1, 4096, 1024, 512, 512, 1024,
            nullptr, ws + OFF_VROW, 0);
        gemm_f32_128<0><<<dim3(1024 / 128, 4096 / 128), 256, 0, stream>>>(
            adj, Y1, H1, 4096, 1024, 4096, 4096, 1024, gc1_b, nullptr, 1);
        gemm_f32_128<0><<<dim3(1024 / 128, 4096 / 128), 256, 0, stream>>>(
            H1, gc2_W, Y2, 4096, 1024, 1024, 1024, 1024, nullptr, nullptr, 0);
        gemm_f32_128<0><<<dim3(1024 / 128, 4096 / 128), 256, 0, stream>>>(
            adj, Y2, H2, 4096, 1024, 4096, 4096, 1024, gc2_b, nullptr, 1);
        y3_kernel<<<4096, 256, 0, stream>>>(H2, gc3_W, ws);
        h3_kernel<<<4096, 256, 0, stream>>>(adj, gc3_b, ws);
        gcn_kernel<<<512, 256, 0, stream>>>(gcn512_W, gcn512_b, ws);
        x_kernel<<<512, 256, 0, stream>>>(hidden_W, hidden_b, ws);
        out_kernel<<<1, 512, 0, stream>>>(ws, critic_W, critic_b, actor_W, actor_b, out);
    }

    (void)in_sizes; (void)n_in; (void)out_size;
}